// Round 9
// baseline (401.025 us; speedup 1.0000x reference)
//
#include <hip/hip_runtime.h>

#define DI __device__ __forceinline__

// ---------------- ws layout (float offsets) ----------------
constexpr int OFF_WSF0 = 8;
constexpr int OFF_BNS0 = 40;
constexpr int OFF_BNB0 = 72;
constexpr int OFF_W0I  = 104;    // 32*27
constexpr int OFF_WSF1 = 968;
constexpr int OFF_BNS1 = 972;
constexpr int OFF_BNB1 = 976;
constexpr int OFF_W1I  = 980;    // 4*32
constexpr int OFF_WSF2 = 1108;
constexpr int OFF_BNS2 = 1140;
constexpr int OFF_BNB2 = 1172;
constexpr int OFF_W2I  = 1204;   // 32*36
constexpr int OFF_WSF3 = 2356;
constexpr int OFF_BNS3 = 2388;
constexpr int OFF_BNB3 = 2420;
constexpr int OFF_W3I  = 2452;   // 32*288
constexpr int OFF_WSF4 = 11668;
constexpr int OFF_BNS4 = 11700;
constexpr int OFF_BNB4 = 11732;
constexpr int OFF_W4I  = 11764;  // 9216
constexpr int OFF_WSFD = 20980;  // 10
constexpr int OFF_WDI  = 20992;  // 20480
constexpr int OFF_LOG  = 41472;  // 10240
constexpr int OFF_ACT  = 51712;
constexpr long ACT_A_OFF = OFF_ACT;              // act2/act4
constexpr long ACT_B_OFF = OFF_ACT + 8388608L;   // act1/act3

// ---------------- helpers (scalar-only) ----------------
DI float quantv(float x, float sf) {
    float q = rintf(x / sf);
    return fminf(fmaxf(q, -127.0f), 127.0f);
}
DI float get_sf(const unsigned* umax, int slot) {
    return fmaxf(__uint_as_float(umax[slot]) / 127.0f, 1e-8f);
}
DI void block_max_atomic(float v, unsigned* dst) {
    __shared__ float redm_[4];
    #pragma unroll
    for (int o = 32; o; o >>= 1) v = fmaxf(v, __shfl_down(v, o, 64));
    int wid = threadIdx.x >> 6;
    if ((threadIdx.x & 63) == 0) redm_[wid] = v;
    __syncthreads();
    if (threadIdx.x == 0) {
        int nw = blockDim.x >> 6;
        float m = redm_[0];
        for (int i = 1; i < nw; ++i) m = fmaxf(m, redm_[i]);
        atomicMax(dst, __float_as_uint(m));
    }
}

// ---- named-scalar macros (SROA-proof register tiles; rule #20) ----
#define DECL8(A) float A##0=0.f,A##1=0.f,A##2=0.f,A##3=0.f,A##4=0.f,A##5=0.f,A##6=0.f,A##7=0.f
#define DECL4(A) float A##0=0.f,A##1=0.f,A##2=0.f,A##3=0.f
#define F8(A,W,X0,X1,X2,X3,X4,X5,X6,X7) \
    A##0=fmaf(X0,W,A##0); A##1=fmaf(X1,W,A##1); A##2=fmaf(X2,W,A##2); A##3=fmaf(X3,W,A##3); \
    A##4=fmaf(X4,W,A##4); A##5=fmaf(X5,W,A##5); A##6=fmaf(X6,W,A##6); A##7=fmaf(X7,W,A##7);
#define F4(A,W,X0,X1,X2,X3) \
    A##0=fmaf(X0,W,A##0); A##1=fmaf(X1,W,A##1); A##2=fmaf(X2,W,A##2); A##3=fmaf(X3,W,A##3);
#define AMAX8(A,AA,CC) \
    lmax=fmaxf(lmax,fabsf(fmaf(A##0,AA,CC))); lmax=fmaxf(lmax,fabsf(fmaf(A##1,AA,CC))); \
    lmax=fmaxf(lmax,fabsf(fmaf(A##2,AA,CC))); lmax=fmaxf(lmax,fabsf(fmaf(A##3,AA,CC))); \
    lmax=fmaxf(lmax,fabsf(fmaf(A##4,AA,CC))); lmax=fmaxf(lmax,fabsf(fmaf(A##5,AA,CC))); \
    lmax=fmaxf(lmax,fabsf(fmaf(A##6,AA,CC))); lmax=fmaxf(lmax,fabsf(fmaf(A##7,AA,CC)));
#define SHX8(A) \
    A##0+=__shfl_xor(A##0,32,64); A##1+=__shfl_xor(A##1,32,64); A##2+=__shfl_xor(A##2,32,64); A##3+=__shfl_xor(A##3,32,64); \
    A##4+=__shfl_xor(A##4,32,64); A##5+=__shfl_xor(A##5,32,64); A##6+=__shfl_xor(A##6,32,64); A##7+=__shfl_xor(A##7,32,64);

// shared conv0 core: identical FMA structure/order in both passes
#define CONV0_MAIN \
    for (int kk = 0; kk < 9; ++kk) { \
        const int base = (kk / 3) * 360 + (row + (kk % 3)) * 36 + cb; \
        const float x0=tile[base+0],x1=tile[base+1],x2=tile[base+2],x3=tile[base+3],x4=tile[base+4]; \
        const float x5=tile[base+5],x6=tile[base+6],x7=tile[base+7],x8=tile[base+8],x9=tile[base+9]; \
        const int wb = kk * 96 + ocg * 4; \
        float wA=wlds[wb+0],wB=wlds[wb+1],wC=wlds[wb+2],wD=wlds[wb+3]; \
        F8(p0,wA,x0,x1,x2,x3,x4,x5,x6,x7); F8(p1,wB,x0,x1,x2,x3,x4,x5,x6,x7); \
        F8(p2,wC,x0,x1,x2,x3,x4,x5,x6,x7); F8(p3,wD,x0,x1,x2,x3,x4,x5,x6,x7); \
        wA=wlds[wb+32];wB=wlds[wb+33];wC=wlds[wb+34];wD=wlds[wb+35]; \
        F8(p0,wA,x1,x2,x3,x4,x5,x6,x7,x8); F8(p1,wB,x1,x2,x3,x4,x5,x6,x7,x8); \
        F8(p2,wC,x1,x2,x3,x4,x5,x6,x7,x8); F8(p3,wD,x1,x2,x3,x4,x5,x6,x7,x8); \
        wA=wlds[wb+64];wB=wlds[wb+65];wC=wlds[wb+66];wD=wlds[wb+67]; \
        F8(p0,wA,x2,x3,x4,x5,x6,x7,x8,x9); F8(p1,wB,x2,x3,x4,x5,x6,x7,x8,x9); \
        F8(p2,wC,x2,x3,x4,x5,x6,x7,x8,x9); F8(p3,wD,x2,x3,x4,x5,x6,x7,x8,x9); \
    }

// ---------------- prep ----------------
struct PrepEntry {
    const float *w, *g, *bb, *m, *v;
    float *wsf, *wint, *bns, *bnb;
    int K; int has_bn;
};
struct PrepAll { PrepEntry e[6]; unsigned* umax; };

__global__ __launch_bounds__(256) void k_prep_all(PrepAll pa) {
    int blk = blockIdx.x;
    if (blk == 142) { if (threadIdx.x < 8) pa.umax[threadIdx.x] = 0u; return; }
    int layer, oc;
    if      (blk < 32)  { layer = 0; oc = blk; }
    else if (blk < 36)  { layer = 1; oc = blk - 32; }
    else if (blk < 68)  { layer = 2; oc = blk - 36; }
    else if (blk < 100) { layer = 3; oc = blk - 68; }
    else if (blk < 132) { layer = 4; oc = blk - 100; }
    else                { layer = 5; oc = blk - 132; }
    PrepEntry a = pa.e[layer];
    const float* wr = a.w + (long)oc * a.K;
    float mx = 0.f;
    for (int i = threadIdx.x; i < a.K; i += 256) mx = fmaxf(mx, fabsf(wr[i]));
    __shared__ float red[4];
    __shared__ float s_sf;
    #pragma unroll
    for (int o = 32; o; o >>= 1) mx = fmaxf(mx, __shfl_down(mx, o, 64));
    if ((threadIdx.x & 63) == 0) red[threadIdx.x >> 6] = mx;
    __syncthreads();
    if (threadIdx.x == 0) {
        float t = fmaxf(fmaxf(red[0], red[1]), fmaxf(red[2], red[3]));
        t = fmaxf(t / 127.0f, 1e-8f);
        a.wsf[oc] = t; s_sf = t;
        if (a.has_bn) {
            float inv = a.g[oc] / sqrtf(a.v[oc] + 1e-5f);
            a.bns[oc] = inv;
            a.bnb[oc] = a.bb[oc] - a.m[oc] * inv;
        }
    }
    __syncthreads();
    float sf = s_sf;
    for (int i = threadIdx.x; i < a.K; i += 256) a.wint[(long)oc * a.K + i] = rintf(wr[i] / sf);
}

__global__ __launch_bounds__(256) void k_absmax(const float4* __restrict__ x, int n4, unsigned* dst) {
    float m = 0.f;
    for (int i = blockIdx.x * blockDim.x + threadIdx.x; i < n4; i += gridDim.x * blockDim.x) {
        float4 t = x[i];
        m = fmaxf(m, fmaxf(fmaxf(fabsf(t.x), fabsf(t.y)), fmaxf(fabsf(t.z), fabsf(t.w))));
    }
    block_max_atomic(m, dst);
}

// =========== conv0 pass 1: max only. grid 4096 = (image, 8-row band) ===========
__global__ __launch_bounds__(256, 4) void k_conv0maxN(
    const float* __restrict__ x, const float* __restrict__ w0i,
    const float* __restrict__ wsf0, const float* __restrict__ bias0,
    const float* __restrict__ bns0, const float* __restrict__ bnb0,
    const unsigned* __restrict__ umax, unsigned* __restrict__ mout) {
    __shared__ float tile[1080];
    __shared__ float wlds[864];
    __shared__ float As[32], Cs[32];
    const int b  = blockIdx.x >> 2;
    const int r0 = (blockIdx.x & 3) * 8;
    const int tid = threadIdx.x;
    const float sfx = get_sf(umax, 0);
    if (tid < 32) {
        int oc = tid;
        float bsf = wsf0[oc] * sfx;
        float bint = rintf(bias0[oc] / bsf);
        float a = bsf * bns0[oc];
        As[oc] = a;
        Cs[oc] = fmaf(bint, a, bnb0[oc]);
    }
    for (int i = tid; i < 1080; i += 256) tile[i] = 0.f;
    for (int i = tid; i < 864; i += 256) {
        int k = i >> 5, oc = i & 31;
        wlds[i] = w0i[oc * 27 + k];
    }
    __syncthreads();
    const float* xb = x + (long)b * 3072;
    for (int i = tid; i < 960; i += 256) {
        int ci = i / 320, rem = i - ci * 320;
        int rr = rem >> 5, cc = rem & 31;
        int gr = r0 - 1 + rr;
        if ((unsigned)gr < 32u)
            tile[ci * 360 + rr * 36 + cc + 1] = quantv(xb[ci * 1024 + gr * 32 + cc], sfx);
    }
    __syncthreads();
    const int ocg = tid >> 5;
    const int pxg = tid & 31;
    const int row = pxg >> 2;
    const int cb  = (pxg & 3) * 8;
    DECL8(p0); DECL8(p1); DECL8(p2); DECL8(p3);
    CONV0_MAIN
    float lmax = 0.f;
    { const float A = As[ocg*4+0], C = Cs[ocg*4+0]; AMAX8(p0, A, C); }
    { const float A = As[ocg*4+1], C = Cs[ocg*4+1]; AMAX8(p1, A, C); }
    { const float A = As[ocg*4+2], C = Cs[ocg*4+2]; AMAX8(p2, A, C); }
    { const float A = As[ocg*4+3], C = Cs[ocg*4+3]; AMAX8(p3, A, C); }
    block_max_atomic(lmax, mout);
}

// =========== conv0 pass 2 + fused 1x1 conv1. grid 4096 ===========
#define OC1X1(PO, O) { \
    const int oc_ = ocg * 4 + (O); \
    const float A_ = As[oc_], C_ = Cs[oc_]; \
    const float u0 = w1s[oc_], u1 = w1s[32+oc_], u2 = w1s[64+oc_], u3 = w1s[96+oc_]; \
    const float q0=quantv(fmaf(PO##0,A_,C_),sf1), q1=quantv(fmaf(PO##1,A_,C_),sf1); \
    const float q2=quantv(fmaf(PO##2,A_,C_),sf1), q3=quantv(fmaf(PO##3,A_,C_),sf1); \
    const float q4=quantv(fmaf(PO##4,A_,C_),sf1), q5=quantv(fmaf(PO##5,A_,C_),sf1); \
    const float q6=quantv(fmaf(PO##6,A_,C_),sf1), q7=quantv(fmaf(PO##7,A_,C_),sf1); \
    F8(r0,u0,q0,q1,q2,q3,q4,q5,q6,q7); F8(r1,u1,q0,q1,q2,q3,q4,q5,q6,q7); \
    F8(r2,u2,q0,q1,q2,q3,q4,q5,q6,q7); F8(r3,u3,q0,q1,q2,q3,q4,q5,q6,q7); \
}

__global__ __launch_bounds__(256, 4) void k_conv01n(
    const float* __restrict__ x, const float* __restrict__ w0i,
    const float* __restrict__ wsf0, const float* __restrict__ bias0,
    const float* __restrict__ bns0, const float* __restrict__ bnb0,
    const float* __restrict__ w1i,
    const float* __restrict__ wsf1, const float* __restrict__ bias1,
    const float* __restrict__ bns1, const float* __restrict__ bnb1,
    const unsigned* __restrict__ umax, unsigned* __restrict__ mout,
    float* __restrict__ out) {
    __shared__ float tile[1080];
    __shared__ float wlds[864];
    __shared__ float w1s[128];
    __shared__ float As[32], Cs[32];
    __shared__ float A1s[4], C1s[4];
    __shared__ float red[4][32][36];
    const int b  = blockIdx.x >> 2;
    const int r0 = (blockIdx.x & 3) * 8;
    const int tid = threadIdx.x;
    const float sfx = get_sf(umax, 0);
    const float sf1 = get_sf(umax, 1);
    if (tid < 32) {
        int oc = tid;
        float bsf = wsf0[oc] * sfx;
        float bint = rintf(bias0[oc] / bsf);
        float a = bsf * bns0[oc];
        As[oc] = a;
        Cs[oc] = fmaf(bint, a, bnb0[oc]);
    }
    if (tid >= 64 && tid < 68) {
        int oc = tid - 64;
        float bsf = wsf1[oc] * sf1;
        float bint = rintf(bias1[oc] / bsf);
        float a = bsf * bns1[oc];
        A1s[oc] = a;
        C1s[oc] = fmaf(bint, a, bnb1[oc]);
    }
    if (tid >= 128 && tid < 256) w1s[tid - 128] = w1i[tid - 128];
    for (int i = tid; i < 1080; i += 256) tile[i] = 0.f;
    for (int i = tid; i < 864; i += 256) {
        int k = i >> 5, oc = i & 31;
        wlds[i] = w0i[oc * 27 + k];
    }
    __syncthreads();
    const float* xb = x + (long)b * 3072;
    for (int i = tid; i < 960; i += 256) {
        int ci = i / 320, rem = i - ci * 320;
        int rr = rem >> 5, cc = rem & 31;
        int gr = r0 - 1 + rr;
        if ((unsigned)gr < 32u)
            tile[ci * 360 + rr * 36 + cc + 1] = quantv(xb[ci * 1024 + gr * 32 + cc], sfx);
    }
    __syncthreads();
    const int ocg = tid >> 5;
    const int pxg = tid & 31;
    const int row = pxg >> 2;
    const int cb  = (pxg & 3) * 8;
    DECL8(p0); DECL8(p1); DECL8(p2); DECL8(p3);
    CONV0_MAIN
    // quantize act0 + partial 1x1 over this thread's 4 input channels
    DECL8(r0); DECL8(r1); DECL8(r2); DECL8(r3);
    OC1X1(p0, 0)
    OC1X1(p1, 1)
    OC1X1(p2, 2)
    OC1X1(p3, 3)
    // reduce ocg pairs within wave (integer-exact)
    SHX8(r0); SHX8(r1); SHX8(r2); SHX8(r3);
    const int wv = tid >> 6;
    if ((tid & 63) < 32) {
        float* rp = &red[wv][pxg][0];
        rp[0]=r00; rp[1]=r01; rp[2]=r02; rp[3]=r03; rp[4]=r04; rp[5]=r05; rp[6]=r06; rp[7]=r07;
        rp[8]=r10; rp[9]=r11; rp[10]=r12; rp[11]=r13; rp[12]=r14; rp[13]=r15; rp[14]=r16; rp[15]=r17;
        rp[16]=r20; rp[17]=r21; rp[18]=r22; rp[19]=r23; rp[20]=r24; rp[21]=r25; rp[22]=r26; rp[23]=r27;
        rp[24]=r30; rp[25]=r31; rp[26]=r32; rp[27]=r33; rp[28]=r34; rp[29]=r35; rp[30]=r36; rp[31]=r37;
    }
    __syncthreads();
    // final: sum 4 waves, BN1, write
    const int col  = tid & 31;
    const int orow = tid >> 5;
    const int pxg2 = orow * 4 + (col >> 3);
    const int ps   = col & 7;
    float lmax = 0.f;
    float* ob = out + (long)b * 4096 + (r0 + orow) * 32 + col;
    #pragma unroll
    for (int o1 = 0; o1 < 4; ++o1) {
        int j = o1 * 8 + ps;
        float s = (red[0][pxg2][j] + red[1][pxg2][j]) + (red[2][pxg2][j] + red[3][pxg2][j]);
        float y = fmaf(s, A1s[o1], C1s[o1]);
        lmax = fmaxf(lmax, fabsf(y));
        ob[o1 * 1024] = y;
    }
    block_max_atomic(lmax, mout);
}

// =========== conv2 (4->32, 3x3, s2): thread = 8 oc x 4 px, scalarized ===========
#define C2KX(G0,G1,G2,G3,G4,G5,G6,G7,X0,X1,X2,X3) \
    F4(c0,G0,X0,X1,X2,X3); F4(c1,G1,X0,X1,X2,X3); F4(c2,G2,X0,X1,X2,X3); F4(c3,G3,X0,X1,X2,X3); \
    F4(c4,G4,X0,X1,X2,X3); F4(c5,G5,X0,X1,X2,X3); F4(c6,G6,X0,X1,X2,X3); F4(c7,G7,X0,X1,X2,X3);
#define C2OUT(A, K) { \
    const float Aa = As[oc0+(K)], Cc = Cs[oc0+(K)]; \
    const float y0 = fmaf(A##0, Aa, Cc), y1 = fmaf(A##1, Aa, Cc); \
    const float y2 = fmaf(A##2, Aa, Cc), y3 = fmaf(A##3, Aa, Cc); \
    lmax = fmaxf(lmax, fmaxf(fmaxf(fabsf(y0), fabsf(y1)), fmaxf(fabsf(y2), fabsf(y3)))); \
    float4 rr; rr.x = y0; rr.y = y1; rr.z = y2; rr.w = y3; \
    *(float4*)&ob[(oc0+(K)) * 256 + h * 16 + c * 4] = rr; }

__global__ __launch_bounds__(256, 4) void k_conv2c(
    const float* __restrict__ inp, const float* __restrict__ wgl,
    const float* __restrict__ wsf, const float* __restrict__ bias,
    const float* __restrict__ bns, const float* __restrict__ bnb,
    const unsigned* __restrict__ umax, unsigned* __restrict__ mout,
    float* __restrict__ out) {
    __shared__ float tile[4 * 34 * 36];
    __shared__ float wlds[36 * 32];
    __shared__ float As[32], Cs[32];
    const int tid = threadIdx.x;
    const float sf = get_sf(umax, 2);
    if (tid < 32) {
        int oc = tid;
        float bsf = wsf[oc] * sf;
        float bint = rintf(bias[oc] / bsf);
        float a = bsf * bns[oc];
        As[oc] = a;
        Cs[oc] = fmaf(bint, a, bnb[oc]);
    }
    for (int i = tid; i < 4896; i += 256) tile[i] = 0.f;
    for (int i = tid; i < 1152; i += 256) {
        int k = i >> 5, oc = i & 31;
        wlds[i] = wgl[oc * 36 + k];
    }
    __syncthreads();
    const float* ib = inp + (long)blockIdx.x * 4096;
    for (int i = tid; i < 4096; i += 256) {
        int ci = i >> 10, px = i & 1023;
        int iy = px >> 5, ix = px & 31;
        tile[ci * 1224 + (iy + 1) * 36 + (ix + 1)] = quantv(ib[i], sf);
    }
    __syncthreads();
    const int oc0 = (tid >> 6) * 8;
    const int pxq = tid & 63;
    const int h = pxq >> 2, c = pxq & 3;
    DECL4(c0); DECL4(c1); DECL4(c2); DECL4(c3);
    DECL4(c4); DECL4(c5); DECL4(c6); DECL4(c7);
    for (int kk = 0; kk < 12; ++kk) {       // kk = ci*3 + ky
        const int base = (kk / 3) * 1224 + (2 * h + (kk % 3)) * 36 + 8 * c;
        const float x0=tile[base+0],x1=tile[base+1],x2=tile[base+2],x3=tile[base+3],x4=tile[base+4];
        const float x5=tile[base+5],x6=tile[base+6],x7=tile[base+7],x8=tile[base+8];
        const int wb = kk * 96 + oc0;       // (kk*3+kx)*32 + oc0
        {
            const float g0=wlds[wb+0],g1=wlds[wb+1],g2=wlds[wb+2],g3=wlds[wb+3];
            const float g4=wlds[wb+4],g5=wlds[wb+5],g6=wlds[wb+6],g7=wlds[wb+7];
            C2KX(g0,g1,g2,g3,g4,g5,g6,g7, x0,x2,x4,x6);
        }
        {
            const float g0=wlds[wb+32],g1=wlds[wb+33],g2=wlds[wb+34],g3=wlds[wb+35];
            const float g4=wlds[wb+36],g5=wlds[wb+37],g6=wlds[wb+38],g7=wlds[wb+39];
            C2KX(g0,g1,g2,g3,g4,g5,g6,g7, x1,x3,x5,x7);
        }
        {
            const float g0=wlds[wb+64],g1=wlds[wb+65],g2=wlds[wb+66],g3=wlds[wb+67];
            const float g4=wlds[wb+68],g5=wlds[wb+69],g6=wlds[wb+70],g7=wlds[wb+71];
            C2KX(g0,g1,g2,g3,g4,g5,g6,g7, x2,x4,x6,x8);
        }
    }
    float lmax = 0.f;
    float* ob = out + (long)blockIdx.x * 8192;
    C2OUT(c0, 0) C2OUT(c1, 1) C2OUT(c2, 2) C2OUT(c3, 3)
    C2OUT(c4, 4) C2OUT(c5, 5) C2OUT(c6, 6) C2OUT(c7, 7)
    block_max_atomic(lmax, mout);
}

// =========== conv3/conv4: 2 img/block, 4oc x 4px, K-phased (arrays <=64B, OK) ===========
template<int HIN, int S>
__global__ __launch_bounds__(256, 4) void k_conv34b(
    const float* __restrict__ inp, const float* __restrict__ wi,
    const float* __restrict__ wsf, const float* __restrict__ bias,
    const float* __restrict__ bns, const float* __restrict__ bnb,
    const unsigned* __restrict__ umax, int slot, unsigned* __restrict__ mout,
    float* __restrict__ out) {
    constexpr int ROWS = HIN + 2;
    constexpr int RS   = (S == 2) ? 20 : 12;
    constexpr int TI   = 8 * ROWS * RS;
    constexpr int PIX  = HIN * HIN;
    constexpr int NELT = 2 * 8 * PIX;
    constexpr int WINW = (S == 2) ? 10 : 6;
    __shared__ float tile[2 * TI];
    __shared__ float wlds[72 * 36];
    __shared__ float As[32], Cs[32];
    const int tid  = threadIdx.x;
    const int imgl = tid >> 7;
    const int ocg  = (tid >> 4) & 7;
    const int pxq  = tid & 15;
    const int h = pxq >> 1, c = pxq & 1;
    const float sf = get_sf(umax, slot);
    if (tid < 32) {
        int oc = tid;
        float bsf = wsf[oc] * sf;
        float bint = rintf(bias[oc] / bsf);
        float a = bsf * bns[oc];
        As[oc] = a;
        Cs[oc] = fmaf(bint, a, bnb[oc]);
    }
    for (int i = tid; i < 2 * TI; i += 256) tile[i] = 0.f;
    float acc[4][4];
    #pragma unroll
    for (int k = 0; k < 4; ++k)
        #pragma unroll
        for (int p = 0; p < 4; ++p) acc[k][p] = 0.f;
    const float* ib = inp + (long)blockIdx.x * 2 * 32 * PIX;
    for (int ph = 0; ph < 4; ++ph) {
        __syncthreads();
        for (int i = tid; i < NELT; i += 256) {
            int im = i / (8 * PIX);
            int r  = i % (8 * PIX);
            int ci = r / PIX;
            int px = r % PIX;
            int iy = px / HIN, ix = px % HIN;
            tile[(im * 8 + ci) * (ROWS * RS) + (iy + 1) * RS + (ix + 1)] =
                quantv(ib[(long)(im * 32 + ph * 8 + ci) * PIX + px], sf);
        }
        for (int i = tid; i < 2304; i += 256) {
            int oc = i / 72, k = i - oc * 72;
            wlds[k * 36 + oc] = wi[oc * 288 + ph * 72 + k];
        }
        __syncthreads();
        const int tbo = imgl * TI;
        #pragma unroll 2
        for (int ci = 0; ci < 8; ++ci) {
            #pragma unroll
            for (int ky = 0; ky < 3; ++ky) {
                const int base = tbo + ci * (ROWS * RS) + (S * h + ky) * RS + S * 4 * c;
                float xw[WINW];
                #pragma unroll
                for (int d = 0; d < WINW; ++d) xw[d] = tile[base + d];
                #pragma unroll
                for (int kx = 0; kx < 3; ++kx) {
                    const int wb = (ci * 9 + ky * 3 + kx) * 36 + ocg * 4;
                    float wv0 = wlds[wb + 0];
                    float wv1 = wlds[wb + 1];
                    float wv2 = wlds[wb + 2];
                    float wv3 = wlds[wb + 3];
                    #pragma unroll
                    for (int p = 0; p < 4; ++p) {
                        acc[0][p] = fmaf(xw[S * p + kx], wv0, acc[0][p]);
                        acc[1][p] = fmaf(xw[S * p + kx], wv1, acc[1][p]);
                        acc[2][p] = fmaf(xw[S * p + kx], wv2, acc[2][p]);
                        acc[3][p] = fmaf(xw[S * p + kx], wv3, acc[3][p]);
                    }
                }
            }
        }
    }
    float lmax = 0.f;
    long imgg = (long)blockIdx.x * 2 + imgl;
    #pragma unroll
    for (int k = 0; k < 4; ++k) {
        int oc = ocg * 4 + k;
        float A = As[oc], C = Cs[oc];
        float y0 = fmaf(acc[k][0], A, C);
        float y1 = fmaf(acc[k][1], A, C);
        float y2 = fmaf(acc[k][2], A, C);
        float y3 = fmaf(acc[k][3], A, C);
        lmax = fmaxf(lmax, fmaxf(fmaxf(fabsf(y0), fabsf(y1)), fmaxf(fabsf(y2), fabsf(y3))));
        float4 r;
        r.x = y0; r.y = y1; r.z = y2; r.w = y3;
        *(float4*)&out[(imgg * 32 + oc) * 64 + h * 8 + c * 4] = r;
    }
    block_max_atomic(lmax, mout);
}

// ---------------- linear 2048->10 ----------------
__global__ __launch_bounds__(256) void k_fc(
    const float* __restrict__ act, const float* __restrict__ wdi,
    const float* __restrict__ wsfd, const float* __restrict__ bd,
    const unsigned* __restrict__ umax, float* __restrict__ logits) {
    int b = blockIdx.x;
    float sf = get_sf(umax, 5);
    const float* ab = act + (long)b * 2048;
    float acc[10];
    #pragma unroll
    for (int c = 0; c < 10; ++c) acc[c] = 0.f;
    #pragma unroll
    for (int k = 0; k < 8; ++k) {
        int j = threadIdx.x + 256 * k;
        float q = quantv(ab[j], sf);
        #pragma unroll
        for (int c = 0; c < 10; ++c) acc[c] = fmaf(q, wdi[c * 2048 + j], acc[c]);
    }
    #pragma unroll
    for (int c = 0; c < 10; ++c)
        #pragma unroll
        for (int o = 32; o; o >>= 1) acc[c] += __shfl_down(acc[c], o, 64);
    __shared__ float red[4][10];
    int wid = threadIdx.x >> 6;
    if ((threadIdx.x & 63) == 0)
        #pragma unroll
        for (int c = 0; c < 10; ++c) red[wid][c] = acc[c];
    __syncthreads();
    if (threadIdx.x < 10) {
        int c = threadIdx.x;
        float s = red[0][c] + red[1][c] + red[2][c] + red[3][c];
        float bsf = wsfd[c] * sf;
        float bint = rintf(bd[c] / bsf);
        logits[b * 10 + c] = (s + bint) * bsf;
    }
}

// ---------------- softmax over batch axis ----------------
__global__ __launch_bounds__(256) void k_softmax(const float* __restrict__ logits, float* __restrict__ out) {
    int c = blockIdx.x;
    float v0 = logits[(threadIdx.x +   0) * 10 + c];
    float v1 = logits[(threadIdx.x + 256) * 10 + c];
    float v2 = logits[(threadIdx.x + 512) * 10 + c];
    float v3 = logits[(threadIdx.x + 768) * 10 + c];
    float mx = fmaxf(fmaxf(v0, v1), fmaxf(v2, v3));
    __shared__ float redm[4];
    __shared__ float reds[4];
    #pragma unroll
    for (int o = 32; o; o >>= 1) mx = fmaxf(mx, __shfl_down(mx, o, 64));
    if ((threadIdx.x & 63) == 0) redm[threadIdx.x >> 6] = mx;
    __syncthreads();
    mx = fmaxf(fmaxf(redm[0], redm[1]), fmaxf(redm[2], redm[3]));
    float e0 = expf(v0 - mx), e1 = expf(v1 - mx), e2 = expf(v2 - mx), e3 = expf(v3 - mx);
    float s = (e0 + e1) + (e2 + e3);
    #pragma unroll
    for (int o = 32; o; o >>= 1) s += __shfl_down(s, o, 64);
    if ((threadIdx.x & 63) == 0) reds[threadIdx.x >> 6] = s;
    __syncthreads();
    s = reds[0] + reds[1] + reds[2] + reds[3];
    out[(threadIdx.x +   0) * 10 + c] = e0 / s;
    out[(threadIdx.x + 256) * 10 + c] = e1 / s;
    out[(threadIdx.x + 512) * 10 + c] = e2 / s;
    out[(threadIdx.x + 768) * 10 + c] = e3 / s;
}

extern "C" void kernel_launch(void* const* d_in, const int* in_sizes, int n_in,
                              void* d_out, int out_size, void* d_ws, size_t ws_size,
                              hipStream_t stream) {
    (void)in_sizes; (void)n_in; (void)out_size; (void)ws_size;
    const float* x = (const float*)d_in[0];
    const float *w[5], *bia[5], *g[5], *bb[5], *m[5], *v[5];
    for (int i = 0; i < 5; ++i) {
        w[i]   = (const float*)d_in[1 + 6 * i + 0];
        bia[i] = (const float*)d_in[1 + 6 * i + 1];
        g[i]   = (const float*)d_in[1 + 6 * i + 2];
        bb[i]  = (const float*)d_in[1 + 6 * i + 3];
        m[i]   = (const float*)d_in[1 + 6 * i + 4];
        v[i]   = (const float*)d_in[1 + 6 * i + 5];
    }
    const float* wd = (const float*)d_in[31];
    const float* bd = (const float*)d_in[32];
    float* ws = (float*)d_ws;
    unsigned* umax = (unsigned*)ws;
    float* out = (float*)d_out;

    float* wsf0 = ws + OFF_WSF0; float* bns0 = ws + OFF_BNS0; float* bnb0 = ws + OFF_BNB0; float* w0i = ws + OFF_W0I;
    float* wsf1 = ws + OFF_WSF1; float* bns1 = ws + OFF_BNS1; float* bnb1 = ws + OFF_BNB1; float* w1i = ws + OFF_W1I;
    float* wsf2 = ws + OFF_WSF2; float* bns2 = ws + OFF_BNS2; float* bnb2 = ws + OFF_BNB2; float* w2i = ws + OFF_W2I;
    float* wsf3 = ws + OFF_WSF3; float* bns3 = ws + OFF_BNS3; float* bnb3 = ws + OFF_BNB3; float* w3i = ws + OFF_W3I;
    float* wsf4 = ws + OFF_WSF4; float* bns4 = ws + OFF_BNS4; float* bnb4 = ws + OFF_BNB4; float* w4i = ws + OFF_W4I;
    float* wsfd = ws + OFF_WSFD; float* wdi = ws + OFF_WDI;
    float* logits = ws + OFF_LOG;
    float* actA = ws + ACT_A_OFF;   // act2 / act4
    float* actB = ws + ACT_B_OFF;   // act1 / act3

    PrepAll pa;
    pa.umax = umax;
    const float* ww[6] = {w[0], w[1], w[2], w[3], w[4], wd};
    float* wsfp[6] = {wsf0, wsf1, wsf2, wsf3, wsf4, wsfd};
    float* wip[6]  = {w0i, w1i, w2i, w3i, w4i, wdi};
    float* bnsp[6] = {bns0, bns1, bns2, bns3, bns4, nullptr};
    float* bnbp[6] = {bnb0, bnb1, bnb2, bnb3, bnb4, nullptr};
    int Ks[6] = {27, 32, 36, 288, 288, 2048};
    for (int i = 0; i < 6; ++i) {
        pa.e[i].w = ww[i];
        pa.e[i].g = (i < 5) ? g[i] : nullptr;
        pa.e[i].bb = (i < 5) ? bb[i] : nullptr;
        pa.e[i].m = (i < 5) ? m[i] : nullptr;
        pa.e[i].v = (i < 5) ? v[i] : nullptr;
        pa.e[i].wsf = wsfp[i];
        pa.e[i].wint = wip[i];
        pa.e[i].bns = bnsp[i];
        pa.e[i].bnb = bnbp[i];
        pa.e[i].K = Ks[i];
        pa.e[i].has_bn = (i < 5) ? 1 : 0;
    }

    hipLaunchKernelGGL(k_prep_all, dim3(143), dim3(256), 0, stream, pa);
    hipLaunchKernelGGL(k_absmax, dim3(256), dim3(256), 0, stream,
                       (const float4*)x, 1024 * 3 * 32 * 32 / 4, umax + 0);
    hipLaunchKernelGGL(k_conv0maxN, dim3(4096), dim3(256), 0, stream,
                       x, w0i, wsf0, bia[0], bns0, bnb0, umax, umax + 1);
    hipLaunchKernelGGL(k_conv01n, dim3(4096), dim3(256), 0, stream,
                       x, w0i, wsf0, bia[0], bns0, bnb0,
                       w1i, wsf1, bia[1], bns1, bnb1, umax, umax + 2, actB);
    hipLaunchKernelGGL(k_conv2c, dim3(1024), dim3(256), 0, stream,
                       actB, w2i, wsf2, bia[2], bns2, bnb2, umax, umax + 3, actA);
    hipLaunchKernelGGL((k_conv34b<16, 2>), dim3(512), dim3(256), 0, stream,
                       actA, w3i, wsf3, bia[3], bns3, bnb3, umax, 3, umax + 4, actB);
    hipLaunchKernelGGL((k_conv34b<8, 1>),  dim3(512), dim3(256), 0, stream,
                       actB, w4i, wsf4, bia[4], bns4, bnb4, umax, 4, umax + 5, actA);
    hipLaunchKernelGGL(k_fc, dim3(1024), dim3(256), 0, stream, actA, wdi, wsfd, bd, umax, logits);
    hipLaunchKernelGGL(k_softmax, dim3(10), dim3(256), 0, stream, logits, out);
}

// Round 10
// 231.260 us; speedup vs baseline: 1.7341x; 1.7341x over previous
//
#include <hip/hip_runtime.h>

#define DI __device__ __forceinline__

// ---------------- ws layout (float offsets) ----------------
constexpr int OFF_WSF0 = 8;
constexpr int OFF_BNS0 = 40;
constexpr int OFF_BNB0 = 72;
constexpr int OFF_W0I  = 104;    // 32*27
constexpr int OFF_WSF1 = 968;
constexpr int OFF_BNS1 = 972;
constexpr int OFF_BNB1 = 976;
constexpr int OFF_W1I  = 980;    // 4*32
constexpr int OFF_WSF2 = 1108;
constexpr int OFF_BNS2 = 1140;
constexpr int OFF_BNB2 = 1172;
constexpr int OFF_W2I  = 1204;   // 32*36
constexpr int OFF_WSF3 = 2356;
constexpr int OFF_BNS3 = 2388;
constexpr int OFF_BNB3 = 2420;
constexpr int OFF_W3I  = 2452;   // 32*288
constexpr int OFF_WSF4 = 11668;
constexpr int OFF_BNS4 = 11700;
constexpr int OFF_BNB4 = 11732;
constexpr int OFF_W4I  = 11764;  // 9216
constexpr int OFF_WSFD = 20980;  // 10
constexpr int OFF_WDI  = 20992;  // 20480
constexpr int OFF_LOG  = 41472;  // 10240
constexpr int OFF_ACT  = 51712;
constexpr long ACT_A_OFF = OFF_ACT;              // act2/act4
constexpr long ACT_B_OFF = OFF_ACT + 8388608L;   // act1/act3

// ---------------- helpers ----------------
DI float quantv(float x, float sf) {
    float q = rintf(x / sf);
    return fminf(fmaxf(q, -127.0f), 127.0f);
}
DI float get_sf(const unsigned* umax, int slot) {
    return fmaxf(__uint_as_float(umax[slot]) / 127.0f, 1e-8f);
}
DI void block_max_atomic(float v, unsigned* dst) {
    __shared__ float redm_[4];
    #pragma unroll
    for (int o = 32; o; o >>= 1) v = fmaxf(v, __shfl_down(v, o, 64));
    int wid = threadIdx.x >> 6;
    if ((threadIdx.x & 63) == 0) redm_[wid] = v;
    __syncthreads();
    if (threadIdx.x == 0) {
        int nw = blockDim.x >> 6;
        float m = redm_[0];
        for (int i = 1; i < nw; ++i) m = fmaxf(m, redm_[i]);
        atomicMax(dst, __float_as_uint(m));
    }
}

// ---------------- prep: weight quant + BN fold ----------------
struct PrepEntry {
    const float *w, *g, *bb, *m, *v;
    float *wsf, *wint, *bns, *bnb;
    int K; int has_bn;
};
struct PrepAll { PrepEntry e[6]; unsigned* umax; };

__global__ __launch_bounds__(256) void k_prep_all(PrepAll pa) {
    int blk = blockIdx.x;
    if (blk == 142) { if (threadIdx.x < 8) pa.umax[threadIdx.x] = 0u; return; }
    int layer, oc;
    if      (blk < 32)  { layer = 0; oc = blk; }
    else if (blk < 36)  { layer = 1; oc = blk - 32; }
    else if (blk < 68)  { layer = 2; oc = blk - 36; }
    else if (blk < 100) { layer = 3; oc = blk - 68; }
    else if (blk < 132) { layer = 4; oc = blk - 100; }
    else                { layer = 5; oc = blk - 132; }
    PrepEntry a = pa.e[layer];
    const float* wr = a.w + (long)oc * a.K;
    float mx = 0.f;
    for (int i = threadIdx.x; i < a.K; i += 256) mx = fmaxf(mx, fabsf(wr[i]));
    __shared__ float red[4];
    __shared__ float s_sf;
    #pragma unroll
    for (int o = 32; o; o >>= 1) mx = fmaxf(mx, __shfl_down(mx, o, 64));
    if ((threadIdx.x & 63) == 0) red[threadIdx.x >> 6] = mx;
    __syncthreads();
    if (threadIdx.x == 0) {
        float t = fmaxf(fmaxf(red[0], red[1]), fmaxf(red[2], red[3]));
        t = fmaxf(t / 127.0f, 1e-8f);
        a.wsf[oc] = t; s_sf = t;
        if (a.has_bn) {
            float inv = a.g[oc] / sqrtf(a.v[oc] + 1e-5f);
            a.bns[oc] = inv;
            a.bnb[oc] = a.bb[oc] - a.m[oc] * inv;
        }
    }
    __syncthreads();
    float sf = s_sf;
    for (int i = threadIdx.x; i < a.K; i += 256) a.wint[(long)oc * a.K + i] = rintf(wr[i] / sf);
}

__global__ __launch_bounds__(256) void k_absmax(const float4* __restrict__ x, int n4, unsigned* dst) {
    float m = 0.f;
    for (int i = blockIdx.x * blockDim.x + threadIdx.x; i < n4; i += gridDim.x * blockDim.x) {
        float4 t = x[i];
        m = fmaxf(m, fmaxf(fmaxf(fabsf(t.x), fabsf(t.y)), fmaxf(fabsf(t.z), fabsf(t.w))));
    }
    block_max_atomic(m, dst);
}

// ---------------- conv0 pass 1: max only. grid 2048 = (image, row-half) ----------------
// thread = 4 oc x 16 px. amdgpu_waves_per_eu(1,4): cap occupancy target -> VGPR budget 128.
__global__ __attribute__((amdgpu_waves_per_eu(1, 4))) __launch_bounds__(256) void k_conv0maxN(
    const float* __restrict__ x, const float* __restrict__ w0i,
    const float* __restrict__ wsf0, const float* __restrict__ bias0,
    const float* __restrict__ bns0, const float* __restrict__ bnb0,
    const unsigned* __restrict__ umax, unsigned* __restrict__ mout) {
    __shared__ float tile[3 * 18 * 36];   // 1944
    __shared__ float wlds[27 * 32];       // 864
    __shared__ float As[32], Cs[32];
    const int b  = blockIdx.x >> 1;
    const int r0 = (blockIdx.x & 1) * 16;
    const int tid = threadIdx.x;
    const float sfx = get_sf(umax, 0);
    if (tid < 32) {
        int oc = tid;
        float bsf = wsf0[oc] * sfx;
        float bint = rintf(bias0[oc] / bsf);
        float a = bsf * bns0[oc];
        As[oc] = a;
        Cs[oc] = fmaf(bint, a, bnb0[oc]);
    }
    for (int i = tid; i < 1944; i += 256) tile[i] = 0.f;
    for (int i = tid; i < 864; i += 256) {
        int k = i >> 5, oc = i & 31;
        wlds[i] = w0i[oc * 27 + k];
    }
    __syncthreads();
    const float* xb = x + (long)b * 3072;
    for (int i = tid; i < 1728; i += 256) {          // 3 ci * 18 rows * 32 cols
        int ci = i / 576, rem = i - ci * 576;
        int rr = rem >> 5, cc = rem & 31;
        int gr = r0 - 1 + rr;
        if ((unsigned)gr < 32u)
            tile[ci * 648 + rr * 36 + cc + 1] = quantv(xb[ci * 1024 + gr * 32 + cc], sfx);
    }
    __syncthreads();
    const int oc0  = (tid >> 5) * 4;       // 8 oc-quads
    const int pxg  = tid & 31;
    const int row  = pxg >> 1;             // 0..15 (output row r0+row)
    const int wcol = (pxg & 1) * 16;       // output col base
    float acc[4][16];
    #pragma unroll
    for (int o = 0; o < 4; ++o)
        #pragma unroll
        for (int p = 0; p < 16; ++p) acc[o][p] = 0.f;
    #pragma unroll 1
    for (int kk = 0; kk < 9; ++kk) {       // kk = ci*3 + ky
        int ci = kk / 3, ky = kk - ci * 3;
        const float* rp = tile + ci * 648 + (row + ky) * 36 + wcol;
        float wn[20];
        #pragma unroll
        for (int d = 0; d < 5; ++d) *(float4*)&wn[4 * d] = *(const float4*)&rp[4 * d];
        #pragma unroll
        for (int kx = 0; kx < 3; ++kx) {
            float4 wv = *(const float4*)&wlds[(kk * 3 + kx) * 32 + oc0];
            const float* wf = &wv.x;
            #pragma unroll
            for (int o = 0; o < 4; ++o)
                #pragma unroll
                for (int p = 0; p < 16; ++p)
                    acc[o][p] = fmaf(wn[p + kx], wf[o], acc[o][p]);
        }
    }
    float lmax = 0.f;
    #pragma unroll
    for (int o = 0; o < 4; ++o) {
        float A = As[oc0 + o], C = Cs[oc0 + o];
        #pragma unroll
        for (int p = 0; p < 16; ++p)
            lmax = fmaxf(lmax, fabsf(fmaf(acc[o][p], A, C)));
    }
    block_max_atomic(lmax, mout);
}

// ---------------- conv0 pass 2 + fused 1x1 conv1. grid 512 = B/2 ----------------
// thread = 8 px, all 32 oc sequential; window cached in 108 registers.
// amdgpu_waves_per_eu(1,2): VGPR budget 256 to hold the win/wreg/acc tile.
__global__ __attribute__((amdgpu_waves_per_eu(1, 2))) __launch_bounds__(256) void k_conv01n(
    const float* __restrict__ x, const float* __restrict__ w0i,
    const float* __restrict__ wsf0, const float* __restrict__ bias0,
    const float* __restrict__ bns0, const float* __restrict__ bnb0,
    const float* __restrict__ w1i,
    const float* __restrict__ wsf1, const float* __restrict__ bias1,
    const float* __restrict__ bns1, const float* __restrict__ bnb1,
    const unsigned* __restrict__ umax, unsigned* __restrict__ mout,
    float* __restrict__ out) {
    __shared__ float tile[2 * 3672];      // [img][3][34][36]
    __shared__ float wls0[896];           // [32][28]
    __shared__ float wls1[128];           // [32][4]
    __shared__ float As[32], Cs[32];
    __shared__ float A1s[4], C1s[4];
    const int tid = threadIdx.x;
    const long b2 = (long)blockIdx.x * 2;
    const float sfx = get_sf(umax, 0);
    const float sf1 = get_sf(umax, 1);
    if (tid < 32) {
        int oc = tid;
        float bsf = wsf0[oc] * sfx;
        float bint = rintf(bias0[oc] / bsf);
        float a = bsf * bns0[oc];
        As[oc] = a;
        Cs[oc] = fmaf(bint, a, bnb0[oc]);
    }
    if (tid >= 64 && tid < 68) {
        int oc = tid - 64;
        float bsf = wsf1[oc] * sf1;
        float bint = rintf(bias1[oc] / bsf);
        float a = bsf * bns1[oc];
        A1s[oc] = a;
        C1s[oc] = fmaf(bint, a, bnb1[oc]);
    }
    for (int i = tid; i < 2 * 3672; i += 256) tile[i] = 0.f;
    for (int i = tid; i < 864; i += 256) {
        int oc = i / 27, k = i - oc * 27;
        wls0[oc * 28 + k] = w0i[i];
    }
    if (tid < 128) {
        int o1 = tid >> 5, oc = tid & 31;
        wls1[oc * 4 + o1] = w1i[tid];
    }
    __syncthreads();
    for (int i = tid; i < 6144; i += 256) {
        int img = i / 3072, rem = i - img * 3072;
        int ci = rem >> 10, px = rem & 1023;
        int iy = px >> 5, ix = px & 31;
        tile[img * 3672 + ci * 1224 + (iy + 1) * 36 + (ix + 1)] =
            quantv(x[(b2 + img) * 3072 + rem], sfx);
    }
    __syncthreads();
    const int img = tid >> 7;
    const int pt  = tid & 127;
    const int h   = pt >> 2;          // out row 0..31
    const int w0  = (pt & 3) * 8;     // out col base
    // cache the full 3x3x(8+2) window in registers
    float win[3][3][12];
    #pragma unroll
    for (int ci = 0; ci < 3; ++ci)
        #pragma unroll
        for (int ky = 0; ky < 3; ++ky) {
            const float* rp = tile + img * 3672 + ci * 1224 + (h + ky) * 36 + w0;
            #pragma unroll
            for (int d = 0; d < 3; ++d)
                *(float4*)&win[ci][ky][4 * d] = *(const float4*)&rp[4 * d];
        }
    float acc1[4][8];
    #pragma unroll
    for (int o = 0; o < 4; ++o)
        #pragma unroll
        for (int p = 0; p < 8; ++p) acc1[o][p] = 0.f;
    #pragma unroll 1
    for (int oc = 0; oc < 32; ++oc) {
        float wreg[28];
        const float4* wp4 = (const float4*)&wls0[oc * 28];
        #pragma unroll
        for (int d = 0; d < 7; ++d) *(float4*)&wreg[4 * d] = wp4[d];
        float acc0[8];
        #pragma unroll
        for (int p = 0; p < 8; ++p) acc0[p] = 0.f;
        #pragma unroll
        for (int ci = 0; ci < 3; ++ci)
            #pragma unroll
            for (int ky = 0; ky < 3; ++ky)
                #pragma unroll
                for (int kx = 0; kx < 3; ++kx) {
                    float wv = wreg[ci * 9 + ky * 3 + kx];
                    #pragma unroll
                    for (int p = 0; p < 8; ++p)
                        acc0[p] = fmaf(win[ci][ky][p + kx], wv, acc0[p]);
                }
        float A = As[oc], C = Cs[oc];
        float4 w1v = *(const float4*)&wls1[oc * 4];
        const float* w1f = &w1v.x;
        #pragma unroll
        for (int p = 0; p < 8; ++p) {
            float q = quantv(fmaf(acc0[p], A, C), sf1);
            #pragma unroll
            for (int o = 0; o < 4; ++o)
                acc1[o][p] = fmaf(q, w1f[o], acc1[o][p]);
        }
    }
    float lmax = 0.f;
    float* ob = out + (b2 + img) * 4096;
    #pragma unroll
    for (int o = 0; o < 4; ++o) {
        float A = A1s[o], C = C1s[o];
        float r[8];
        #pragma unroll
        for (int p = 0; p < 8; ++p) {
            float y = fmaf(acc1[o][p], A, C);
            r[p] = y;
            lmax = fmaxf(lmax, fabsf(y));
        }
        *(float4*)&ob[o * 1024 + h * 32 + w0]     = *(float4*)&r[0];
        *(float4*)&ob[o * 1024 + h * 32 + w0 + 4] = *(float4*)&r[4];
    }
    block_max_atomic(lmax, mout);
}

// ---------------- conv2 (4->32, 3x3, s2): thread = 8 oc x 4 px, weights k-major LDS ----------------
__global__ __attribute__((amdgpu_waves_per_eu(1, 4))) __launch_bounds__(256) void k_conv2c(
    const float* __restrict__ inp, const float* __restrict__ wgl,
    const float* __restrict__ wsf, const float* __restrict__ bias,
    const float* __restrict__ bns, const float* __restrict__ bnb,
    const unsigned* __restrict__ umax, unsigned* __restrict__ mout,
    float* __restrict__ out) {
    __shared__ float tile[4 * 34 * 36];   // 4896
    __shared__ float wlds[36 * 32];       // 1152, k-major
    __shared__ float As[32], Cs[32];
    const int tid = threadIdx.x;
    const float sf = get_sf(umax, 2);
    if (tid < 32) {
        int oc = tid;
        float bsf = wsf[oc] * sf;
        float bint = rintf(bias[oc] / bsf);
        float a = bsf * bns[oc];
        As[oc] = a;
        Cs[oc] = fmaf(bint, a, bnb[oc]);
    }
    for (int i = tid; i < 4896; i += 256) tile[i] = 0.f;
    for (int i = tid; i < 1152; i += 256) {
        int k = i >> 5, oc = i & 31;
        wlds[i] = wgl[oc * 36 + k];
    }
    __syncthreads();
    const float* ib = inp + (long)blockIdx.x * 4096;
    for (int i = tid; i < 4096; i += 256) {
        int ci = i >> 10, px = i & 1023;
        int iy = px >> 5, ix = px & 31;
        tile[ci * 1224 + (iy + 1) * 36 + (ix + 1)] = quantv(ib[i], sf);
    }
    __syncthreads();
    const int oc0 = (tid >> 6) * 8;
    const int pxq = tid & 63;
    const int h = pxq >> 2, c = pxq & 3;   // out row h, cols 4c..4c+3
    float acc[8][4];
    #pragma unroll
    for (int k = 0; k < 8; ++k)
        #pragma unroll
        for (int p = 0; p < 4; ++p) acc[k][p] = 0.f;
    #pragma unroll 1
    for (int ci = 0; ci < 4; ++ci) {
        #pragma unroll
        for (int ky = 0; ky < 3; ++ky) {
            const float* rp = tile + ci * 1224 + (2 * h + ky) * 36 + 8 * c;
            float wn[12];
            #pragma unroll
            for (int d = 0; d < 3; ++d) *(float4*)&wn[4 * d] = *(const float4*)&rp[4 * d];
            #pragma unroll
            for (int kx = 0; kx < 3; ++kx) {
                const float* wp = &wlds[(ci * 9 + ky * 3 + kx) * 32 + oc0];
                float4 wa = *(const float4*)&wp[0];
                float4 wb = *(const float4*)&wp[4];
                float wf[8] = {wa.x, wa.y, wa.z, wa.w, wb.x, wb.y, wb.z, wb.w};
                #pragma unroll
                for (int k = 0; k < 8; ++k)
                    #pragma unroll
                    for (int p = 0; p < 4; ++p)
                        acc[k][p] = fmaf(wn[2 * p + kx], wf[k], acc[k][p]);
            }
        }
    }
    float lmax = 0.f;
    float* ob = out + (long)blockIdx.x * 8192;
    #pragma unroll
    for (int k = 0; k < 8; ++k) {
        int oc = oc0 + k;
        float A = As[oc], C = Cs[oc];
        float4 r;
        float* rp = &r.x;
        #pragma unroll
        for (int p = 0; p < 4; ++p) {
            float y = fmaf(acc[k][p], A, C);
            rp[p] = y;
            lmax = fmaxf(lmax, fabsf(y));
        }
        *(float4*)&ob[oc * 256 + h * 16 + c * 4] = r;
    }
    block_max_atomic(lmax, mout);
}

// ---------------- conv3/conv4: 2 img/block, 4oc x 4px, K-phased LDS ----------------
template<int HIN, int S>
__global__ __attribute__((amdgpu_waves_per_eu(1, 4))) __launch_bounds__(256) void k_conv34b(
    const float* __restrict__ inp, const float* __restrict__ wi,
    const float* __restrict__ wsf, const float* __restrict__ bias,
    const float* __restrict__ bns, const float* __restrict__ bnb,
    const unsigned* __restrict__ umax, int slot, unsigned* __restrict__ mout,
    float* __restrict__ out) {
    constexpr int ROWS = HIN + 2;
    constexpr int RS   = (S == 2) ? 20 : 12;
    constexpr int TI   = 8 * ROWS * RS;
    constexpr int PIX  = HIN * HIN;
    constexpr int NELT = 2 * 8 * PIX;
    constexpr int WINW = (S == 2) ? 12 : 8;
    constexpr int ND   = (S == 2) ? 3 : 2;
    __shared__ float tile[2 * TI];
    __shared__ float wlds[72 * 36];
    __shared__ float As[32], Cs[32];
    const int tid  = threadIdx.x;
    const int imgl = tid >> 7;
    const int ocg  = (tid >> 4) & 7;
    const int pxq  = tid & 15;
    const int h = pxq >> 1, c = pxq & 1;
    const float sf = get_sf(umax, slot);
    if (tid < 32) {
        int oc = tid;
        float bsf = wsf[oc] * sf;
        float bint = rintf(bias[oc] / bsf);
        float a = bsf * bns[oc];
        As[oc] = a;
        Cs[oc] = fmaf(bint, a, bnb[oc]);
    }
    for (int i = tid; i < 2 * TI; i += 256) tile[i] = 0.f;
    float acc[16];
    #pragma unroll
    for (int i = 0; i < 16; ++i) acc[i] = 0.f;
    const float* ib = inp + (long)blockIdx.x * 2 * 32 * PIX;
    for (int ph = 0; ph < 4; ++ph) {
        __syncthreads();
        for (int i = tid; i < NELT; i += 256) {
            int im = i / (8 * PIX);
            int r  = i % (8 * PIX);
            int ci = r / PIX;
            int px = r % PIX;
            int iy = px / HIN, ix = px % HIN;
            tile[(im * 8 + ci) * (ROWS * RS) + (iy + 1) * RS + (ix + 1)] =
                quantv(ib[(long)(im * 32 + ph * 8 + ci) * PIX + px], sf);
        }
        for (int i = tid; i < 2304; i += 256) {
            int oc = i / 72, k = i - oc * 72;
            wlds[k * 36 + oc] = wi[oc * 288 + ph * 72 + k];
        }
        __syncthreads();
        const float* tb = tile + imgl * TI;
        #pragma unroll 2
        for (int ci = 0; ci < 8; ++ci) {
            float win[3][WINW];
            #pragma unroll
            for (int ky = 0; ky < 3; ++ky) {
                const float* rp = tb + ci * (ROWS * RS) + (S * h + ky) * RS + S * 4 * c;
                #pragma unroll
                for (int d = 0; d < ND; ++d)
                    *(float4*)&win[ky][4 * d] = *(const float4*)&rp[4 * d];
            }
            #pragma unroll
            for (int ky = 0; ky < 3; ++ky)
                #pragma unroll
                for (int kx = 0; kx < 3; ++kx) {
                    int j = ky * 3 + kx;
                    float4 wv = *(const float4*)&wlds[(ci * 9 + j) * 36 + ocg * 4];
                    float wvf[4] = {wv.x, wv.y, wv.z, wv.w};
                    #pragma unroll
                    for (int k = 0; k < 4; ++k)
                        #pragma unroll
                        for (int px = 0; px < 4; ++px)
                            acc[k * 4 + px] = fmaf(win[ky][S * px + kx], wvf[k], acc[k * 4 + px]);
                }
        }
    }
    float lmax = 0.f;
    long imgg = (long)blockIdx.x * 2 + imgl;
    #pragma unroll
    for (int k = 0; k < 4; ++k) {
        int oc = ocg * 4 + k;
        float A = As[oc], C = Cs[oc];
        float4 r;
        float* rp = &r.x;
        #pragma unroll
        for (int px = 0; px < 4; ++px) {
            float y = fmaf(acc[k * 4 + px], A, C);
            rp[px] = y;
            lmax = fmaxf(lmax, fabsf(y));
        }
        *(float4*)&out[(imgg * 32 + oc) * 64 + h * 8 + c * 4] = r;
    }
    block_max_atomic(lmax, mout);
}

// ---------------- linear 2048->10 per image ----------------
__global__ __launch_bounds__(256) void k_fc(
    const float* __restrict__ act, const float* __restrict__ wdi,
    const float* __restrict__ wsfd, const float* __restrict__ bd,
    const unsigned* __restrict__ umax, float* __restrict__ logits) {
    int b = blockIdx.x;
    float sf = get_sf(umax, 5);
    const float* ab = act + (long)b * 2048;
    float acc[10];
    #pragma unroll
    for (int c = 0; c < 10; ++c) acc[c] = 0.f;
    #pragma unroll
    for (int k = 0; k < 8; ++k) {
        int j = threadIdx.x + 256 * k;
        float q = quantv(ab[j], sf);
        #pragma unroll
        for (int c = 0; c < 10; ++c) acc[c] = fmaf(q, wdi[c * 2048 + j], acc[c]);
    }
    #pragma unroll
    for (int c = 0; c < 10; ++c)
        #pragma unroll
        for (int o = 32; o; o >>= 1) acc[c] += __shfl_down(acc[c], o, 64);
    __shared__ float red[4][10];
    int wid = threadIdx.x >> 6;
    if ((threadIdx.x & 63) == 0)
        #pragma unroll
        for (int c = 0; c < 10; ++c) red[wid][c] = acc[c];
    __syncthreads();
    if (threadIdx.x < 10) {
        int c = threadIdx.x;
        float s = red[0][c] + red[1][c] + red[2][c] + red[3][c];
        float bsf = wsfd[c] * sf;
        float bint = rintf(bd[c] / bsf);
        logits[b * 10 + c] = (s + bint) * bsf;
    }
}

// ---------------- softmax over batch axis (dim 0) ----------------
__global__ __launch_bounds__(256) void k_softmax(const float* __restrict__ logits, float* __restrict__ out) {
    int c = blockIdx.x;
    float v0 = logits[(threadIdx.x +   0) * 10 + c];
    float v1 = logits[(threadIdx.x + 256) * 10 + c];
    float v2 = logits[(threadIdx.x + 512) * 10 + c];
    float v3 = logits[(threadIdx.x + 768) * 10 + c];
    float mx = fmaxf(fmaxf(v0, v1), fmaxf(v2, v3));
    __shared__ float redm[4];
    __shared__ float reds[4];
    #pragma unroll
    for (int o = 32; o; o >>= 1) mx = fmaxf(mx, __shfl_down(mx, o, 64));
    if ((threadIdx.x & 63) == 0) redm[threadIdx.x >> 6] = mx;
    __syncthreads();
    mx = fmaxf(fmaxf(redm[0], redm[1]), fmaxf(redm[2], redm[3]));
    float e0 = expf(v0 - mx), e1 = expf(v1 - mx), e2 = expf(v2 - mx), e3 = expf(v3 - mx);
    float s = (e0 + e1) + (e2 + e3);
    #pragma unroll
    for (int o = 32; o; o >>= 1) s += __shfl_down(s, o, 64);
    if ((threadIdx.x & 63) == 0) reds[threadIdx.x >> 6] = s;
    __syncthreads();
    s = reds[0] + reds[1] + reds[2] + reds[3];
    out[(threadIdx.x +   0) * 10 + c] = e0 / s;
    out[(threadIdx.x + 256) * 10 + c] = e1 / s;
    out[(threadIdx.x + 512) * 10 + c] = e2 / s;
    out[(threadIdx.x + 768) * 10 + c] = e3 / s;
}

extern "C" void kernel_launch(void* const* d_in, const int* in_sizes, int n_in,
                              void* d_out, int out_size, void* d_ws, size_t ws_size,
                              hipStream_t stream) {
    (void)in_sizes; (void)n_in; (void)out_size; (void)ws_size;
    const float* x = (const float*)d_in[0];
    const float *w[5], *bia[5], *g[5], *bb[5], *m[5], *v[5];
    for (int i = 0; i < 5; ++i) {
        w[i]   = (const float*)d_in[1 + 6 * i + 0];
        bia[i] = (const float*)d_in[1 + 6 * i + 1];
        g[i]   = (const float*)d_in[1 + 6 * i + 2];
        bb[i]  = (const float*)d_in[1 + 6 * i + 3];
        m[i]   = (const float*)d_in[1 + 6 * i + 4];
        v[i]   = (const float*)d_in[1 + 6 * i + 5];
    }
    const float* wd = (const float*)d_in[31];
    const float* bd = (const float*)d_in[32];
    float* ws = (float*)d_ws;
    unsigned* umax = (unsigned*)ws;
    float* out = (float*)d_out;

    float* wsf0 = ws + OFF_WSF0; float* bns0 = ws + OFF_BNS0; float* bnb0 = ws + OFF_BNB0; float* w0i = ws + OFF_W0I;
    float* wsf1 = ws + OFF_WSF1; float* bns1 = ws + OFF_BNS1; float* bnb1 = ws + OFF_BNB1; float* w1i = ws + OFF_W1I;
    float* wsf2 = ws + OFF_WSF2; float* bns2 = ws + OFF_BNS2; float* bnb2 = ws + OFF_BNB2; float* w2i = ws + OFF_W2I;
    float* wsf3 = ws + OFF_WSF3; float* bns3 = ws + OFF_BNS3; float* bnb3 = ws + OFF_BNB3; float* w3i = ws + OFF_W3I;
    float* wsf4 = ws + OFF_WSF4; float* bns4 = ws + OFF_BNS4; float* bnb4 = ws + OFF_BNB4; float* w4i = ws + OFF_W4I;
    float* wsfd = ws + OFF_WSFD; float* wdi = ws + OFF_WDI;
    float* logits = ws + OFF_LOG;
    float* actA = ws + ACT_A_OFF;   // act2 / act4
    float* actB = ws + ACT_B_OFF;   // act1 / act3

    PrepAll pa;
    pa.umax = umax;
    const float* ww[6] = {w[0], w[1], w[2], w[3], w[4], wd};
    float* wsfp[6] = {wsf0, wsf1, wsf2, wsf3, wsf4, wsfd};
    float* wip[6]  = {w0i, w1i, w2i, w3i, w4i, wdi};
    float* bnsp[6] = {bns0, bns1, bns2, bns3, bns4, nullptr};
    float* bnbp[6] = {bnb0, bnb1, bnb2, bnb3, bnb4, nullptr};
    int Ks[6] = {27, 32, 36, 288, 288, 2048};
    for (int i = 0; i < 6; ++i) {
        pa.e[i].w = ww[i];
        pa.e[i].g = (i < 5) ? g[i] : nullptr;
        pa.e[i].bb = (i < 5) ? bb[i] : nullptr;
        pa.e[i].m = (i < 5) ? m[i] : nullptr;
        pa.e[i].v = (i < 5) ? v[i] : nullptr;
        pa.e[i].wsf = wsfp[i];
        pa.e[i].wint = wip[i];
        pa.e[i].bns = bnsp[i];
        pa.e[i].bnb = bnbp[i];
        pa.e[i].K = Ks[i];
        pa.e[i].has_bn = (i < 5) ? 1 : 0;
    }

    hipLaunchKernelGGL(k_prep_all, dim3(143), dim3(256), 0, stream, pa);
    hipLaunchKernelGGL(k_absmax, dim3(256), dim3(256), 0, stream,
                       (const float4*)x, 1024 * 3 * 32 * 32 / 4, umax + 0);
    hipLaunchKernelGGL(k_conv0maxN, dim3(2048), dim3(256), 0, stream,
                       x, w0i, wsf0, bia[0], bns0, bnb0, umax, umax + 1);
    hipLaunchKernelGGL(k_conv01n, dim3(512), dim3(256), 0, stream,
                       x, w0i, wsf0, bia[0], bns0, bnb0,
                       w1i, wsf1, bia[1], bns1, bnb1, umax, umax + 2, actB);
    hipLaunchKernelGGL(k_conv2c, dim3(1024), dim3(256), 0, stream,
                       actB, w2i, wsf2, bia[2], bns2, bnb2, umax, umax + 3, actA);
    hipLaunchKernelGGL((k_conv34b<16, 2>), dim3(512), dim3(256), 0, stream,
                       actA, w3i, wsf3, bia[3], bns3, bnb3, umax, 3, umax + 4, actB);
    hipLaunchKernelGGL((k_conv34b<8, 1>),  dim3(512), dim3(256), 0, stream,
                       actB, w4i, wsf4, bia[4], bns4, bnb4, umax, 4, umax + 5, actA);
    hipLaunchKernelGGL(k_fc, dim3(1024), dim3(256), 0, stream, actA, wdi, wsfd, bd, umax, logits);
    hipLaunchKernelGGL(k_softmax, dim3(10), dim3(256), 0, stream, logits, out);
}

// Round 11
// 192.889 us; speedup vs baseline: 2.0790x; 1.1989x over previous
//
#include <hip/hip_runtime.h>

#define DI __device__ __forceinline__

// ---------------- ws layout (float offsets) ----------------
// umax[6][64] buckets (uint32) at 0..384
constexpr int OFF_WSF0 = 384;
constexpr int OFF_BNS0 = 416;
constexpr int OFF_BNB0 = 448;
constexpr int OFF_W0I  = 480;    // 32*27 = 864
constexpr int OFF_WSF1 = 1344;
constexpr int OFF_BNS1 = 1348;
constexpr int OFF_BNB1 = 1352;
constexpr int OFF_W1I  = 1356;   // 128
constexpr int OFF_WSF2 = 1484;
constexpr int OFF_BNS2 = 1516;
constexpr int OFF_BNB2 = 1548;
constexpr int OFF_W2I  = 1580;   // 1152
constexpr int OFF_WSF3 = 2732;
constexpr int OFF_BNS3 = 2764;
constexpr int OFF_BNB3 = 2796;
constexpr int OFF_W3I  = 2828;   // 9216
constexpr int OFF_WSF4 = 12044;
constexpr int OFF_BNS4 = 12076;
constexpr int OFF_BNB4 = 12108;
constexpr int OFF_W4I  = 12140;  // 9216
constexpr int OFF_WSFD = 21356;  // 10
constexpr int OFF_WDI  = 21368;  // 20480
constexpr int OFF_LOG  = 41856;  // 10240
constexpr int OFF_ACT  = 52224;
constexpr long ACT_A_OFF = OFF_ACT;              // act2/act4
constexpr long ACT_B_OFF = OFF_ACT + 8388608L;   // act1/act3

// ---------------- helpers ----------------
DI float quantv(float x, float sf) {
    float q = rintf(x / sf);
    return fminf(fmaxf(q, -127.0f), 127.0f);
}
// reduce 64 buckets (float bit patterns of non-negative floats -> u32 max == float max)
DI float get_sf(const unsigned* umax, int slot) {
    const unsigned* p = umax + slot * 64;
    unsigned m = 0u;
    #pragma unroll
    for (int i = 0; i < 64; ++i) m = m > p[i] ? m : p[i];
    return fmaxf(__uint_as_float(m) / 127.0f, 1e-8f);
}
// block max -> one atomic into bucket blockIdx&63 (contention /64)
DI void block_max_atomic(float v, unsigned* dst) {
    __shared__ float redm_[4];
    #pragma unroll
    for (int o = 32; o; o >>= 1) v = fmaxf(v, __shfl_down(v, o, 64));
    int wid = threadIdx.x >> 6;
    if ((threadIdx.x & 63) == 0) redm_[wid] = v;
    __syncthreads();
    if (threadIdx.x == 0) {
        int nw = blockDim.x >> 6;
        float m = redm_[0];
        for (int i = 1; i < nw; ++i) m = fmaxf(m, redm_[i]);
        atomicMax(dst + (blockIdx.x & 63), __float_as_uint(m));
    }
}

// ---------------- prep: weight quant + BN fold ----------------
struct PrepEntry {
    const float *w, *g, *bb, *m, *v;
    float *wsf, *wint, *bns, *bnb;
    int K; int has_bn;
};
struct PrepAll { PrepEntry e[6]; unsigned* umax; };

__global__ __launch_bounds__(256) void k_prep_all(PrepAll pa) {
    int blk = blockIdx.x;
    if (blk == 142) {
        for (int i = threadIdx.x; i < 384; i += 256) pa.umax[i] = 0u;
        return;
    }
    int layer, oc;
    if      (blk < 32)  { layer = 0; oc = blk; }
    else if (blk < 36)  { layer = 1; oc = blk - 32; }
    else if (blk < 68)  { layer = 2; oc = blk - 36; }
    else if (blk < 100) { layer = 3; oc = blk - 68; }
    else if (blk < 132) { layer = 4; oc = blk - 100; }
    else                { layer = 5; oc = blk - 132; }
    PrepEntry a = pa.e[layer];
    const float* wr = a.w + (long)oc * a.K;
    float mx = 0.f;
    for (int i = threadIdx.x; i < a.K; i += 256) mx = fmaxf(mx, fabsf(wr[i]));
    __shared__ float red[4];
    __shared__ float s_sf;
    #pragma unroll
    for (int o = 32; o; o >>= 1) mx = fmaxf(mx, __shfl_down(mx, o, 64));
    if ((threadIdx.x & 63) == 0) red[threadIdx.x >> 6] = mx;
    __syncthreads();
    if (threadIdx.x == 0) {
        float t = fmaxf(fmaxf(red[0], red[1]), fmaxf(red[2], red[3]));
        t = fmaxf(t / 127.0f, 1e-8f);
        a.wsf[oc] = t; s_sf = t;
        if (a.has_bn) {
            float inv = a.g[oc] / sqrtf(a.v[oc] + 1e-5f);
            a.bns[oc] = inv;
            a.bnb[oc] = a.bb[oc] - a.m[oc] * inv;
        }
    }
    __syncthreads();
    float sf = s_sf;
    for (int i = threadIdx.x; i < a.K; i += 256) a.wint[(long)oc * a.K + i] = rintf(wr[i] / sf);
}

__global__ __launch_bounds__(256) void k_absmax(const float4* __restrict__ x, int n4, unsigned* dst) {
    float m = 0.f;
    for (int i = blockIdx.x * blockDim.x + threadIdx.x; i < n4; i += gridDim.x * blockDim.x) {
        float4 t = x[i];
        m = fmaxf(m, fmaxf(fmaxf(fabsf(t.x), fabsf(t.y)), fmaxf(fabsf(t.z), fabsf(t.w))));
    }
    block_max_atomic(m, dst);
}

// ---------------- conv0 pass 1: max only. grid 2048 = (image, row-half) ----------------
// thread = 4 oc x 16 px. LDS tile[3][18][36], weights k-major [27][32].
__global__ __launch_bounds__(256) void k_conv0maxN(
    const float* __restrict__ x, const float* __restrict__ w0i,
    const float* __restrict__ wsf0, const float* __restrict__ bias0,
    const float* __restrict__ bns0, const float* __restrict__ bnb0,
    const unsigned* __restrict__ umax, unsigned* __restrict__ mout) {
    __shared__ float tile[3 * 18 * 36];   // 1944
    __shared__ float wlds[27 * 32];       // 864
    __shared__ float As[32], Cs[32];
    const int b  = blockIdx.x >> 1;
    const int r0 = (blockIdx.x & 1) * 16;
    const int tid = threadIdx.x;
    const float sfx = get_sf(umax, 0);
    if (tid < 32) {
        int oc = tid;
        float bsf = wsf0[oc] * sfx;
        float bint = rintf(bias0[oc] / bsf);
        float a = bsf * bns0[oc];
        As[oc] = a;
        Cs[oc] = fmaf(bint, a, bnb0[oc]);
    }
    for (int i = tid; i < 1944; i += 256) tile[i] = 0.f;
    for (int i = tid; i < 864; i += 256) {
        int k = i >> 5, oc = i & 31;
        wlds[i] = w0i[oc * 27 + k];
    }
    __syncthreads();
    const float* xb = x + (long)b * 3072;
    for (int i = tid; i < 1728; i += 256) {          // 3 ci * 18 rows * 32 cols
        int ci = i / 576, rem = i - ci * 576;
        int rr = rem >> 5, cc = rem & 31;
        int gr = r0 - 1 + rr;
        if ((unsigned)gr < 32u)
            tile[ci * 648 + rr * 36 + cc + 1] = quantv(xb[ci * 1024 + gr * 32 + cc], sfx);
    }
    __syncthreads();
    const int oc0  = (tid >> 5) * 4;       // 8 oc-quads
    const int pxg  = tid & 31;
    const int row  = pxg >> 1;             // 0..15 (output row r0+row)
    const int wcol = (pxg & 1) * 16;       // output col base
    float acc[4][16];
    #pragma unroll
    for (int o = 0; o < 4; ++o)
        #pragma unroll
        for (int p = 0; p < 16; ++p) acc[o][p] = 0.f;
    #pragma unroll 1
    for (int kk = 0; kk < 9; ++kk) {       // kk = ci*3 + ky
        int ci = kk / 3, ky = kk - ci * 3;
        const float* rp = tile + ci * 648 + (row + ky) * 36 + wcol;
        float wn[20];
        #pragma unroll
        for (int d = 0; d < 5; ++d) *(float4*)&wn[4 * d] = *(const float4*)&rp[4 * d];
        #pragma unroll
        for (int kx = 0; kx < 3; ++kx) {
            float4 wv = *(const float4*)&wlds[(kk * 3 + kx) * 32 + oc0];
            const float* wf = &wv.x;
            #pragma unroll
            for (int o = 0; o < 4; ++o)
                #pragma unroll
                for (int p = 0; p < 16; ++p)
                    acc[o][p] = fmaf(wn[p + kx], wf[o], acc[o][p]);
        }
    }
    float lmax = 0.f;
    #pragma unroll
    for (int o = 0; o < 4; ++o) {
        float A = As[oc0 + o], C = Cs[oc0 + o];
        #pragma unroll
        for (int p = 0; p < 16; ++p)
            lmax = fmaxf(lmax, fabsf(fmaf(acc[o][p], A, C)));
    }
    block_max_atomic(lmax, mout);
}

// ---------------- conv0 pass 2 + fused 1x1 conv1. grid 512 = B/2 ----------------
// thread = 8 px, all 32 oc sequential; window cached in 108 registers.
__global__ __launch_bounds__(256) void k_conv01n(
    const float* __restrict__ x, const float* __restrict__ w0i,
    const float* __restrict__ wsf0, const float* __restrict__ bias0,
    const float* __restrict__ bns0, const float* __restrict__ bnb0,
    const float* __restrict__ w1i,
    const float* __restrict__ wsf1, const float* __restrict__ bias1,
    const float* __restrict__ bns1, const float* __restrict__ bnb1,
    const unsigned* __restrict__ umax, unsigned* __restrict__ mout,
    float* __restrict__ out) {
    __shared__ float tile[2 * 3672];      // [img][3][34][36]
    __shared__ float wls0[896];           // [32][28]
    __shared__ float wls1[128];           // [32][4]
    __shared__ float As[32], Cs[32];
    __shared__ float A1s[4], C1s[4];
    const int tid = threadIdx.x;
    const long b2 = (long)blockIdx.x * 2;
    const float sfx = get_sf(umax, 0);
    const float sf1 = get_sf(umax, 1);
    if (tid < 32) {
        int oc = tid;
        float bsf = wsf0[oc] * sfx;
        float bint = rintf(bias0[oc] / bsf);
        float a = bsf * bns0[oc];
        As[oc] = a;
        Cs[oc] = fmaf(bint, a, bnb0[oc]);
    }
    if (tid >= 64 && tid < 68) {
        int oc = tid - 64;
        float bsf = wsf1[oc] * sf1;
        float bint = rintf(bias1[oc] / bsf);
        float a = bsf * bns1[oc];
        A1s[oc] = a;
        C1s[oc] = fmaf(bint, a, bnb1[oc]);
    }
    for (int i = tid; i < 2 * 3672; i += 256) tile[i] = 0.f;
    for (int i = tid; i < 864; i += 256) {
        int oc = i / 27, k = i - oc * 27;
        wls0[oc * 28 + k] = w0i[i];
    }
    if (tid < 128) {
        int o1 = tid >> 5, oc = tid & 31;
        wls1[oc * 4 + o1] = w1i[tid];
    }
    __syncthreads();
    for (int i = tid; i < 6144; i += 256) {
        int img = i / 3072, rem = i - img * 3072;
        int ci = rem >> 10, px = rem & 1023;
        int iy = px >> 5, ix = px & 31;
        tile[img * 3672 + ci * 1224 + (iy + 1) * 36 + (ix + 1)] =
            quantv(x[(b2 + img) * 3072 + rem], sfx);
    }
    __syncthreads();
    const int img = tid >> 7;
    const int pt  = tid & 127;
    const int h   = pt >> 2;          // out row 0..31
    const int w0  = (pt & 3) * 8;     // out col base
    float win[3][3][12];
    #pragma unroll
    for (int ci = 0; ci < 3; ++ci)
        #pragma unroll
        for (int ky = 0; ky < 3; ++ky) {
            const float* rp = tile + img * 3672 + ci * 1224 + (h + ky) * 36 + w0;
            #pragma unroll
            for (int d = 0; d < 3; ++d)
                *(float4*)&win[ci][ky][4 * d] = *(const float4*)&rp[4 * d];
        }
    float acc1[4][8];
    #pragma unroll
    for (int o = 0; o < 4; ++o)
        #pragma unroll
        for (int p = 0; p < 8; ++p) acc1[o][p] = 0.f;
    #pragma unroll 1
    for (int oc = 0; oc < 32; ++oc) {
        float wreg[28];
        const float4* wp4 = (const float4*)&wls0[oc * 28];
        #pragma unroll
        for (int d = 0; d < 7; ++d) *(float4*)&wreg[4 * d] = wp4[d];
        float acc0[8];
        #pragma unroll
        for (int p = 0; p < 8; ++p) acc0[p] = 0.f;
        #pragma unroll
        for (int ci = 0; ci < 3; ++ci)
            #pragma unroll
            for (int ky = 0; ky < 3; ++ky)
                #pragma unroll
                for (int kx = 0; kx < 3; ++kx) {
                    float wv = wreg[ci * 9 + ky * 3 + kx];
                    #pragma unroll
                    for (int p = 0; p < 8; ++p)
                        acc0[p] = fmaf(win[ci][ky][p + kx], wv, acc0[p]);
                }
        float A = As[oc], C = Cs[oc];
        float4 w1v = *(const float4*)&wls1[oc * 4];
        const float* w1f = &w1v.x;
        #pragma unroll
        for (int p = 0; p < 8; ++p) {
            float q = quantv(fmaf(acc0[p], A, C), sf1);
            #pragma unroll
            for (int o = 0; o < 4; ++o)
                acc1[o][p] = fmaf(q, w1f[o], acc1[o][p]);
        }
    }
    float lmax = 0.f;
    float* ob = out + (b2 + img) * 4096;
    #pragma unroll
    for (int o = 0; o < 4; ++o) {
        float A = A1s[o], C = C1s[o];
        float r[8];
        #pragma unroll
        for (int p = 0; p < 8; ++p) {
            float y = fmaf(acc1[o][p], A, C);
            r[p] = y;
            lmax = fmaxf(lmax, fabsf(y));
        }
        *(float4*)&ob[o * 1024 + h * 32 + w0]     = *(float4*)&r[0];
        *(float4*)&ob[o * 1024 + h * 32 + w0 + 4] = *(float4*)&r[4];
    }
    block_max_atomic(lmax, mout);
}

// ---------------- conv2 (4->32, 3x3, s2): thread = 8 oc x 4 px, weights k-major LDS ----------------
__global__ __launch_bounds__(256) void k_conv2c(
    const float* __restrict__ inp, const float* __restrict__ wgl,
    const float* __restrict__ wsf, const float* __restrict__ bias,
    const float* __restrict__ bns, const float* __restrict__ bnb,
    const unsigned* __restrict__ umax, unsigned* __restrict__ mout,
    float* __restrict__ out) {
    __shared__ float tile[4 * 34 * 36];   // 4896
    __shared__ float wlds[36 * 32];       // 1152, k-major
    __shared__ float As[32], Cs[32];
    const int tid = threadIdx.x;
    const float sf = get_sf(umax, 2);
    if (tid < 32) {
        int oc = tid;
        float bsf = wsf[oc] * sf;
        float bint = rintf(bias[oc] / bsf);
        float a = bsf * bns[oc];
        As[oc] = a;
        Cs[oc] = fmaf(bint, a, bnb[oc]);
    }
    for (int i = tid; i < 4896; i += 256) tile[i] = 0.f;
    for (int i = tid; i < 1152; i += 256) {
        int k = i >> 5, oc = i & 31;
        wlds[i] = wgl[oc * 36 + k];
    }
    __syncthreads();
    const float* ib = inp + (long)blockIdx.x * 4096;
    for (int i = tid; i < 4096; i += 256) {
        int ci = i >> 10, px = i & 1023;
        int iy = px >> 5, ix = px & 31;
        tile[ci * 1224 + (iy + 1) * 36 + (ix + 1)] = quantv(ib[i], sf);
    }
    __syncthreads();
    const int oc0 = (tid >> 6) * 8;
    const int pxq = tid & 63;
    const int h = pxq >> 2, c = pxq & 3;   // out row h, cols 4c..4c+3
    float acc[8][4];
    #pragma unroll
    for (int k = 0; k < 8; ++k)
        #pragma unroll
        for (int p = 0; p < 4; ++p) acc[k][p] = 0.f;
    #pragma unroll 1
    for (int ci = 0; ci < 4; ++ci) {
        #pragma unroll
        for (int ky = 0; ky < 3; ++ky) {
            const float* rp = tile + ci * 1224 + (2 * h + ky) * 36 + 8 * c;
            float wn[12];
            #pragma unroll
            for (int d = 0; d < 3; ++d) *(float4*)&wn[4 * d] = *(const float4*)&rp[4 * d];
            #pragma unroll
            for (int kx = 0; kx < 3; ++kx) {
                const float* wp = &wlds[(ci * 9 + ky * 3 + kx) * 32 + oc0];
                float4 wa = *(const float4*)&wp[0];
                float4 wb = *(const float4*)&wp[4];
                float wf[8] = {wa.x, wa.y, wa.z, wa.w, wb.x, wb.y, wb.z, wb.w};
                #pragma unroll
                for (int k = 0; k < 8; ++k)
                    #pragma unroll
                    for (int p = 0; p < 4; ++p)
                        acc[k][p] = fmaf(wn[2 * p + kx], wf[k], acc[k][p]);
            }
        }
    }
    float lmax = 0.f;
    float* ob = out + (long)blockIdx.x * 8192;
    #pragma unroll
    for (int k = 0; k < 8; ++k) {
        int oc = oc0 + k;
        float A = As[oc], C = Cs[oc];
        float4 r;
        float* rp = &r.x;
        #pragma unroll
        for (int p = 0; p < 4; ++p) {
            float y = fmaf(acc[k][p], A, C);
            rp[p] = y;
            lmax = fmaxf(lmax, fabsf(y));
        }
        *(float4*)&ob[oc * 256 + h * 16 + c * 4] = r;
    }
    block_max_atomic(lmax, mout);
}

// ---------------- conv3/conv4: 2 img/block, 4oc x 4px, K-phased LDS ----------------
template<int HIN, int S>
__global__ __launch_bounds__(256) void k_conv34b(
    const float* __restrict__ inp, const float* __restrict__ wi,
    const float* __restrict__ wsf, const float* __restrict__ bias,
    const float* __restrict__ bns, const float* __restrict__ bnb,
    const unsigned* __restrict__ umax, int slot, unsigned* __restrict__ mout,
    float* __restrict__ out) {
    constexpr int ROWS = HIN + 2;
    constexpr int RS   = (S == 2) ? 20 : 12;
    constexpr int TI   = 8 * ROWS * RS;
    constexpr int PIX  = HIN * HIN;
    constexpr int NELT = 2 * 8 * PIX;
    constexpr int WINW = (S == 2) ? 12 : 8;
    constexpr int ND   = (S == 2) ? 3 : 2;
    __shared__ float tile[2 * TI];
    __shared__ float wlds[72 * 36];
    __shared__ float As[32], Cs[32];
    const int tid  = threadIdx.x;
    const int imgl = tid >> 7;
    const int ocg  = (tid >> 4) & 7;
    const int pxq  = tid & 15;
    const int h = pxq >> 1, c = pxq & 1;
    const float sf = get_sf(umax, slot);
    if (tid < 32) {
        int oc = tid;
        float bsf = wsf[oc] * sf;
        float bint = rintf(bias[oc] / bsf);
        float a = bsf * bns[oc];
        As[oc] = a;
        Cs[oc] = fmaf(bint, a, bnb[oc]);
    }
    for (int i = tid; i < 2 * TI; i += 256) tile[i] = 0.f;
    float acc[16];
    #pragma unroll
    for (int i = 0; i < 16; ++i) acc[i] = 0.f;
    const float* ib = inp + (long)blockIdx.x * 2 * 32 * PIX;
    for (int ph = 0; ph < 4; ++ph) {
        __syncthreads();
        for (int i = tid; i < NELT; i += 256) {
            int im = i / (8 * PIX);
            int r  = i % (8 * PIX);
            int ci = r / PIX;
            int px = r % PIX;
            int iy = px / HIN, ix = px % HIN;
            tile[(im * 8 + ci) * (ROWS * RS) + (iy + 1) * RS + (ix + 1)] =
                quantv(ib[(long)(im * 32 + ph * 8 + ci) * PIX + px], sf);
        }
        for (int i = tid; i < 2304; i += 256) {
            int oc = i / 72, k = i - oc * 72;
            wlds[k * 36 + oc] = wi[oc * 288 + ph * 72 + k];
        }
        __syncthreads();
        const float* tb = tile + imgl * TI;
        #pragma unroll 2
        for (int ci = 0; ci < 8; ++ci) {
            float win[3][WINW];
            #pragma unroll
            for (int ky = 0; ky < 3; ++ky) {
                const float* rp = tb + ci * (ROWS * RS) + (S * h + ky) * RS + S * 4 * c;
                #pragma unroll
                for (int d = 0; d < ND; ++d)
                    *(float4*)&win[ky][4 * d] = *(const float4*)&rp[4 * d];
            }
            #pragma unroll
            for (int ky = 0; ky < 3; ++ky)
                #pragma unroll
                for (int kx = 0; kx < 3; ++kx) {
                    int j = ky * 3 + kx;
                    float4 wv = *(const float4*)&wlds[(ci * 9 + j) * 36 + ocg * 4];
                    float wvf[4] = {wv.x, wv.y, wv.z, wv.w};
                    #pragma unroll
                    for (int k = 0; k < 4; ++k)
                        #pragma unroll
                        for (int px = 0; px < 4; ++px)
                            acc[k * 4 + px] = fmaf(win[ky][S * px + kx], wvf[k], acc[k * 4 + px]);
                }
        }
    }
    float lmax = 0.f;
    long imgg = (long)blockIdx.x * 2 + imgl;
    #pragma unroll
    for (int k = 0; k < 4; ++k) {
        int oc = ocg * 4 + k;
        float A = As[oc], C = Cs[oc];
        float4 r;
        float* rp = &r.x;
        #pragma unroll
        for (int px = 0; px < 4; ++px) {
            float y = fmaf(acc[k * 4 + px], A, C);
            rp[px] = y;
            lmax = fmaxf(lmax, fabsf(y));
        }
        *(float4*)&out[(imgg * 32 + oc) * 64 + h * 8 + c * 4] = r;
    }
    block_max_atomic(lmax, mout);
}

// ---------------- linear 2048->10 per image ----------------
__global__ __launch_bounds__(256) void k_fc(
    const float* __restrict__ act, const float* __restrict__ wdi,
    const float* __restrict__ wsfd, const float* __restrict__ bd,
    const unsigned* __restrict__ umax, float* __restrict__ logits) {
    int b = blockIdx.x;
    float sf = get_sf(umax, 5);
    const float* ab = act + (long)b * 2048;
    float acc[10];
    #pragma unroll
    for (int c = 0; c < 10; ++c) acc[c] = 0.f;
    #pragma unroll
    for (int k = 0; k < 8; ++k) {
        int j = threadIdx.x + 256 * k;
        float q = quantv(ab[j], sf);
        #pragma unroll
        for (int c = 0; c < 10; ++c) acc[c] = fmaf(q, wdi[c * 2048 + j], acc[c]);
    }
    #pragma unroll
    for (int c = 0; c < 10; ++c)
        #pragma unroll
        for (int o = 32; o; o >>= 1) acc[c] += __shfl_down(acc[c], o, 64);
    __shared__ float red[4][10];
    int wid = threadIdx.x >> 6;
    if ((threadIdx.x & 63) == 0)
        #pragma unroll
        for (int c = 0; c < 10; ++c) red[wid][c] = acc[c];
    __syncthreads();
    if (threadIdx.x < 10) {
        int c = threadIdx.x;
        float s = red[0][c] + red[1][c] + red[2][c] + red[3][c];
        float bsf = wsfd[c] * sf;
        float bint = rintf(bd[c] / bsf);
        logits[b * 10 + c] = (s + bint) * bsf;
    }
}

// ---------------- softmax over batch axis (dim 0) ----------------
__global__ __launch_bounds__(256) void k_softmax(const float* __restrict__ logits, float* __restrict__ out) {
    int c = blockIdx.x;
    float v0 = logits[(threadIdx.x +   0) * 10 + c];
    float v1 = logits[(threadIdx.x + 256) * 10 + c];
    float v2 = logits[(threadIdx.x + 512) * 10 + c];
    float v3 = logits[(threadIdx.x + 768) * 10 + c];
    float mx = fmaxf(fmaxf(v0, v1), fmaxf(v2, v3));
    __shared__ float redm[4];
    __shared__ float reds[4];
    #pragma unroll
    for (int o = 32; o; o >>= 1) mx = fmaxf(mx, __shfl_down(mx, o, 64));
    if ((threadIdx.x & 63) == 0) redm[threadIdx.x >> 6] = mx;
    __syncthreads();
    mx = fmaxf(fmaxf(redm[0], redm[1]), fmaxf(redm[2], redm[3]));
    float e0 = expf(v0 - mx), e1 = expf(v1 - mx), e2 = expf(v2 - mx), e3 = expf(v3 - mx);
    float s = (e0 + e1) + (e2 + e3);
    #pragma unroll
    for (int o = 32; o; o >>= 1) s += __shfl_down(s, o, 64);
    if ((threadIdx.x & 63) == 0) reds[threadIdx.x >> 6] = s;
    __syncthreads();
    s = reds[0] + reds[1] + reds[2] + reds[3];
    out[(threadIdx.x +   0) * 10 + c] = e0 / s;
    out[(threadIdx.x + 256) * 10 + c] = e1 / s;
    out[(threadIdx.x + 512) * 10 + c] = e2 / s;
    out[(threadIdx.x + 768) * 10 + c] = e3 / s;
}

extern "C" void kernel_launch(void* const* d_in, const int* in_sizes, int n_in,
                              void* d_out, int out_size, void* d_ws, size_t ws_size,
                              hipStream_t stream) {
    (void)in_sizes; (void)n_in; (void)out_size; (void)ws_size;
    const float* x = (const float*)d_in[0];
    const float *w[5], *bia[5], *g[5], *bb[5], *m[5], *v[5];
    for (int i = 0; i < 5; ++i) {
        w[i]   = (const float*)d_in[1 + 6 * i + 0];
        bia[i] = (const float*)d_in[1 + 6 * i + 1];
        g[i]   = (const float*)d_in[1 + 6 * i + 2];
        bb[i]  = (const float*)d_in[1 + 6 * i + 3];
        m[i]   = (const float*)d_in[1 + 6 * i + 4];
        v[i]   = (const float*)d_in[1 + 6 * i + 5];
    }
    const float* wd = (const float*)d_in[31];
    const float* bd = (const float*)d_in[32];
    float* ws = (float*)d_ws;
    unsigned* umax = (unsigned*)ws;   // [6][64] buckets
    float* out = (float*)d_out;

    float* wsf0 = ws + OFF_WSF0; float* bns0 = ws + OFF_BNS0; float* bnb0 = ws + OFF_BNB0; float* w0i = ws + OFF_W0I;
    float* wsf1 = ws + OFF_WSF1; float* bns1 = ws + OFF_BNS1; float* bnb1 = ws + OFF_BNB1; float* w1i = ws + OFF_W1I;
    float* wsf2 = ws + OFF_WSF2; float* bns2 = ws + OFF_BNS2; float* bnb2 = ws + OFF_BNB2; float* w2i = ws + OFF_W2I;
    float* wsf3 = ws + OFF_WSF3; float* bns3 = ws + OFF_BNS3; float* bnb3 = ws + OFF_BNB3; float* w3i = ws + OFF_W3I;
    float* wsf4 = ws + OFF_WSF4; float* bns4 = ws + OFF_BNS4; float* bnb4 = ws + OFF_BNB4; float* w4i = ws + OFF_W4I;
    float* wsfd = ws + OFF_WSFD; float* wdi = ws + OFF_WDI;
    float* logits = ws + OFF_LOG;
    float* actA = ws + ACT_A_OFF;   // act2 / act4
    float* actB = ws + ACT_B_OFF;   // act1 / act3

    PrepAll pa;
    pa.umax = umax;
    const float* ww[6] = {w[0], w[1], w[2], w[3], w[4], wd};
    float* wsfp[6] = {wsf0, wsf1, wsf2, wsf3, wsf4, wsfd};
    float* wip[6]  = {w0i, w1i, w2i, w3i, w4i, wdi};
    float* bnsp[6] = {bns0, bns1, bns2, bns3, bns4, nullptr};
    float* bnbp[6] = {bnb0, bnb1, bnb2, bnb3, bnb4, nullptr};
    int Ks[6] = {27, 32, 36, 288, 288, 2048};
    for (int i = 0; i < 6; ++i) {
        pa.e[i].w = ww[i];
        pa.e[i].g = (i < 5) ? g[i] : nullptr;
        pa.e[i].bb = (i < 5) ? bb[i] : nullptr;
        pa.e[i].m = (i < 5) ? m[i] : nullptr;
        pa.e[i].v = (i < 5) ? v[i] : nullptr;
        pa.e[i].wsf = wsfp[i];
        pa.e[i].wint = wip[i];
        pa.e[i].bns = bnsp[i];
        pa.e[i].bnb = bnbp[i];
        pa.e[i].K = Ks[i];
        pa.e[i].has_bn = (i < 5) ? 1 : 0;
    }

    hipLaunchKernelGGL(k_prep_all, dim3(143), dim3(256), 0, stream, pa);
    hipLaunchKernelGGL(k_absmax, dim3(256), dim3(256), 0, stream,
                       (const float4*)x, 1024 * 3 * 32 * 32 / 4, umax + 0 * 64);
    hipLaunchKernelGGL(k_conv0maxN, dim3(2048), dim3(256), 0, stream,
                       x, w0i, wsf0, bia[0], bns0, bnb0, umax, umax + 1 * 64);
    hipLaunchKernelGGL(k_conv01n, dim3(512), dim3(256), 0, stream,
                       x, w0i, wsf0, bia[0], bns0, bnb0,
                       w1i, wsf1, bia[1], bns1, bnb1, umax, umax + 2 * 64, actB);
    hipLaunchKernelGGL(k_conv2c, dim3(1024), dim3(256), 0, stream,
                       actB, w2i, wsf2, bia[2], bns2, bnb2, umax, umax + 3 * 64, actA);
    hipLaunchKernelGGL((k_conv34b<16, 2>), dim3(512), dim3(256), 0, stream,
                       actA, w3i, wsf3, bia[3], bns3, bnb3, umax, 3, umax + 4 * 64, actB);
    hipLaunchKernelGGL((k_conv34b<8, 1>),  dim3(512), dim3(256), 0, stream,
                       actB, w4i, wsf4, bia[4], bns4, bnb4, umax, 4, umax + 5 * 64, actA);
    hipLaunchKernelGGL(k_fc, dim3(1024), dim3(256), 0, stream, actA, wdi, wsfd, bd, umax, logits);
    hipLaunchKernelGGL(k_softmax, dim3(10), dim3(256), 0, stream, logits, out);
}

// Round 12
// 185.154 us; speedup vs baseline: 2.1659x; 1.0418x over previous
//
#include <hip/hip_runtime.h>

#define DI __device__ __forceinline__

// ---------------- ws layout (float offsets) ----------------
// umax[6][64] buckets (uint32) at 0..384
constexpr int OFF_WSF0 = 384;
constexpr int OFF_BNS0 = 416;
constexpr int OFF_BNB0 = 448;
constexpr int OFF_W0I  = 480;    // 32*27 = 864
constexpr int OFF_WSF1 = 1344;
constexpr int OFF_BNS1 = 1348;
constexpr int OFF_BNB1 = 1352;
constexpr int OFF_W1I  = 1356;   // 128
constexpr int OFF_WSF2 = 1484;
constexpr int OFF_BNS2 = 1516;
constexpr int OFF_BNB2 = 1548;
constexpr int OFF_W2I  = 1580;   // 1152
constexpr int OFF_WSF3 = 2732;
constexpr int OFF_BNS3 = 2764;
constexpr int OFF_BNB3 = 2796;
constexpr int OFF_W3I  = 2828;   // 9216
constexpr int OFF_WSF4 = 12044;
constexpr int OFF_BNS4 = 12076;
constexpr int OFF_BNB4 = 12108;
constexpr int OFF_W4I  = 12140;  // 9216
constexpr int OFF_WSFD = 21356;  // 10
constexpr int OFF_WDI  = 21368;  // 20480
constexpr int OFF_LOG  = 41856;  // 10240
constexpr int OFF_ACT  = 52224;
constexpr long ACT_A_OFF = OFF_ACT;              // act2/act4
constexpr long ACT_B_OFF = OFF_ACT + 8388608L;   // act1/act3

// ---------------- helpers ----------------
DI float quantv(float x, float sf) {
    float q = rintf(x / sf);
    return fminf(fmaxf(q, -127.0f), 127.0f);
}
// reduce 64 buckets (bit patterns of non-negative floats -> u32 max == float max)
DI float get_sf(const unsigned* umax, int slot) {
    const unsigned* p = umax + slot * 64;
    unsigned m = 0u;
    #pragma unroll
    for (int i = 0; i < 64; ++i) m = m > p[i] ? m : p[i];
    return fmaxf(__uint_as_float(m) / 127.0f, 1e-8f);
}
// block max -> one atomic into bucket blockIdx&63 (contention /64)
DI void block_max_atomic(float v, unsigned* dst) {
    __shared__ float redm_[4];
    #pragma unroll
    for (int o = 32; o; o >>= 1) v = fmaxf(v, __shfl_down(v, o, 64));
    int wid = threadIdx.x >> 6;
    if ((threadIdx.x & 63) == 0) redm_[wid] = v;
    __syncthreads();
    if (threadIdx.x == 0) {
        int nw = blockDim.x >> 6;
        float m = redm_[0];
        for (int i = 1; i < nw; ++i) m = fmaxf(m, redm_[i]);
        atomicMax(dst + (blockIdx.x & 63), __float_as_uint(m));
    }
}

// ---------------- prep: weight quant + BN fold ----------------
struct PrepEntry {
    const float *w, *g, *bb, *m, *v;
    float *wsf, *wint, *bns, *bnb;
    int K; int has_bn;
};
struct PrepAll { PrepEntry e[6]; unsigned* umax; };

__global__ __launch_bounds__(256) void k_prep_all(PrepAll pa) {
    int blk = blockIdx.x;
    if (blk == 142) {
        for (int i = threadIdx.x; i < 384; i += 256) pa.umax[i] = 0u;
        return;
    }
    int layer, oc;
    if      (blk < 32)  { layer = 0; oc = blk; }
    else if (blk < 36)  { layer = 1; oc = blk - 32; }
    else if (blk < 68)  { layer = 2; oc = blk - 36; }
    else if (blk < 100) { layer = 3; oc = blk - 68; }
    else if (blk < 132) { layer = 4; oc = blk - 100; }
    else                { layer = 5; oc = blk - 132; }
    PrepEntry a = pa.e[layer];
    const float* wr = a.w + (long)oc * a.K;
    float mx = 0.f;
    for (int i = threadIdx.x; i < a.K; i += 256) mx = fmaxf(mx, fabsf(wr[i]));
    __shared__ float red[4];
    __shared__ float s_sf;
    #pragma unroll
    for (int o = 32; o; o >>= 1) mx = fmaxf(mx, __shfl_down(mx, o, 64));
    if ((threadIdx.x & 63) == 0) red[threadIdx.x >> 6] = mx;
    __syncthreads();
    if (threadIdx.x == 0) {
        float t = fmaxf(fmaxf(red[0], red[1]), fmaxf(red[2], red[3]));
        t = fmaxf(t / 127.0f, 1e-8f);
        a.wsf[oc] = t; s_sf = t;
        if (a.has_bn) {
            float inv = a.g[oc] / sqrtf(a.v[oc] + 1e-5f);
            a.bns[oc] = inv;
            a.bnb[oc] = a.bb[oc] - a.m[oc] * inv;
        }
    }
    __syncthreads();
    float sf = s_sf;
    for (int i = threadIdx.x; i < a.K; i += 256) a.wint[(long)oc * a.K + i] = rintf(wr[i] / sf);
}

__global__ __launch_bounds__(256) void k_absmax(const float4* __restrict__ x, int n4, unsigned* dst) {
    float m = 0.f;
    for (int i = blockIdx.x * blockDim.x + threadIdx.x; i < n4; i += gridDim.x * blockDim.x) {
        float4 t = x[i];
        m = fmaxf(m, fmaxf(fmaxf(fabsf(t.x), fabsf(t.y)), fmaxf(fabsf(t.z), fabsf(t.w))));
    }
    block_max_atomic(m, dst);
}

// ---------------- conv0 pass 1: max only. grid 2048 = (image, row-half) ----------------
// thread = 4 oc x 16 px. LDS tile[3][18][36], weights k-major [27][32].
__global__ __launch_bounds__(256) void k_conv0maxN(
    const float* __restrict__ x, const float* __restrict__ w0i,
    const float* __restrict__ wsf0, const float* __restrict__ bias0,
    const float* __restrict__ bns0, const float* __restrict__ bnb0,
    const unsigned* __restrict__ umax, unsigned* __restrict__ mout) {
    __shared__ float tile[3 * 18 * 36];   // 1944
    __shared__ float wlds[27 * 32];       // 864
    __shared__ float As[32], Cs[32];
    const int b  = blockIdx.x >> 1;
    const int r0 = (blockIdx.x & 1) * 16;
    const int tid = threadIdx.x;
    const float sfx = get_sf(umax, 0);
    if (tid < 32) {
        int oc = tid;
        float bsf = wsf0[oc] * sfx;
        float bint = rintf(bias0[oc] / bsf);
        float a = bsf * bns0[oc];
        As[oc] = a;
        Cs[oc] = fmaf(bint, a, bnb0[oc]);
    }
    for (int i = tid; i < 1944; i += 256) tile[i] = 0.f;
    for (int i = tid; i < 864; i += 256) {
        int k = i >> 5, oc = i & 31;
        wlds[i] = w0i[oc * 27 + k];
    }
    __syncthreads();
    const float* xb = x + (long)b * 3072;
    for (int i = tid; i < 1728; i += 256) {          // 3 ci * 18 rows * 32 cols
        int ci = i / 576, rem = i - ci * 576;
        int rr = rem >> 5, cc = rem & 31;
        int gr = r0 - 1 + rr;
        if ((unsigned)gr < 32u)
            tile[ci * 648 + rr * 36 + cc + 1] = quantv(xb[ci * 1024 + gr * 32 + cc], sfx);
    }
    __syncthreads();
    const int oc0  = (tid >> 5) * 4;       // 8 oc-quads
    const int pxg  = tid & 31;
    const int row  = pxg >> 1;             // 0..15 (output row r0+row)
    const int wcol = (pxg & 1) * 16;       // output col base
    float acc[4][16];
    #pragma unroll
    for (int o = 0; o < 4; ++o)
        #pragma unroll
        for (int p = 0; p < 16; ++p) acc[o][p] = 0.f;
    #pragma unroll 1
    for (int kk = 0; kk < 9; ++kk) {       // kk = ci*3 + ky
        int ci = kk / 3, ky = kk - ci * 3;
        const float* rp = tile + ci * 648 + (row + ky) * 36 + wcol;
        float wn[20];
        #pragma unroll
        for (int d = 0; d < 5; ++d) *(float4*)&wn[4 * d] = *(const float4*)&rp[4 * d];
        #pragma unroll
        for (int kx = 0; kx < 3; ++kx) {
            float4 wv = *(const float4*)&wlds[(kk * 3 + kx) * 32 + oc0];
            const float* wf = &wv.x;
            #pragma unroll
            for (int o = 0; o < 4; ++o)
                #pragma unroll
                for (int p = 0; p < 16; ++p)
                    acc[o][p] = fmaf(wn[p + kx], wf[o], acc[o][p]);
        }
    }
    float lmax = 0.f;
    #pragma unroll
    for (int o = 0; o < 4; ++o) {
        float A = As[oc0 + o], C = Cs[oc0 + o];
        #pragma unroll
        for (int p = 0; p < 16; ++p)
            lmax = fmaxf(lmax, fabsf(fmaf(acc[o][p], A, C)));
    }
    block_max_atomic(lmax, mout);
}

// ---------------- conv0 pass 2 + fused 1x1 conv1. grid 2048 = (image, 16-row band) ----------------
// thread = 2 px, all 32 oc sequential; window in 36 regs. 8 blocks/CU.
__global__ __launch_bounds__(256) void k_conv01n(
    const float* __restrict__ x, const float* __restrict__ w0i,
    const float* __restrict__ wsf0, const float* __restrict__ bias0,
    const float* __restrict__ bns0, const float* __restrict__ bnb0,
    const float* __restrict__ w1i,
    const float* __restrict__ wsf1, const float* __restrict__ bias1,
    const float* __restrict__ bns1, const float* __restrict__ bnb1,
    const unsigned* __restrict__ umax, unsigned* __restrict__ mout,
    float* __restrict__ out) {
    __shared__ float tile[1944];   // [3][18][36]
    __shared__ float wls0[896];    // [32][28]
    __shared__ float wls1[128];    // [32][4] oc-major
    __shared__ float As[32], Cs[32];
    __shared__ float A1s[4], C1s[4];
    const int b  = blockIdx.x >> 1;
    const int r0 = (blockIdx.x & 1) * 16;
    const int tid = threadIdx.x;
    const float sfx = get_sf(umax, 0);
    const float sf1 = get_sf(umax, 1);
    if (tid < 32) {
        int oc = tid;
        float bsf = wsf0[oc] * sfx;
        float bint = rintf(bias0[oc] / bsf);
        float a = bsf * bns0[oc];
        As[oc] = a;
        Cs[oc] = fmaf(bint, a, bnb0[oc]);
    }
    if (tid >= 64 && tid < 68) {
        int oc = tid - 64;
        float bsf = wsf1[oc] * sf1;
        float bint = rintf(bias1[oc] / bsf);
        float a = bsf * bns1[oc];
        A1s[oc] = a;
        C1s[oc] = fmaf(bint, a, bnb1[oc]);
    }
    for (int i = tid; i < 1944; i += 256) tile[i] = 0.f;
    for (int i = tid; i < 864; i += 256) {
        int oc = i / 27, k = i - oc * 27;
        wls0[oc * 28 + k] = w0i[i];
    }
    if (tid >= 128 && tid < 256) {
        int j = tid - 128;
        wls1[(j & 31) * 4 + (j >> 5)] = w1i[j];
    }
    __syncthreads();
    const float* xb = x + (long)b * 3072;
    for (int i = tid; i < 1728; i += 256) {
        int ci = i / 576, rem = i - ci * 576;
        int rr = rem >> 5, cc = rem & 31;
        int gr = r0 - 1 + rr;
        if ((unsigned)gr < 32u)
            tile[ci * 648 + rr * 36 + cc + 1] = quantv(xb[ci * 1024 + gr * 32 + cc], sfx);
    }
    __syncthreads();
    const int h   = tid >> 4;          // 0..15 (local out row)
    const int w0c = (tid & 15) * 2;    // 0..30 (out col base)
    float win[3][3][4];
    #pragma unroll
    for (int ci = 0; ci < 3; ++ci)
        #pragma unroll
        for (int ky = 0; ky < 3; ++ky) {
            const int base = ci * 648 + (h + ky) * 36 + w0c;
            #pragma unroll
            for (int d = 0; d < 4; ++d) win[ci][ky][d] = tile[base + d];
        }
    float acc1[4][2];
    #pragma unroll
    for (int o = 0; o < 4; ++o) { acc1[o][0] = 0.f; acc1[o][1] = 0.f; }
    #pragma unroll 1
    for (int oc = 0; oc < 32; ++oc) {
        float wreg[28];
        const float4* wp4 = (const float4*)&wls0[oc * 28];
        #pragma unroll
        for (int d = 0; d < 7; ++d) *(float4*)&wreg[4 * d] = wp4[d];
        float a0 = 0.f, a1 = 0.f;
        #pragma unroll
        for (int ci = 0; ci < 3; ++ci)
            #pragma unroll
            for (int ky = 0; ky < 3; ++ky)
                #pragma unroll
                for (int kx = 0; kx < 3; ++kx) {
                    float wv = wreg[ci * 9 + ky * 3 + kx];
                    a0 = fmaf(win[ci][ky][kx],     wv, a0);
                    a1 = fmaf(win[ci][ky][kx + 1], wv, a1);
                }
        float A = As[oc], C = Cs[oc];
        float q0 = quantv(fmaf(a0, A, C), sf1);
        float q1 = quantv(fmaf(a1, A, C), sf1);
        const float4 w1v = *(const float4*)&wls1[oc * 4];
        acc1[0][0] = fmaf(q0, w1v.x, acc1[0][0]); acc1[0][1] = fmaf(q1, w1v.x, acc1[0][1]);
        acc1[1][0] = fmaf(q0, w1v.y, acc1[1][0]); acc1[1][1] = fmaf(q1, w1v.y, acc1[1][1]);
        acc1[2][0] = fmaf(q0, w1v.z, acc1[2][0]); acc1[2][1] = fmaf(q1, w1v.z, acc1[2][1]);
        acc1[3][0] = fmaf(q0, w1v.w, acc1[3][0]); acc1[3][1] = fmaf(q1, w1v.w, acc1[3][1]);
    }
    float lmax = 0.f;
    float* ob = out + (long)b * 4096 + (r0 + h) * 32 + w0c;
    #pragma unroll
    for (int o = 0; o < 4; ++o) {
        float y0 = fmaf(acc1[o][0], A1s[o], C1s[o]);
        float y1 = fmaf(acc1[o][1], A1s[o], C1s[o]);
        lmax = fmaxf(lmax, fmaxf(fabsf(y0), fabsf(y1)));
        float2 r2; r2.x = y0; r2.y = y1;
        *(float2*)&ob[o * 1024] = r2;
    }
    block_max_atomic(lmax, mout);
}

// ---------------- conv2 (4->32, 3x3, s2): thread = 8 oc x 4 px, weights k-major LDS ----------------
__global__ __launch_bounds__(256) void k_conv2c(
    const float* __restrict__ inp, const float* __restrict__ wgl,
    const float* __restrict__ wsf, const float* __restrict__ bias,
    const float* __restrict__ bns, const float* __restrict__ bnb,
    const unsigned* __restrict__ umax, unsigned* __restrict__ mout,
    float* __restrict__ out) {
    __shared__ float tile[4 * 34 * 36];   // 4896
    __shared__ float wlds[36 * 32];       // 1152, k-major
    __shared__ float As[32], Cs[32];
    const int tid = threadIdx.x;
    const float sf = get_sf(umax, 2);
    if (tid < 32) {
        int oc = tid;
        float bsf = wsf[oc] * sf;
        float bint = rintf(bias[oc] / bsf);
        float a = bsf * bns[oc];
        As[oc] = a;
        Cs[oc] = fmaf(bint, a, bnb[oc]);
    }
    for (int i = tid; i < 4896; i += 256) tile[i] = 0.f;
    for (int i = tid; i < 1152; i += 256) {
        int k = i >> 5, oc = i & 31;
        wlds[i] = wgl[oc * 36 + k];
    }
    __syncthreads();
    const float* ib = inp + (long)blockIdx.x * 4096;
    for (int i = tid; i < 4096; i += 256) {
        int ci = i >> 10, px = i & 1023;
        int iy = px >> 5, ix = px & 31;
        tile[ci * 1224 + (iy + 1) * 36 + (ix + 1)] = quantv(ib[i], sf);
    }
    __syncthreads();
    const int oc0 = (tid >> 6) * 8;
    const int pxq = tid & 63;
    const int h = pxq >> 2, c = pxq & 3;   // out row h, cols 4c..4c+3
    float acc[8][4];
    #pragma unroll
    for (int k = 0; k < 8; ++k)
        #pragma unroll
        for (int p = 0; p < 4; ++p) acc[k][p] = 0.f;
    #pragma unroll 1
    for (int ci = 0; ci < 4; ++ci) {
        #pragma unroll
        for (int ky = 0; ky < 3; ++ky) {
            const float* rp = tile + ci * 1224 + (2 * h + ky) * 36 + 8 * c;
            float wn[12];
            #pragma unroll
            for (int d = 0; d < 3; ++d) *(float4*)&wn[4 * d] = *(const float4*)&rp[4 * d];
            #pragma unroll
            for (int kx = 0; kx < 3; ++kx) {
                const float* wp = &wlds[(ci * 9 + ky * 3 + kx) * 32 + oc0];
                float4 wa = *(const float4*)&wp[0];
                float4 wb = *(const float4*)&wp[4];
                float wf[8] = {wa.x, wa.y, wa.z, wa.w, wb.x, wb.y, wb.z, wb.w};
                #pragma unroll
                for (int k = 0; k < 8; ++k)
                    #pragma unroll
                    for (int p = 0; p < 4; ++p)
                        acc[k][p] = fmaf(wn[2 * p + kx], wf[k], acc[k][p]);
            }
        }
    }
    float lmax = 0.f;
    float* ob = out + (long)blockIdx.x * 8192;
    #pragma unroll
    for (int k = 0; k < 8; ++k) {
        int oc = oc0 + k;
        float A = As[oc], C = Cs[oc];
        float4 r;
        float* rp = &r.x;
        #pragma unroll
        for (int p = 0; p < 4; ++p) {
            float y = fmaf(acc[k][p], A, C);
            rp[p] = y;
            lmax = fmaxf(lmax, fabsf(y));
        }
        *(float4*)&ob[oc * 256 + h * 16 + c * 4] = r;
    }
    block_max_atomic(lmax, mout);
}

// ---------------- conv3/conv4: 2 img/block, 4oc x 4px, K-phased LDS ----------------
template<int HIN, int S>
__global__ __launch_bounds__(256) void k_conv34b(
    const float* __restrict__ inp, const float* __restrict__ wi,
    const float* __restrict__ wsf, const float* __restrict__ bias,
    const float* __restrict__ bns, const float* __restrict__ bnb,
    const unsigned* __restrict__ umax, int slot, unsigned* __restrict__ mout,
    float* __restrict__ out) {
    constexpr int ROWS = HIN + 2;
    constexpr int RS   = (S == 2) ? 20 : 12;
    constexpr int TI   = 8 * ROWS * RS;
    constexpr int PIX  = HIN * HIN;
    constexpr int NELT = 2 * 8 * PIX;
    constexpr int WINW = (S == 2) ? 12 : 8;
    constexpr int ND   = (S == 2) ? 3 : 2;
    __shared__ float tile[2 * TI];
    __shared__ float wlds[72 * 36];
    __shared__ float As[32], Cs[32];
    const int tid  = threadIdx.x;
    const int imgl = tid >> 7;
    const int ocg  = (tid >> 4) & 7;
    const int pxq  = tid & 15;
    const int h = pxq >> 1, c = pxq & 1;
    const float sf = get_sf(umax, slot);
    if (tid < 32) {
        int oc = tid;
        float bsf = wsf[oc] * sf;
        float bint = rintf(bias[oc] / bsf);
        float a = bsf * bns[oc];
        As[oc] = a;
        Cs[oc] = fmaf(bint, a, bnb[oc]);
    }
    for (int i = tid; i < 2 * TI; i += 256) tile[i] = 0.f;
    float acc[16];
    #pragma unroll
    for (int i = 0; i < 16; ++i) acc[i] = 0.f;
    const float* ib = inp + (long)blockIdx.x * 2 * 32 * PIX;
    for (int ph = 0; ph < 4; ++ph) {
        __syncthreads();
        for (int i = tid; i < NELT; i += 256) {
            int im = i / (8 * PIX);
            int r  = i % (8 * PIX);
            int ci = r / PIX;
            int px = r % PIX;
            int iy = px / HIN, ix = px % HIN;
            tile[(im * 8 + ci) * (ROWS * RS) + (iy + 1) * RS + (ix + 1)] =
                quantv(ib[(long)(im * 32 + ph * 8 + ci) * PIX + px], sf);
        }
        for (int i = tid; i < 2304; i += 256) {
            int oc = i / 72, k = i - oc * 72;
            wlds[k * 36 + oc] = wi[oc * 288 + ph * 72 + k];
        }
        __syncthreads();
        const float* tb = tile + imgl * TI;
        #pragma unroll 2
        for (int ci = 0; ci < 8; ++ci) {
            float win[3][WINW];
            #pragma unroll
            for (int ky = 0; ky < 3; ++ky) {
                const float* rp = tb + ci * (ROWS * RS) + (S * h + ky) * RS + S * 4 * c;
                #pragma unroll
                for (int d = 0; d < ND; ++d)
                    *(float4*)&win[ky][4 * d] = *(const float4*)&rp[4 * d];
            }
            #pragma unroll
            for (int ky = 0; ky < 3; ++ky)
                #pragma unroll
                for (int kx = 0; kx < 3; ++kx) {
                    int j = ky * 3 + kx;
                    float4 wv = *(const float4*)&wlds[(ci * 9 + j) * 36 + ocg * 4];
                    float wvf[4] = {wv.x, wv.y, wv.z, wv.w};
                    #pragma unroll
                    for (int k = 0; k < 4; ++k)
                        #pragma unroll
                        for (int px = 0; px < 4; ++px)
                            acc[k * 4 + px] = fmaf(win[ky][S * px + kx], wvf[k], acc[k * 4 + px]);
                }
        }
    }
    float lmax = 0.f;
    long imgg = (long)blockIdx.x * 2 + imgl;
    #pragma unroll
    for (int k = 0; k < 4; ++k) {
        int oc = ocg * 4 + k;
        float A = As[oc], C = Cs[oc];
        float4 r;
        float* rp = &r.x;
        #pragma unroll
        for (int px = 0; px < 4; ++px) {
            float y = fmaf(acc[k * 4 + px], A, C);
            rp[px] = y;
            lmax = fmaxf(lmax, fabsf(y));
        }
        *(float4*)&out[(imgg * 32 + oc) * 64 + h * 8 + c * 4] = r;
    }
    block_max_atomic(lmax, mout);
}

// ---------------- linear 2048->10 per image ----------------
__global__ __launch_bounds__(256) void k_fc(
    const float* __restrict__ act, const float* __restrict__ wdi,
    const float* __restrict__ wsfd, const float* __restrict__ bd,
    const unsigned* __restrict__ umax, float* __restrict__ logits) {
    int b = blockIdx.x;
    float sf = get_sf(umax, 5);
    const float* ab = act + (long)b * 2048;
    float acc[10];
    #pragma unroll
    for (int c = 0; c < 10; ++c) acc[c] = 0.f;
    #pragma unroll
    for (int k = 0; k < 8; ++k) {
        int j = threadIdx.x + 256 * k;
        float q = quantv(ab[j], sf);
        #pragma unroll
        for (int c = 0; c < 10; ++c) acc[c] = fmaf(q, wdi[c * 2048 + j], acc[c]);
    }
    #pragma unroll
    for (int c = 0; c < 10; ++c)
        #pragma unroll
        for (int o = 32; o; o >>= 1) acc[c] += __shfl_down(acc[c], o, 64);
    __shared__ float red[4][10];
    int wid = threadIdx.x >> 6;
    if ((threadIdx.x & 63) == 0)
        #pragma unroll
        for (int c = 0; c < 10; ++c) red[wid][c] = acc[c];
    __syncthreads();
    if (threadIdx.x < 10) {
        int c = threadIdx.x;
        float s = red[0][c] + red[1][c] + red[2][c] + red[3][c];
        float bsf = wsfd[c] * sf;
        float bint = rintf(bd[c] / bsf);
        logits[b * 10 + c] = (s + bint) * bsf;
    }
}

// ---------------- softmax over batch axis (dim 0) ----------------
__global__ __launch_bounds__(256) void k_softmax(const float* __restrict__ logits, float* __restrict__ out) {
    int c = blockIdx.x;
    float v0 = logits[(threadIdx.x +   0) * 10 + c];
    float v1 = logits[(threadIdx.x + 256) * 10 + c];
    float v2 = logits[(threadIdx.x + 512) * 10 + c];
    float v3 = logits[(threadIdx.x + 768) * 10 + c];
    float mx = fmaxf(fmaxf(v0, v1), fmaxf(v2, v3));
    __shared__ float redm[4];
    __shared__ float reds[4];
    #pragma unroll
    for (int o = 32; o; o >>= 1) mx = fmaxf(mx, __shfl_down(mx, o, 64));
    if ((threadIdx.x & 63) == 0) redm[threadIdx.x >> 6] = mx;
    __syncthreads();
    mx = fmaxf(fmaxf(redm[0], redm[1]), fmaxf(redm[2], redm[3]));
    float e0 = expf(v0 - mx), e1 = expf(v1 - mx), e2 = expf(v2 - mx), e3 = expf(v3 - mx);
    float s = (e0 + e1) + (e2 + e3);
    #pragma unroll
    for (int o = 32; o; o >>= 1) s += __shfl_down(s, o, 64);
    if ((threadIdx.x & 63) == 0) reds[threadIdx.x >> 6] = s;
    __syncthreads();
    s = reds[0] + reds[1] + reds[2] + reds[3];
    out[(threadIdx.x +   0) * 10 + c] = e0 / s;
    out[(threadIdx.x + 256) * 10 + c] = e1 / s;
    out[(threadIdx.x + 512) * 10 + c] = e2 / s;
    out[(threadIdx.x + 768) * 10 + c] = e3 / s;
}

extern "C" void kernel_launch(void* const* d_in, const int* in_sizes, int n_in,
                              void* d_out, int out_size, void* d_ws, size_t ws_size,
                              hipStream_t stream) {
    (void)in_sizes; (void)n_in; (void)out_size; (void)ws_size;
    const float* x = (const float*)d_in[0];
    const float *w[5], *bia[5], *g[5], *bb[5], *m[5], *v[5];
    for (int i = 0; i < 5; ++i) {
        w[i]   = (const float*)d_in[1 + 6 * i + 0];
        bia[i] = (const float*)d_in[1 + 6 * i + 1];
        g[i]   = (const float*)d_in[1 + 6 * i + 2];
        bb[i]  = (const float*)d_in[1 + 6 * i + 3];
        m[i]   = (const float*)d_in[1 + 6 * i + 4];
        v[i]   = (const float*)d_in[1 + 6 * i + 5];
    }
    const float* wd = (const float*)d_in[31];
    const float* bd = (const float*)d_in[32];
    float* ws = (float*)d_ws;
    unsigned* umax = (unsigned*)ws;   // [6][64] buckets
    float* out = (float*)d_out;

    float* wsf0 = ws + OFF_WSF0; float* bns0 = ws + OFF_BNS0; float* bnb0 = ws + OFF_BNB0; float* w0i = ws + OFF_W0I;
    float* wsf1 = ws + OFF_WSF1; float* bns1 = ws + OFF_BNS1; float* bnb1 = ws + OFF_BNB1; float* w1i = ws + OFF_W1I;
    float* wsf2 = ws + OFF_WSF2; float* bns2 = ws + OFF_BNS2; float* bnb2 = ws + OFF_BNB2; float* w2i = ws + OFF_W2I;
    float* wsf3 = ws + OFF_WSF3; float* bns3 = ws + OFF_BNS3; float* bnb3 = ws + OFF_BNB3; float* w3i = ws + OFF_W3I;
    float* wsf4 = ws + OFF_WSF4; float* bns4 = ws + OFF_BNS4; float* bnb4 = ws + OFF_BNB4; float* w4i = ws + OFF_W4I;
    float* wsfd = ws + OFF_WSFD; float* wdi = ws + OFF_WDI;
    float* logits = ws + OFF_LOG;
    float* actA = ws + ACT_A_OFF;   // act2 / act4
    float* actB = ws + ACT_B_OFF;   // act1 / act3

    PrepAll pa;
    pa.umax = umax;
    const float* ww[6] = {w[0], w[1], w[2], w[3], w[4], wd};
    float* wsfp[6] = {wsf0, wsf1, wsf2, wsf3, wsf4, wsfd};
    float* wip[6]  = {w0i, w1i, w2i, w3i, w4i, wdi};
    float* bnsp[6] = {bns0, bns1, bns2, bns3, bns4, nullptr};
    float* bnbp[6] = {bnb0, bnb1, bnb2, bnb3, bnb4, nullptr};
    int Ks[6] = {27, 32, 36, 288, 288, 2048};
    for (int i = 0; i < 6; ++i) {
        pa.e[i].w = ww[i];
        pa.e[i].g = (i < 5) ? g[i] : nullptr;
        pa.e[i].bb = (i < 5) ? bb[i] : nullptr;
        pa.e[i].m = (i < 5) ? m[i] : nullptr;
        pa.e[i].v = (i < 5) ? v[i] : nullptr;
        pa.e[i].wsf = wsfp[i];
        pa.e[i].wint = wip[i];
        pa.e[i].bns = bnsp[i];
        pa.e[i].bnb = bnbp[i];
        pa.e[i].K = Ks[i];
        pa.e[i].has_bn = (i < 5) ? 1 : 0;
    }

    hipLaunchKernelGGL(k_prep_all, dim3(143), dim3(256), 0, stream, pa);
    hipLaunchKernelGGL(k_absmax, dim3(1024), dim3(256), 0, stream,
                       (const float4*)x, 1024 * 3 * 32 * 32 / 4, umax + 0 * 64);
    hipLaunchKernelGGL(k_conv0maxN, dim3(2048), dim3(256), 0, stream,
                       x, w0i, wsf0, bia[0], bns0, bnb0, umax, umax + 1 * 64);
    hipLaunchKernelGGL(k_conv01n, dim3(2048), dim3(256), 0, stream,
                       x, w0i, wsf0, bia[0], bns0, bnb0,
                       w1i, wsf1, bia[1], bns1, bnb1, umax, umax + 2 * 64, actB);
    hipLaunchKernelGGL(k_conv2c, dim3(1024), dim3(256), 0, stream,
                       actB, w2i, wsf2, bia[2], bns2, bnb2, umax, umax + 3 * 64, actA);
    hipLaunchKernelGGL((k_conv34b<16, 2>), dim3(512), dim3(256), 0, stream,
                       actA, w3i, wsf3, bia[3], bns3, bnb3, umax, 3, umax + 4 * 64, actB);
    hipLaunchKernelGGL((k_conv34b<8, 1>),  dim3(512), dim3(256), 0, stream,
                       actB, w4i, wsf4, bia[4], bns4, bnb4, umax, 4, umax + 5 * 64, actA);
    hipLaunchKernelGGL(k_fc, dim3(1024), dim3(256), 0, stream, actA, wdi, wsfd, bd, umax, logits);
    hipLaunchKernelGGL(k_softmax, dim3(10), dim3(256), 0, stream, logits, out);
}

// Round 13
// 184.736 us; speedup vs baseline: 2.1708x; 1.0023x over previous
//
#include <hip/hip_runtime.h>

#define DI __device__ __forceinline__

// ---------------- ws layout (float offsets) ----------------
// umax[6][64] buckets (uint32) at 0..384
constexpr int OFF_WSF0 = 384;
constexpr int OFF_BNS0 = 416;
constexpr int OFF_BNB0 = 448;
constexpr int OFF_W0I  = 480;    // 32*27 = 864
constexpr int OFF_WSF1 = 1344;
constexpr int OFF_BNS1 = 1348;
constexpr int OFF_BNB1 = 1352;
constexpr int OFF_W1I  = 1356;   // 128
constexpr int OFF_WSF2 = 1484;
constexpr int OFF_BNS2 = 1516;
constexpr int OFF_BNB2 = 1548;
constexpr int OFF_W2I  = 1580;   // 1152
constexpr int OFF_WSF3 = 2732;
constexpr int OFF_BNS3 = 2764;
constexpr int OFF_BNB3 = 2796;
constexpr int OFF_W3I  = 2828;   // 9216
constexpr int OFF_WSF4 = 12044;
constexpr int OFF_BNS4 = 12076;
constexpr int OFF_BNB4 = 12108;
constexpr int OFF_W4I  = 12140;  // 9216
constexpr int OFF_WSFD = 21356;  // 10
constexpr int OFF_WDI  = 21368;  // 20480
constexpr int OFF_LOG  = 41856;  // 10240
constexpr int OFF_ACT  = 52224;
constexpr long ACT_A_OFF = OFF_ACT;              // act2/act4
constexpr long ACT_B_OFF = OFF_ACT + 8388608L;   // act1/act3

// ---------------- helpers ----------------
// quant via reciprocal multiply (rsf = 1/sf, uniform). Deviation vs x/sf is
// ~1e-5 in q-space -- 100x below the epilogue deviation already tolerated.
DI float quantm(float x, float rsf) {
    float q = rintf(x * rsf);
    return fminf(fmaxf(q, -127.0f), 127.0f);
}
// reduce 64 buckets (bit patterns of non-negative floats -> u32 max == float max)
DI float get_sf(const unsigned* umax, int slot) {
    const unsigned* p = umax + slot * 64;
    unsigned m = 0u;
    #pragma unroll
    for (int i = 0; i < 64; ++i) m = m > p[i] ? m : p[i];
    return fmaxf(__uint_as_float(m) / 127.0f, 1e-8f);
}
// block max -> one atomic into bucket blockIdx&63 (contention /64)
DI void block_max_atomic(float v, unsigned* dst) {
    __shared__ float redm_[4];
    #pragma unroll
    for (int o = 32; o; o >>= 1) v = fmaxf(v, __shfl_down(v, o, 64));
    int wid = threadIdx.x >> 6;
    if ((threadIdx.x & 63) == 0) redm_[wid] = v;
    __syncthreads();
    if (threadIdx.x == 0) {
        int nw = blockDim.x >> 6;
        float m = redm_[0];
        for (int i = 1; i < nw; ++i) m = fmaxf(m, redm_[i]);
        atomicMax(dst + (blockIdx.x & 63), __float_as_uint(m));
    }
}

// ---------------- prep: weight quant + BN fold ----------------
struct PrepEntry {
    const float *w, *g, *bb, *m, *v;
    float *wsf, *wint, *bns, *bnb;
    int K; int has_bn;
};
struct PrepAll { PrepEntry e[6]; unsigned* umax; };

__global__ __launch_bounds__(256) void k_prep_all(PrepAll pa) {
    int blk = blockIdx.x;
    if (blk == 142) {
        for (int i = threadIdx.x; i < 384; i += 256) pa.umax[i] = 0u;
        return;
    }
    int layer, oc;
    if      (blk < 32)  { layer = 0; oc = blk; }
    else if (blk < 36)  { layer = 1; oc = blk - 32; }
    else if (blk < 68)  { layer = 2; oc = blk - 36; }
    else if (blk < 100) { layer = 3; oc = blk - 68; }
    else if (blk < 132) { layer = 4; oc = blk - 100; }
    else                { layer = 5; oc = blk - 132; }
    PrepEntry a = pa.e[layer];
    const float* wr = a.w + (long)oc * a.K;
    float mx = 0.f;
    for (int i = threadIdx.x; i < a.K; i += 256) mx = fmaxf(mx, fabsf(wr[i]));
    __shared__ float red[4];
    __shared__ float s_sf;
    #pragma unroll
    for (int o = 32; o; o >>= 1) mx = fmaxf(mx, __shfl_down(mx, o, 64));
    if ((threadIdx.x & 63) == 0) red[threadIdx.x >> 6] = mx;
    __syncthreads();
    if (threadIdx.x == 0) {
        float t = fmaxf(fmaxf(red[0], red[1]), fmaxf(red[2], red[3]));
        t = fmaxf(t / 127.0f, 1e-8f);
        a.wsf[oc] = t; s_sf = t;
        if (a.has_bn) {
            float inv = a.g[oc] / sqrtf(a.v[oc] + 1e-5f);
            a.bns[oc] = inv;
            a.bnb[oc] = a.bb[oc] - a.m[oc] * inv;
        }
    }
    __syncthreads();
    float sf = s_sf;
    for (int i = threadIdx.x; i < a.K; i += 256) a.wint[(long)oc * a.K + i] = rintf(wr[i] / sf);
}

__global__ __launch_bounds__(256) void k_absmax(const float4* __restrict__ x, int n4, unsigned* dst) {
    float m = 0.f;
    for (int i = blockIdx.x * blockDim.x + threadIdx.x; i < n4; i += gridDim.x * blockDim.x) {
        float4 t = x[i];
        m = fmaxf(m, fmaxf(fmaxf(fabsf(t.x), fabsf(t.y)), fmaxf(fabsf(t.z), fabsf(t.w))));
    }
    block_max_atomic(m, dst);
}

// ---------------- conv0 pass 1: max only. grid 2048 = (image, row-half) ----------------
// thread = 4 oc x 16 px. LDS tile[3][18][36], weights k-major [27][32].
__global__ __launch_bounds__(256) void k_conv0maxN(
    const float* __restrict__ x, const float* __restrict__ w0i,
    const float* __restrict__ wsf0, const float* __restrict__ bias0,
    const float* __restrict__ bns0, const float* __restrict__ bnb0,
    const unsigned* __restrict__ umax, unsigned* __restrict__ mout) {
    __shared__ float tile[3 * 18 * 36];   // 1944
    __shared__ float wlds[27 * 32];       // 864
    __shared__ float As[32], Cs[32];
    const int b  = blockIdx.x >> 1;
    const int r0 = (blockIdx.x & 1) * 16;
    const int tid = threadIdx.x;
    const float sfx = get_sf(umax, 0);
    const float rsfx = 1.0f / sfx;
    if (tid < 32) {
        int oc = tid;
        float bsf = wsf0[oc] * sfx;
        float bint = rintf(bias0[oc] / bsf);
        float a = bsf * bns0[oc];
        As[oc] = a;
        Cs[oc] = fmaf(bint, a, bnb0[oc]);
    }
    for (int i = tid; i < 1944; i += 256) tile[i] = 0.f;
    for (int i = tid; i < 864; i += 256) {
        int k = i >> 5, oc = i & 31;
        wlds[i] = w0i[oc * 27 + k];
    }
    __syncthreads();
    const float* xb = x + (long)b * 3072;
    for (int i = tid; i < 1728; i += 256) {          // 3 ci * 18 rows * 32 cols
        int ci = i / 576, rem = i - ci * 576;
        int rr = rem >> 5, cc = rem & 31;
        int gr = r0 - 1 + rr;
        if ((unsigned)gr < 32u)
            tile[ci * 648 + rr * 36 + cc + 1] = quantm(xb[ci * 1024 + gr * 32 + cc], rsfx);
    }
    __syncthreads();
    const int oc0  = (tid >> 5) * 4;       // 8 oc-quads
    const int pxg  = tid & 31;
    const int row  = pxg >> 1;             // 0..15 (output row r0+row)
    const int wcol = (pxg & 1) * 16;       // output col base
    float acc[4][16];
    #pragma unroll
    for (int o = 0; o < 4; ++o)
        #pragma unroll
        for (int p = 0; p < 16; ++p) acc[o][p] = 0.f;
    #pragma unroll 1
    for (int kk = 0; kk < 9; ++kk) {       // kk = ci*3 + ky
        int ci = kk / 3, ky = kk - ci * 3;
        const float* rp = tile + ci * 648 + (row + ky) * 36 + wcol;
        float wn[20];
        #pragma unroll
        for (int d = 0; d < 5; ++d) *(float4*)&wn[4 * d] = *(const float4*)&rp[4 * d];
        #pragma unroll
        for (int kx = 0; kx < 3; ++kx) {
            float4 wv = *(const float4*)&wlds[(kk * 3 + kx) * 32 + oc0];
            const float* wf = &wv.x;
            #pragma unroll
            for (int o = 0; o < 4; ++o)
                #pragma unroll
                for (int p = 0; p < 16; ++p)
                    acc[o][p] = fmaf(wn[p + kx], wf[o], acc[o][p]);
        }
    }
    float lmax = 0.f;
    #pragma unroll
    for (int o = 0; o < 4; ++o) {
        float A = As[oc0 + o], C = Cs[oc0 + o];
        #pragma unroll
        for (int p = 0; p < 16; ++p)
            lmax = fmaxf(lmax, fabsf(fmaf(acc[o][p], A, C)));
    }
    block_max_atomic(lmax, mout);
}

// ---------------- conv0 pass 2 + fused 1x1 conv1. grid 2048 = (image, 16-row band) ----------------
// thread = 2 px, all 32 oc sequential; quant folded into per-oc constants (no div).
__global__ __launch_bounds__(256) void k_conv01n(
    const float* __restrict__ x, const float* __restrict__ w0i,
    const float* __restrict__ wsf0, const float* __restrict__ bias0,
    const float* __restrict__ bns0, const float* __restrict__ bnb0,
    const float* __restrict__ w1i,
    const float* __restrict__ wsf1, const float* __restrict__ bias1,
    const float* __restrict__ bns1, const float* __restrict__ bnb1,
    const unsigned* __restrict__ umax, unsigned* __restrict__ mout,
    float* __restrict__ out) {
    __shared__ float tile[1944];   // [3][18][36]
    __shared__ float wls0[896];    // [32][28]
    __shared__ float wls1[128];    // [32][4] oc-major
    __shared__ float Aq[32], Cq[32];   // A*rsf1, C*rsf1 (quant-folded epilogue)
    __shared__ float A1s[4], C1s[4];
    const int b  = blockIdx.x >> 1;
    const int r0 = (blockIdx.x & 1) * 16;
    const int tid = threadIdx.x;
    const float sfx = get_sf(umax, 0);
    const float rsfx = 1.0f / sfx;
    const float sf1 = get_sf(umax, 1);
    const float rsf1 = 1.0f / sf1;
    if (tid < 32) {
        int oc = tid;
        float bsf = wsf0[oc] * sfx;
        float bint = rintf(bias0[oc] / bsf);
        float a = bsf * bns0[oc];
        float c = fmaf(bint, a, bnb0[oc]);
        Aq[oc] = a * rsf1;
        Cq[oc] = c * rsf1;
    }
    if (tid >= 64 && tid < 68) {
        int oc = tid - 64;
        float bsf = wsf1[oc] * sf1;
        float bint = rintf(bias1[oc] / bsf);
        float a = bsf * bns1[oc];
        A1s[oc] = a;
        C1s[oc] = fmaf(bint, a, bnb1[oc]);
    }
    for (int i = tid; i < 1944; i += 256) tile[i] = 0.f;
    for (int i = tid; i < 864; i += 256) {
        int oc = i / 27, k = i - oc * 27;
        wls0[oc * 28 + k] = w0i[i];
    }
    if (tid >= 128 && tid < 256) {
        int j = tid - 128;
        wls1[(j & 31) * 4 + (j >> 5)] = w1i[j];
    }
    __syncthreads();
    const float* xb = x + (long)b * 3072;
    for (int i = tid; i < 1728; i += 256) {
        int ci = i / 576, rem = i - ci * 576;
        int rr = rem >> 5, cc = rem & 31;
        int gr = r0 - 1 + rr;
        if ((unsigned)gr < 32u)
            tile[ci * 648 + rr * 36 + cc + 1] = quantm(xb[ci * 1024 + gr * 32 + cc], rsfx);
    }
    __syncthreads();
    const int h   = tid >> 4;          // 0..15 (local out row)
    const int w0c = (tid & 15) * 2;    // 0..30 (out col base)
    float win[3][3][4];
    #pragma unroll
    for (int ci = 0; ci < 3; ++ci)
        #pragma unroll
        for (int ky = 0; ky < 3; ++ky) {
            const int base = ci * 648 + (h + ky) * 36 + w0c;
            #pragma unroll
            for (int d = 0; d < 4; ++d) win[ci][ky][d] = tile[base + d];
        }
    float acc1[4][2];
    #pragma unroll
    for (int o = 0; o < 4; ++o) { acc1[o][0] = 0.f; acc1[o][1] = 0.f; }
    #pragma unroll 1
    for (int oc = 0; oc < 32; ++oc) {
        float wreg[28];
        const float4* wp4 = (const float4*)&wls0[oc * 28];
        #pragma unroll
        for (int d = 0; d < 7; ++d) *(float4*)&wreg[4 * d] = wp4[d];
        float a0 = 0.f, a1 = 0.f;
        #pragma unroll
        for (int ci = 0; ci < 3; ++ci)
            #pragma unroll
            for (int ky = 0; ky < 3; ++ky)
                #pragma unroll
                for (int kx = 0; kx < 3; ++kx) {
                    float wv = wreg[ci * 9 + ky * 3 + kx];
                    a0 = fmaf(win[ci][ky][kx],     wv, a0);
                    a1 = fmaf(win[ci][ky][kx + 1], wv, a1);
                }
        float A = Aq[oc], C = Cq[oc];
        float q0 = fminf(fmaxf(rintf(fmaf(a0, A, C)), -127.0f), 127.0f);
        float q1 = fminf(fmaxf(rintf(fmaf(a1, A, C)), -127.0f), 127.0f);
        const float4 w1v = *(const float4*)&wls1[oc * 4];
        acc1[0][0] = fmaf(q0, w1v.x, acc1[0][0]); acc1[0][1] = fmaf(q1, w1v.x, acc1[0][1]);
        acc1[1][0] = fmaf(q0, w1v.y, acc1[1][0]); acc1[1][1] = fmaf(q1, w1v.y, acc1[1][1]);
        acc1[2][0] = fmaf(q0, w1v.z, acc1[2][0]); acc1[2][1] = fmaf(q1, w1v.z, acc1[2][1]);
        acc1[3][0] = fmaf(q0, w1v.w, acc1[3][0]); acc1[3][1] = fmaf(q1, w1v.w, acc1[3][1]);
    }
    float lmax = 0.f;
    float* ob = out + (long)b * 4096 + (r0 + h) * 32 + w0c;
    #pragma unroll
    for (int o = 0; o < 4; ++o) {
        float y0 = fmaf(acc1[o][0], A1s[o], C1s[o]);
        float y1 = fmaf(acc1[o][1], A1s[o], C1s[o]);
        lmax = fmaxf(lmax, fmaxf(fabsf(y0), fabsf(y1)));
        float2 r2; r2.x = y0; r2.y = y1;
        *(float2*)&ob[o * 1024] = r2;
    }
    block_max_atomic(lmax, mout);
}

// ---------------- conv2 (4->32, 3x3, s2): thread = 8 oc x 4 px, weights k-major LDS ----------------
__global__ __launch_bounds__(256) void k_conv2c(
    const float* __restrict__ inp, const float* __restrict__ wgl,
    const float* __restrict__ wsf, const float* __restrict__ bias,
    const float* __restrict__ bns, const float* __restrict__ bnb,
    const unsigned* __restrict__ umax, unsigned* __restrict__ mout,
    float* __restrict__ out) {
    __shared__ float tile[4 * 34 * 36];   // 4896
    __shared__ float wlds[36 * 32];       // 1152, k-major
    __shared__ float As[32], Cs[32];
    const int tid = threadIdx.x;
    const float sf = get_sf(umax, 2);
    const float rsf = 1.0f / sf;
    if (tid < 32) {
        int oc = tid;
        float bsf = wsf[oc] * sf;
        float bint = rintf(bias[oc] / bsf);
        float a = bsf * bns[oc];
        As[oc] = a;
        Cs[oc] = fmaf(bint, a, bnb[oc]);
    }
    for (int i = tid; i < 4896; i += 256) tile[i] = 0.f;
    for (int i = tid; i < 1152; i += 256) {
        int k = i >> 5, oc = i & 31;
        wlds[i] = wgl[oc * 36 + k];
    }
    __syncthreads();
    const float* ib = inp + (long)blockIdx.x * 4096;
    for (int i = tid; i < 4096; i += 256) {
        int ci = i >> 10, px = i & 1023;
        int iy = px >> 5, ix = px & 31;
        tile[ci * 1224 + (iy + 1) * 36 + (ix + 1)] = quantm(ib[i], rsf);
    }
    __syncthreads();
    const int oc0 = (tid >> 6) * 8;
    const int pxq = tid & 63;
    const int h = pxq >> 2, c = pxq & 3;   // out row h, cols 4c..4c+3
    float acc[8][4];
    #pragma unroll
    for (int k = 0; k < 8; ++k)
        #pragma unroll
        for (int p = 0; p < 4; ++p) acc[k][p] = 0.f;
    #pragma unroll 1
    for (int ci = 0; ci < 4; ++ci) {
        #pragma unroll
        for (int ky = 0; ky < 3; ++ky) {
            const float* rp = tile + ci * 1224 + (2 * h + ky) * 36 + 8 * c;
            float wn[12];
            #pragma unroll
            for (int d = 0; d < 3; ++d) *(float4*)&wn[4 * d] = *(const float4*)&rp[4 * d];
            #pragma unroll
            for (int kx = 0; kx < 3; ++kx) {
                const float* wp = &wlds[(ci * 9 + ky * 3 + kx) * 32 + oc0];
                float4 wa = *(const float4*)&wp[0];
                float4 wb = *(const float4*)&wp[4];
                float wf[8] = {wa.x, wa.y, wa.z, wa.w, wb.x, wb.y, wb.z, wb.w};
                #pragma unroll
                for (int k = 0; k < 8; ++k)
                    #pragma unroll
                    for (int p = 0; p < 4; ++p)
                        acc[k][p] = fmaf(wn[2 * p + kx], wf[k], acc[k][p]);
            }
        }
    }
    float lmax = 0.f;
    float* ob = out + (long)blockIdx.x * 8192;
    #pragma unroll
    for (int k = 0; k < 8; ++k) {
        int oc = oc0 + k;
        float A = As[oc], C = Cs[oc];
        float4 r;
        float* rp = &r.x;
        #pragma unroll
        for (int p = 0; p < 4; ++p) {
            float y = fmaf(acc[k][p], A, C);
            rp[p] = y;
            lmax = fmaxf(lmax, fabsf(y));
        }
        *(float4*)&ob[oc * 256 + h * 16 + c * 4] = r;
    }
    block_max_atomic(lmax, mout);
}

// ---------------- conv3/conv4: 1 img/block, 4oc x 2px, K-phased LDS. grid 1024 ----------------
template<int HIN, int S>
__global__ __launch_bounds__(256) void k_conv34c(
    const float* __restrict__ inp, const float* __restrict__ wi,
    const float* __restrict__ wsf, const float* __restrict__ bias,
    const float* __restrict__ bns, const float* __restrict__ bnb,
    const unsigned* __restrict__ umax, int slot, unsigned* __restrict__ mout,
    float* __restrict__ out) {
    constexpr int ROWS = HIN + 2;
    constexpr int RS   = (S == 2) ? 20 : 12;
    constexpr int TI   = 8 * ROWS * RS;
    constexpr int PIX  = HIN * HIN;
    constexpr int NELT = 8 * PIX;
    constexpr int WINW = S + 3;          // 2 px: cols S*2c + [0 .. S+2]
    __shared__ float tile[TI];
    __shared__ float wlds[72 * 36];
    __shared__ float As[32], Cs[32];
    const int tid = threadIdx.x;
    const int ocg = tid >> 5;            // 0..7 (4 oc each)
    const int pxq = tid & 31;
    const int h = pxq >> 2, c = pxq & 3; // out row h(0..7), cols 2c, 2c+1
    const float sf = get_sf(umax, slot);
    const float rsf = 1.0f / sf;
    if (tid < 32) {
        int oc = tid;
        float bsf = wsf[oc] * sf;
        float bint = rintf(bias[oc] / bsf);
        float a = bsf * bns[oc];
        As[oc] = a;
        Cs[oc] = fmaf(bint, a, bnb[oc]);
    }
    for (int i = tid; i < TI; i += 256) tile[i] = 0.f;
    float acc[4][2];
    #pragma unroll
    for (int k = 0; k < 4; ++k) { acc[k][0] = 0.f; acc[k][1] = 0.f; }
    const float* ib = inp + (long)blockIdx.x * 32 * PIX;
    for (int ph = 0; ph < 4; ++ph) {
        __syncthreads();
        for (int i = tid; i < NELT; i += 256) {
            int ci = i / PIX;
            int px = i - ci * PIX;
            int iy = px / HIN, ix = px & (HIN - 1);
            tile[ci * (ROWS * RS) + (iy + 1) * RS + (ix + 1)] =
                quantm(ib[(long)(ph * 8 + ci) * PIX + px], rsf);
        }
        for (int i = tid; i < 2304; i += 256) {
            int oc = i / 72, k = i - oc * 72;
            wlds[k * 36 + oc] = wi[oc * 288 + ph * 72 + k];
        }
        __syncthreads();
        #pragma unroll 2
        for (int ci = 0; ci < 8; ++ci) {
            float win[3][WINW];
            #pragma unroll
            for (int ky = 0; ky < 3; ++ky) {
                const int base = ci * (ROWS * RS) + (S * h + ky) * RS + S * 2 * c;
                #pragma unroll
                for (int d = 0; d < WINW; ++d) win[ky][d] = tile[base + d];
            }
            #pragma unroll
            for (int ky = 0; ky < 3; ++ky)
                #pragma unroll
                for (int kx = 0; kx < 3; ++kx) {
                    int j = ky * 3 + kx;
                    float4 wv = *(const float4*)&wlds[(ci * 9 + j) * 36 + ocg * 4];
                    float x0 = win[ky][kx], x1 = win[ky][S + kx];
                    acc[0][0] = fmaf(x0, wv.x, acc[0][0]); acc[0][1] = fmaf(x1, wv.x, acc[0][1]);
                    acc[1][0] = fmaf(x0, wv.y, acc[1][0]); acc[1][1] = fmaf(x1, wv.y, acc[1][1]);
                    acc[2][0] = fmaf(x0, wv.z, acc[2][0]); acc[2][1] = fmaf(x1, wv.z, acc[2][1]);
                    acc[3][0] = fmaf(x0, wv.w, acc[3][0]); acc[3][1] = fmaf(x1, wv.w, acc[3][1]);
                }
        }
    }
    float lmax = 0.f;
    #pragma unroll
    for (int k = 0; k < 4; ++k) {
        int oc = ocg * 4 + k;
        float A = As[oc], C = Cs[oc];
        float y0 = fmaf(acc[k][0], A, C);
        float y1 = fmaf(acc[k][1], A, C);
        lmax = fmaxf(lmax, fmaxf(fabsf(y0), fabsf(y1)));
        float2 r2; r2.x = y0; r2.y = y1;
        *(float2*)&out[((long)blockIdx.x * 32 + oc) * 64 + h * 8 + c * 2] = r2;
    }
    block_max_atomic(lmax, mout);
}

// ---------------- linear 2048->10 per image ----------------
__global__ __launch_bounds__(256) void k_fc(
    const float* __restrict__ act, const float* __restrict__ wdi,
    const float* __restrict__ wsfd, const float* __restrict__ bd,
    const unsigned* __restrict__ umax, float* __restrict__ logits) {
    int b = blockIdx.x;
    float sf = get_sf(umax, 5);
    float rsf = 1.0f / sf;
    const float* ab = act + (long)b * 2048;
    float acc[10];
    #pragma unroll
    for (int c = 0; c < 10; ++c) acc[c] = 0.f;
    #pragma unroll
    for (int k = 0; k < 8; ++k) {
        int j = threadIdx.x + 256 * k;
        float q = quantm(ab[j], rsf);
        #pragma unroll
        for (int c = 0; c < 10; ++c) acc[c] = fmaf(q, wdi[c * 2048 + j], acc[c]);
    }
    #pragma unroll
    for (int c = 0; c < 10; ++c)
        #pragma unroll
        for (int o = 32; o; o >>= 1) acc[c] += __shfl_down(acc[c], o, 64);
    __shared__ float red[4][10];
    int wid = threadIdx.x >> 6;
    if ((threadIdx.x & 63) == 0)
        #pragma unroll
        for (int c = 0; c < 10; ++c) red[wid][c] = acc[c];
    __syncthreads();
    if (threadIdx.x < 10) {
        int c = threadIdx.x;
        float s = red[0][c] + red[1][c] + red[2][c] + red[3][c];
        float bsf = wsfd[c] * sf;
        float bint = rintf(bd[c] / bsf);
        logits[b * 10 + c] = (s + bint) * bsf;
    }
}

// ---------------- softmax over batch axis (dim 0) ----------------
__global__ __launch_bounds__(256) void k_softmax(const float* __restrict__ logits, float* __restrict__ out) {
    int c = blockIdx.x;
    float v0 = logits[(threadIdx.x +   0) * 10 + c];
    float v1 = logits[(threadIdx.x + 256) * 10 + c];
    float v2 = logits[(threadIdx.x + 512) * 10 + c];
    float v3 = logits[(threadIdx.x + 768) * 10 + c];
    float mx = fmaxf(fmaxf(v0, v1), fmaxf(v2, v3));
    __shared__ float redm[4];
    __shared__ float reds[4];
    #pragma unroll
    for (int o = 32; o; o >>= 1) mx = fmaxf(mx, __shfl_down(mx, o, 64));
    if ((threadIdx.x & 63) == 0) redm[threadIdx.x >> 6] = mx;
    __syncthreads();
    mx = fmaxf(fmaxf(redm[0], redm[1]), fmaxf(redm[2], redm[3]));
    float e0 = expf(v0 - mx), e1 = expf(v1 - mx), e2 = expf(v2 - mx), e3 = expf(v3 - mx);
    float s = (e0 + e1) + (e2 + e3);
    #pragma unroll
    for (int o = 32; o; o >>= 1) s += __shfl_down(s, o, 64);
    if ((threadIdx.x & 63) == 0) reds[threadIdx.x >> 6] = s;
    __syncthreads();
    s = reds[0] + reds[1] + reds[2] + reds[3];
    out[(threadIdx.x +   0) * 10 + c] = e0 / s;
    out[(threadIdx.x + 256) * 10 + c] = e1 / s;
    out[(threadIdx.x + 512) * 10 + c] = e2 / s;
    out[(threadIdx.x + 768) * 10 + c] = e3 / s;
}

extern "C" void kernel_launch(void* const* d_in, const int* in_sizes, int n_in,
                              void* d_out, int out_size, void* d_ws, size_t ws_size,
                              hipStream_t stream) {
    (void)in_sizes; (void)n_in; (void)out_size; (void)ws_size;
    const float* x = (const float*)d_in[0];
    const float *w[5], *bia[5], *g[5], *bb[5], *m[5], *v[5];
    for (int i = 0; i < 5; ++i) {
        w[i]   = (const float*)d_in[1 + 6 * i + 0];
        bia[i] = (const float*)d_in[1 + 6 * i + 1];
        g[i]   = (const float*)d_in[1 + 6 * i + 2];
        bb[i]  = (const float*)d_in[1 + 6 * i + 3];
        m[i]   = (const float*)d_in[1 + 6 * i + 4];
        v[i]   = (const float*)d_in[1 + 6 * i + 5];
    }
    const float* wd = (const float*)d_in[31];
    const float* bd = (const float*)d_in[32];
    float* ws = (float*)d_ws;
    unsigned* umax = (unsigned*)ws;   // [6][64] buckets
    float* out = (float*)d_out;

    float* wsf0 = ws + OFF_WSF0; float* bns0 = ws + OFF_BNS0; float* bnb0 = ws + OFF_BNB0; float* w0i = ws + OFF_W0I;
    float* wsf1 = ws + OFF_WSF1; float* bns1 = ws + OFF_BNS1; float* bnb1 = ws + OFF_BNB1; float* w1i = ws + OFF_W1I;
    float* wsf2 = ws + OFF_WSF2; float* bns2 = ws + OFF_BNS2; float* bnb2 = ws + OFF_BNB2; float* w2i = ws + OFF_W2I;
    float* wsf3 = ws + OFF_WSF3; float* bns3 = ws + OFF_BNS3; float* bnb3 = ws + OFF_BNB3; float* w3i = ws + OFF_W3I;
    float* wsf4 = ws + OFF_WSF4; float* bns4 = ws + OFF_BNS4; float* bnb4 = ws + OFF_BNB4; float* w4i = ws + OFF_W4I;
    float* wsfd = ws + OFF_WSFD; float* wdi = ws + OFF_WDI;
    float* logits = ws + OFF_LOG;
    float* actA = ws + ACT_A_OFF;   // act2 / act4
    float* actB = ws + ACT_B_OFF;   // act1 / act3

    PrepAll pa;
    pa.umax = umax;
    const float* ww[6] = {w[0], w[1], w[2], w[3], w[4], wd};
    float* wsfp[6] = {wsf0, wsf1, wsf2, wsf3, wsf4, wsfd};
    float* wip[6]  = {w0i, w1i, w2i, w3i, w4i, wdi};
    float* bnsp[6] = {bns0, bns1, bns2, bns3, bns4, nullptr};
    float* bnbp[6] = {bnb0, bnb1, bnb2, bnb3, bnb4, nullptr};
    int Ks[6] = {27, 32, 36, 288, 288, 2048};
    for (int i = 0; i < 6; ++i) {
        pa.e[i].w = ww[i];
        pa.e[i].g = (i < 5) ? g[i] : nullptr;
        pa.e[i].bb = (i < 5) ? bb[i] : nullptr;
        pa.e[i].m = (i < 5) ? m[i] : nullptr;
        pa.e[i].v = (i < 5) ? v[i] : nullptr;
        pa.e[i].wsf = wsfp[i];
        pa.e[i].wint = wip[i];
        pa.e[i].bns = bnsp[i];
        pa.e[i].bnb = bnbp[i];
        pa.e[i].K = Ks[i];
        pa.e[i].has_bn = (i < 5) ? 1 : 0;
    }

    hipLaunchKernelGGL(k_prep_all, dim3(143), dim3(256), 0, stream, pa);
    hipLaunchKernelGGL(k_absmax, dim3(1024), dim3(256), 0, stream,
                       (const float4*)x, 1024 * 3 * 32 * 32 / 4, umax + 0 * 64);
    hipLaunchKernelGGL(k_conv0maxN, dim3(2048), dim3(256), 0, stream,
                       x, w0i, wsf0, bia[0], bns0, bnb0, umax, umax + 1 * 64);
    hipLaunchKernelGGL(k_conv01n, dim3(2048), dim3(256), 0, stream,
                       x, w0i, wsf0, bia[0], bns0, bnb0,
                       w1i, wsf1, bia[1], bns1, bnb1, umax, umax + 2 * 64, actB);
    hipLaunchKernelGGL(k_conv2c, dim3(1024), dim3(256), 0, stream,
                       actB, w2i, wsf2, bia[2], bns2, bnb2, umax, umax + 3 * 64, actA);
    hipLaunchKernelGGL((k_conv34c<16, 2>), dim3(1024), dim3(256), 0, stream,
                       actA, w3i, wsf3, bia[3], bns3, bnb3, umax, 3, umax + 4 * 64, actB);
    hipLaunchKernelGGL((k_conv34c<8, 1>),  dim3(1024), dim3(256), 0, stream,
                       actB, w4i, wsf4, bia[4], bns4, bnb4, umax, 4, umax + 5 * 64, actA);
    hipLaunchKernelGGL(k_fc, dim3(1024), dim3(256), 0, stream, actA, wdi, wsfd, bd, umax, logits);
    hipLaunchKernelGGL(k_softmax, dim3(10), dim3(256), 0, stream, logits, out);
}

// Round 14
// 176.482 us; speedup vs baseline: 2.2723x; 1.0468x over previous
//
#include <hip/hip_runtime.h>

#define DI __device__ __forceinline__

// ---------------- ws layout (float offsets) ----------------
// umax[6][64] buckets (uint32) at 0..384
constexpr int OFF_W0KT = 384;     // 27*32 = 864   (k-major, conv0maxN)
constexpr int OFF_W0P  = 1248;    // 32*28 = 896   (padded oc-major, conv01n)
constexpr int OFF_W1I  = 2144;    // 4*32 = 128
constexpr int OFF_W2KT = 2272;    // 36*32 = 1152  (k-major, conv2c)
constexpr int OFF_W3T  = 3424;    // 4*72*36 = 10368 (phase-k-major, conv3)
constexpr int OFF_W4T  = 13792;   // 10368           (phase-k-major, conv4)
constexpr int OFF_WDI  = 24160;   // 10*2048 = 20480
constexpr int OFF_WSF0 = 44640;
constexpr int OFF_BNS0 = 44672;
constexpr int OFF_BNB0 = 44704;
constexpr int OFF_WSF1 = 44736;
constexpr int OFF_BNS1 = 44740;
constexpr int OFF_BNB1 = 44744;
constexpr int OFF_WSF2 = 44748;
constexpr int OFF_BNS2 = 44780;
constexpr int OFF_BNB2 = 44812;
constexpr int OFF_WSF3 = 44844;
constexpr int OFF_BNS3 = 44876;
constexpr int OFF_BNB3 = 44908;
constexpr int OFF_WSF4 = 44940;
constexpr int OFF_BNS4 = 44972;
constexpr int OFF_BNB4 = 45004;
constexpr int OFF_WSFD = 45036;   // 10
constexpr int OFF_LOG  = 45056;   // 10240
constexpr int OFF_ACT  = 55296;
constexpr long ACT_A_OFF = OFF_ACT;              // act2/act4
constexpr long ACT_B_OFF = OFF_ACT + 8388608L;   // act1/act3

// ---------------- helpers ----------------
DI float quantm(float x, float rsf) {
    float q = rintf(x * rsf);
    return fminf(fmaxf(q, -127.0f), 127.0f);
}
DI float get_sf(const unsigned* umax, int slot) {
    const unsigned* p = umax + slot * 64;
    unsigned m = 0u;
    #pragma unroll
    for (int i = 0; i < 64; ++i) m = m > p[i] ? m : p[i];
    return fmaxf(__uint_as_float(m) / 127.0f, 1e-8f);
}
DI void block_max_atomic(float v, unsigned* dst) {
    __shared__ float redm_[4];
    #pragma unroll
    for (int o = 32; o; o >>= 1) v = fmaxf(v, __shfl_down(v, o, 64));
    int wid = threadIdx.x >> 6;
    if ((threadIdx.x & 63) == 0) redm_[wid] = v;
    __syncthreads();
    if (threadIdx.x == 0) {
        int nw = blockDim.x >> 6;
        float m = redm_[0];
        for (int i = 1; i < nw; ++i) m = fmaxf(m, redm_[i]);
        atomicMax(dst + (blockIdx.x & 63), __float_as_uint(m));
    }
}

// ---------------- prep: weight quant + BN fold + layout transposes ----------------
// mode: 0 = flat dst[oc*K+i]; 2 = conv0 (dst[i*32+oc] k-major AND dst2[oc*28+i] padded);
//       1 = k-major dst[i*32+oc]; 3 = phase36 dst[(i/72)*2592 + (i%72)*36 + oc]
struct PrepEntry {
    const float *w, *g, *bb, *m, *v;
    float *wsf, *dst, *dst2, *bns, *bnb;
    int K; int has_bn; int mode;
};
struct PrepAll { PrepEntry e[6]; unsigned* umax; };

__global__ __launch_bounds__(256) void k_prep_all(PrepAll pa) {
    int blk = blockIdx.x;
    if (blk == 142) {
        for (int i = threadIdx.x; i < 384; i += 256) pa.umax[i] = 0u;
        return;
    }
    int layer, oc;
    if      (blk < 32)  { layer = 0; oc = blk; }
    else if (blk < 36)  { layer = 1; oc = blk - 32; }
    else if (blk < 68)  { layer = 2; oc = blk - 36; }
    else if (blk < 100) { layer = 3; oc = blk - 68; }
    else if (blk < 132) { layer = 4; oc = blk - 100; }
    else                { layer = 5; oc = blk - 132; }
    PrepEntry a = pa.e[layer];
    const float* wr = a.w + (long)oc * a.K;
    float mx = 0.f;
    for (int i = threadIdx.x; i < a.K; i += 256) mx = fmaxf(mx, fabsf(wr[i]));
    __shared__ float red[4];
    __shared__ float s_sf;
    #pragma unroll
    for (int o = 32; o; o >>= 1) mx = fmaxf(mx, __shfl_down(mx, o, 64));
    if ((threadIdx.x & 63) == 0) red[threadIdx.x >> 6] = mx;
    __syncthreads();
    if (threadIdx.x == 0) {
        float t = fmaxf(fmaxf(red[0], red[1]), fmaxf(red[2], red[3]));
        t = fmaxf(t / 127.0f, 1e-8f);
        a.wsf[oc] = t; s_sf = t;
        if (a.has_bn) {
            float inv = a.g[oc] / sqrtf(a.v[oc] + 1e-5f);
            a.bns[oc] = inv;
            a.bnb[oc] = a.bb[oc] - a.m[oc] * inv;
        }
    }
    __syncthreads();
    float sf = s_sf;
    for (int i = threadIdx.x; i < a.K; i += 256) {
        float q = rintf(wr[i] / sf);
        if (a.mode == 0) {
            a.dst[(long)oc * a.K + i] = q;
        } else if (a.mode == 1) {
            a.dst[i * 32 + oc] = q;
        } else if (a.mode == 2) {
            a.dst[i * 32 + oc] = q;
            a.dst2[oc * 28 + i] = q;
        } else {
            int ph = i / 72, kk = i - ph * 72;
            a.dst[ph * 2592 + kk * 36 + oc] = q;
        }
    }
    if (a.mode == 2 && threadIdx.x == 0) a.dst2[oc * 28 + 27] = 0.f;   // pad
}

__global__ __launch_bounds__(256) void k_absmax(const float4* __restrict__ x, int n4, unsigned* dst) {
    float m = 0.f;
    for (int i = blockIdx.x * blockDim.x + threadIdx.x; i < n4; i += gridDim.x * blockDim.x) {
        float4 t = x[i];
        m = fmaxf(m, fmaxf(fmaxf(fabsf(t.x), fabsf(t.y)), fmaxf(fabsf(t.z), fabsf(t.w))));
    }
    block_max_atomic(m, dst);
}

// ---------------- conv0 pass 1: max only. grid 2048 = (image, row-half) ----------------
__global__ __launch_bounds__(256) void k_conv0maxN(
    const float* __restrict__ x, const float* __restrict__ w0kt,
    const float* __restrict__ wsf0, const float* __restrict__ bias0,
    const float* __restrict__ bns0, const float* __restrict__ bnb0,
    const unsigned* __restrict__ umax, unsigned* __restrict__ mout) {
    __shared__ float tile[3 * 18 * 36];   // 1944
    __shared__ float wlds[27 * 32];       // 864, k-major
    __shared__ float As[32], Cs[32];
    const int b  = blockIdx.x >> 1;
    const int r0 = (blockIdx.x & 1) * 16;
    const int tid = threadIdx.x;
    const float sfx = get_sf(umax, 0);
    const float rsfx = 1.0f / sfx;
    if (tid < 32) {
        int oc = tid;
        float bsf = wsf0[oc] * sfx;
        float bint = rintf(bias0[oc] / bsf);
        float a = bsf * bns0[oc];
        As[oc] = a;
        Cs[oc] = fmaf(bint, a, bnb0[oc]);
    }
    for (int i = tid; i < 1944; i += 256) tile[i] = 0.f;
    if (tid < 216) ((float4*)wlds)[tid] = ((const float4*)w0kt)[tid];
    __syncthreads();
    const float* xb = x + (long)b * 3072;
    for (int i = tid; i < 1728; i += 256) {
        int ci = i / 576, rem = i - ci * 576;
        int rr = rem >> 5, cc = rem & 31;
        int gr = r0 - 1 + rr;
        if ((unsigned)gr < 32u)
            tile[ci * 648 + rr * 36 + cc + 1] = quantm(xb[ci * 1024 + gr * 32 + cc], rsfx);
    }
    __syncthreads();
    const int oc0  = (tid >> 5) * 4;
    const int pxg  = tid & 31;
    const int row  = pxg >> 1;
    const int wcol = (pxg & 1) * 16;
    float acc[4][16];
    #pragma unroll
    for (int o = 0; o < 4; ++o)
        #pragma unroll
        for (int p = 0; p < 16; ++p) acc[o][p] = 0.f;
    #pragma unroll 1
    for (int kk = 0; kk < 9; ++kk) {
        int ci = kk / 3, ky = kk - ci * 3;
        const float* rp = tile + ci * 648 + (row + ky) * 36 + wcol;
        float wn[20];
        #pragma unroll
        for (int d = 0; d < 5; ++d) *(float4*)&wn[4 * d] = *(const float4*)&rp[4 * d];
        #pragma unroll
        for (int kx = 0; kx < 3; ++kx) {
            float4 wv = *(const float4*)&wlds[(kk * 3 + kx) * 32 + oc0];
            const float* wf = &wv.x;
            #pragma unroll
            for (int o = 0; o < 4; ++o)
                #pragma unroll
                for (int p = 0; p < 16; ++p)
                    acc[o][p] = fmaf(wn[p + kx], wf[o], acc[o][p]);
        }
    }
    float lmax = 0.f;
    #pragma unroll
    for (int o = 0; o < 4; ++o) {
        float A = As[oc0 + o], C = Cs[oc0 + o];
        #pragma unroll
        for (int p = 0; p < 16; ++p)
            lmax = fmaxf(lmax, fabsf(fmaf(acc[o][p], A, C)));
    }
    block_max_atomic(lmax, mout);
}

// ---------------- conv0 pass 2 + fused 1x1 conv1. grid 2048 = (image, 16-row band) ----------------
__global__ __launch_bounds__(256) void k_conv01n(
    const float* __restrict__ x, const float* __restrict__ w0p,
    const float* __restrict__ wsf0, const float* __restrict__ bias0,
    const float* __restrict__ bns0, const float* __restrict__ bnb0,
    const float* __restrict__ w1i,
    const float* __restrict__ wsf1, const float* __restrict__ bias1,
    const float* __restrict__ bns1, const float* __restrict__ bnb1,
    const unsigned* __restrict__ umax, unsigned* __restrict__ mout,
    float* __restrict__ out) {
    __shared__ float tile[1944];   // [3][18][36]
    __shared__ float wls0[896];    // [32][28] padded
    __shared__ float wls1[128];    // [32][4] oc-major
    __shared__ float Aq[32], Cq[32];
    __shared__ float A1s[4], C1s[4];
    const int b  = blockIdx.x >> 1;
    const int r0 = (blockIdx.x & 1) * 16;
    const int tid = threadIdx.x;
    const float sfx = get_sf(umax, 0);
    const float rsfx = 1.0f / sfx;
    const float sf1 = get_sf(umax, 1);
    const float rsf1 = 1.0f / sf1;
    if (tid < 32) {
        int oc = tid;
        float bsf = wsf0[oc] * sfx;
        float bint = rintf(bias0[oc] / bsf);
        float a = bsf * bns0[oc];
        float c = fmaf(bint, a, bnb0[oc]);
        Aq[oc] = a * rsf1;
        Cq[oc] = c * rsf1;
    }
    if (tid >= 64 && tid < 68) {
        int oc = tid - 64;
        float bsf = wsf1[oc] * sf1;
        float bint = rintf(bias1[oc] / bsf);
        float a = bsf * bns1[oc];
        A1s[oc] = a;
        C1s[oc] = fmaf(bint, a, bnb1[oc]);
    }
    for (int i = tid; i < 1944; i += 256) tile[i] = 0.f;
    if (tid < 224) ((float4*)wls0)[tid] = ((const float4*)w0p)[tid];
    if (tid >= 128 && tid < 256) {
        int j = tid - 128;
        wls1[(j & 31) * 4 + (j >> 5)] = w1i[j];
    }
    __syncthreads();
    const float* xb = x + (long)b * 3072;
    for (int i = tid; i < 1728; i += 256) {
        int ci = i / 576, rem = i - ci * 576;
        int rr = rem >> 5, cc = rem & 31;
        int gr = r0 - 1 + rr;
        if ((unsigned)gr < 32u)
            tile[ci * 648 + rr * 36 + cc + 1] = quantm(xb[ci * 1024 + gr * 32 + cc], rsfx);
    }
    __syncthreads();
    const int h   = tid >> 4;
    const int w0c = (tid & 15) * 2;
    float win[3][3][4];
    #pragma unroll
    for (int ci = 0; ci < 3; ++ci)
        #pragma unroll
        for (int ky = 0; ky < 3; ++ky) {
            const int base = ci * 648 + (h + ky) * 36 + w0c;
            #pragma unroll
            for (int d = 0; d < 4; ++d) win[ci][ky][d] = tile[base + d];
        }
    float acc1[4][2];
    #pragma unroll
    for (int o = 0; o < 4; ++o) { acc1[o][0] = 0.f; acc1[o][1] = 0.f; }
    #pragma unroll 1
    for (int oc = 0; oc < 32; ++oc) {
        float wreg[28];
        const float4* wp4 = (const float4*)&wls0[oc * 28];
        #pragma unroll
        for (int d = 0; d < 7; ++d) *(float4*)&wreg[4 * d] = wp4[d];
        float a0 = 0.f, a1 = 0.f;
        #pragma unroll
        for (int ci = 0; ci < 3; ++ci)
            #pragma unroll
            for (int ky = 0; ky < 3; ++ky)
                #pragma unroll
                for (int kx = 0; kx < 3; ++kx) {
                    float wv = wreg[ci * 9 + ky * 3 + kx];
                    a0 = fmaf(win[ci][ky][kx],     wv, a0);
                    a1 = fmaf(win[ci][ky][kx + 1], wv, a1);
                }
        float A = Aq[oc], C = Cq[oc];
        float q0 = fminf(fmaxf(rintf(fmaf(a0, A, C)), -127.0f), 127.0f);
        float q1 = fminf(fmaxf(rintf(fmaf(a1, A, C)), -127.0f), 127.0f);
        const float4 w1v = *(const float4*)&wls1[oc * 4];
        acc1[0][0] = fmaf(q0, w1v.x, acc1[0][0]); acc1[0][1] = fmaf(q1, w1v.x, acc1[0][1]);
        acc1[1][0] = fmaf(q0, w1v.y, acc1[1][0]); acc1[1][1] = fmaf(q1, w1v.y, acc1[1][1]);
        acc1[2][0] = fmaf(q0, w1v.z, acc1[2][0]); acc1[2][1] = fmaf(q1, w1v.z, acc1[2][1]);
        acc1[3][0] = fmaf(q0, w1v.w, acc1[3][0]); acc1[3][1] = fmaf(q1, w1v.w, acc1[3][1]);
    }
    float lmax = 0.f;
    float* ob = out + (long)b * 4096 + (r0 + h) * 32 + w0c;
    #pragma unroll
    for (int o = 0; o < 4; ++o) {
        float y0 = fmaf(acc1[o][0], A1s[o], C1s[o]);
        float y1 = fmaf(acc1[o][1], A1s[o], C1s[o]);
        lmax = fmaxf(lmax, fmaxf(fabsf(y0), fabsf(y1)));
        float2 r2; r2.x = y0; r2.y = y1;
        *(float2*)&ob[o * 1024] = r2;
    }
    block_max_atomic(lmax, mout);
}

// ---------------- conv2 (4->32, 3x3, s2): thread = 8 oc x 4 px ----------------
__global__ __launch_bounds__(256) void k_conv2c(
    const float* __restrict__ inp, const float* __restrict__ w2kt,
    const float* __restrict__ wsf, const float* __restrict__ bias,
    const float* __restrict__ bns, const float* __restrict__ bnb,
    const unsigned* __restrict__ umax, unsigned* __restrict__ mout,
    float* __restrict__ out) {
    __shared__ float tile[4 * 34 * 36];   // 4896
    __shared__ float wlds[36 * 32];       // 1152, k-major
    __shared__ float As[32], Cs[32];
    const int tid = threadIdx.x;
    const float sf = get_sf(umax, 2);
    const float rsf = 1.0f / sf;
    if (tid < 32) {
        int oc = tid;
        float bsf = wsf[oc] * sf;
        float bint = rintf(bias[oc] / bsf);
        float a = bsf * bns[oc];
        As[oc] = a;
        Cs[oc] = fmaf(bint, a, bnb[oc]);
    }
    for (int i = tid; i < 4896; i += 256) tile[i] = 0.f;
    for (int i = tid; i < 288; i += 256) ((float4*)wlds)[i] = ((const float4*)w2kt)[i];
    __syncthreads();
    const float* ib = inp + (long)blockIdx.x * 4096;
    for (int i = tid; i < 4096; i += 256) {
        int ci = i >> 10, px = i & 1023;
        int iy = px >> 5, ix = px & 31;
        tile[ci * 1224 + (iy + 1) * 36 + (ix + 1)] = quantm(ib[i], rsf);
    }
    __syncthreads();
    const int oc0 = (tid >> 6) * 8;
    const int pxq = tid & 63;
    const int h = pxq >> 2, c = pxq & 3;
    float acc[8][4];
    #pragma unroll
    for (int k = 0; k < 8; ++k)
        #pragma unroll
        for (int p = 0; p < 4; ++p) acc[k][p] = 0.f;
    #pragma unroll 1
    for (int ci = 0; ci < 4; ++ci) {
        #pragma unroll
        for (int ky = 0; ky < 3; ++ky) {
            const float* rp = tile + ci * 1224 + (2 * h + ky) * 36 + 8 * c;
            float wn[12];
            #pragma unroll
            for (int d = 0; d < 3; ++d) *(float4*)&wn[4 * d] = *(const float4*)&rp[4 * d];
            #pragma unroll
            for (int kx = 0; kx < 3; ++kx) {
                const float* wp = &wlds[(ci * 9 + ky * 3 + kx) * 32 + oc0];
                float4 wa = *(const float4*)&wp[0];
                float4 wb = *(const float4*)&wp[4];
                float wf[8] = {wa.x, wa.y, wa.z, wa.w, wb.x, wb.y, wb.z, wb.w};
                #pragma unroll
                for (int k = 0; k < 8; ++k)
                    #pragma unroll
                    for (int p = 0; p < 4; ++p)
                        acc[k][p] = fmaf(wn[2 * p + kx], wf[k], acc[k][p]);
            }
        }
    }
    float lmax = 0.f;
    float* ob = out + (long)blockIdx.x * 8192;
    #pragma unroll
    for (int k = 0; k < 8; ++k) {
        int oc = oc0 + k;
        float A = As[oc], C = Cs[oc];
        float4 r;
        float* rp = &r.x;
        #pragma unroll
        for (int p = 0; p < 4; ++p) {
            float y = fmaf(acc[k][p], A, C);
            rp[p] = y;
            lmax = fmaxf(lmax, fabsf(y));
        }
        *(float4*)&ob[oc * 256 + h * 16 + c * 4] = r;
    }
    block_max_atomic(lmax, mout);
}

// ---------------- conv3/conv4: 1 img/block, 4oc x 2px, K-phased. grid 1024 ----------------
// weights pre-transposed to [4][72][36] -> staging is a straight f4 copy.
template<int HIN, int S>
__global__ __launch_bounds__(256) void k_conv34c(
    const float* __restrict__ inp, const float* __restrict__ wt,
    const float* __restrict__ wsf, const float* __restrict__ bias,
    const float* __restrict__ bns, const float* __restrict__ bnb,
    const unsigned* __restrict__ umax, int slot, unsigned* __restrict__ mout,
    float* __restrict__ out) {
    constexpr int ROWS = HIN + 2;
    constexpr int RS   = (S == 2) ? 20 : 12;
    constexpr int TI   = 8 * ROWS * RS;
    constexpr int PIX  = HIN * HIN;
    constexpr int NELT = 8 * PIX;
    constexpr int WINW = S + 3;
    __shared__ float tile[TI];
    __shared__ float wlds[72 * 36];
    __shared__ float As[32], Cs[32];
    const int tid = threadIdx.x;
    const int ocg = tid >> 5;
    const int pxq = tid & 31;
    const int h = pxq >> 2, c = pxq & 3;
    const float sf = get_sf(umax, slot);
    const float rsf = 1.0f / sf;
    if (tid < 32) {
        int oc = tid;
        float bsf = wsf[oc] * sf;
        float bint = rintf(bias[oc] / bsf);
        float a = bsf * bns[oc];
        As[oc] = a;
        Cs[oc] = fmaf(bint, a, bnb[oc]);
    }
    for (int i = tid; i < TI; i += 256) tile[i] = 0.f;
    float acc[4][2];
    #pragma unroll
    for (int k = 0; k < 4; ++k) { acc[k][0] = 0.f; acc[k][1] = 0.f; }
    const float* ib = inp + (long)blockIdx.x * 32 * PIX;
    const float4* wt4 = (const float4*)wt;
    for (int ph = 0; ph < 4; ++ph) {
        __syncthreads();
        for (int i = tid; i < NELT; i += 256) {
            int ci = i / PIX;
            int px = i - ci * PIX;
            int iy = px / HIN, ix = px & (HIN - 1);
            tile[ci * (ROWS * RS) + (iy + 1) * RS + (ix + 1)] =
                quantm(ib[(long)(ph * 8 + ci) * PIX + px], rsf);
        }
        for (int i = tid; i < 648; i += 256) ((float4*)wlds)[i] = wt4[ph * 648 + i];
        __syncthreads();
        #pragma unroll 2
        for (int ci = 0; ci < 8; ++ci) {
            float win[3][WINW];
            #pragma unroll
            for (int ky = 0; ky < 3; ++ky) {
                const int base = ci * (ROWS * RS) + (S * h + ky) * RS + S * 2 * c;
                #pragma unroll
                for (int d = 0; d < WINW; ++d) win[ky][d] = tile[base + d];
            }
            #pragma unroll
            for (int ky = 0; ky < 3; ++ky)
                #pragma unroll
                for (int kx = 0; kx < 3; ++kx) {
                    int j = ky * 3 + kx;
                    float4 wv = *(const float4*)&wlds[(ci * 9 + j) * 36 + ocg * 4];
                    float x0 = win[ky][kx], x1 = win[ky][S + kx];
                    acc[0][0] = fmaf(x0, wv.x, acc[0][0]); acc[0][1] = fmaf(x1, wv.x, acc[0][1]);
                    acc[1][0] = fmaf(x0, wv.y, acc[1][0]); acc[1][1] = fmaf(x1, wv.y, acc[1][1]);
                    acc[2][0] = fmaf(x0, wv.z, acc[2][0]); acc[2][1] = fmaf(x1, wv.z, acc[2][1]);
                    acc[3][0] = fmaf(x0, wv.w, acc[3][0]); acc[3][1] = fmaf(x1, wv.w, acc[3][1]);
                }
        }
    }
    float lmax = 0.f;
    #pragma unroll
    for (int k = 0; k < 4; ++k) {
        int oc = ocg * 4 + k;
        float A = As[oc], C = Cs[oc];
        float y0 = fmaf(acc[k][0], A, C);
        float y1 = fmaf(acc[k][1], A, C);
        lmax = fmaxf(lmax, fmaxf(fabsf(y0), fabsf(y1)));
        float2 r2; r2.x = y0; r2.y = y1;
        *(float2*)&out[((long)blockIdx.x * 32 + oc) * 64 + h * 8 + c * 2] = r2;
    }
    block_max_atomic(lmax, mout);
}

// ---------------- linear 2048->10 per image ----------------
__global__ __launch_bounds__(256) void k_fc(
    const float* __restrict__ act, const float* __restrict__ wdi,
    const float* __restrict__ wsfd, const float* __restrict__ bd,
    const unsigned* __restrict__ umax, float* __restrict__ logits) {
    int b = blockIdx.x;
    float sf = get_sf(umax, 5);
    float rsf = 1.0f / sf;
    const float* ab = act + (long)b * 2048;
    float acc[10];
    #pragma unroll
    for (int c = 0; c < 10; ++c) acc[c] = 0.f;
    #pragma unroll
    for (int k = 0; k < 8; ++k) {
        int j = threadIdx.x + 256 * k;
        float q = quantm(ab[j], rsf);
        #pragma unroll
        for (int c = 0; c < 10; ++c) acc[c] = fmaf(q, wdi[c * 2048 + j], acc[c]);
    }
    #pragma unroll
    for (int c = 0; c < 10; ++c)
        #pragma unroll
        for (int o = 32; o; o >>= 1) acc[c] += __shfl_down(acc[c], o, 64);
    __shared__ float red[4][10];
    int wid = threadIdx.x >> 6;
    if ((threadIdx.x & 63) == 0)
        #pragma unroll
        for (int c = 0; c < 10; ++c) red[wid][c] = acc[c];
    __syncthreads();
    if (threadIdx.x < 10) {
        int c = threadIdx.x;
        float s = red[0][c] + red[1][c] + red[2][c] + red[3][c];
        float bsf = wsfd[c] * sf;
        float bint = rintf(bd[c] / bsf);
        logits[b * 10 + c] = (s + bint) * bsf;
    }
}

// ---------------- softmax over batch axis (dim 0) ----------------
__global__ __launch_bounds__(256) void k_softmax(const float* __restrict__ logits, float* __restrict__ out) {
    int c = blockIdx.x;
    float v0 = logits[(threadIdx.x +   0) * 10 + c];
    float v1 = logits[(threadIdx.x + 256) * 10 + c];
    float v2 = logits[(threadIdx.x + 512) * 10 + c];
    float v3 = logits[(threadIdx.x + 768) * 10 + c];
    float mx = fmaxf(fmaxf(v0, v1), fmaxf(v2, v3));
    __shared__ float redm[4];
    __shared__ float reds[4];
    #pragma unroll
    for (int o = 32; o; o >>= 1) mx = fmaxf(mx, __shfl_down(mx, o, 64));
    if ((threadIdx.x & 63) == 0) redm[threadIdx.x >> 6] = mx;
    __syncthreads();
    mx = fmaxf(fmaxf(redm[0], redm[1]), fmaxf(redm[2], redm[3]));
    float e0 = expf(v0 - mx), e1 = expf(v1 - mx), e2 = expf(v2 - mx), e3 = expf(v3 - mx);
    float s = (e0 + e1) + (e2 + e3);
    #pragma unroll
    for (int o = 32; o; o >>= 1) s += __shfl_down(s, o, 64);
    if ((threadIdx.x & 63) == 0) reds[threadIdx.x >> 6] = s;
    __syncthreads();
    s = reds[0] + reds[1] + reds[2] + reds[3];
    out[(threadIdx.x +   0) * 10 + c] = e0 / s;
    out[(threadIdx.x + 256) * 10 + c] = e1 / s;
    out[(threadIdx.x + 512) * 10 + c] = e2 / s;
    out[(threadIdx.x + 768) * 10 + c] = e3 / s;
}

extern "C" void kernel_launch(void* const* d_in, const int* in_sizes, int n_in,
                              void* d_out, int out_size, void* d_ws, size_t ws_size,
                              hipStream_t stream) {
    (void)in_sizes; (void)n_in; (void)out_size; (void)ws_size;
    const float* x = (const float*)d_in[0];
    const float *w[5], *bia[5], *g[5], *bb[5], *m[5], *v[5];
    for (int i = 0; i < 5; ++i) {
        w[i]   = (const float*)d_in[1 + 6 * i + 0];
        bia[i] = (const float*)d_in[1 + 6 * i + 1];
        g[i]   = (const float*)d_in[1 + 6 * i + 2];
        bb[i]  = (const float*)d_in[1 + 6 * i + 3];
        m[i]   = (const float*)d_in[1 + 6 * i + 4];
        v[i]   = (const float*)d_in[1 + 6 * i + 5];
    }
    const float* wd = (const float*)d_in[31];
    const float* bd = (const float*)d_in[32];
    float* ws = (float*)d_ws;
    unsigned* umax = (unsigned*)ws;   // [6][64] buckets
    float* out = (float*)d_out;

    float* w0kt = ws + OFF_W0KT;
    float* w0p  = ws + OFF_W0P;
    float* w1i  = ws + OFF_W1I;
    float* w2kt = ws + OFF_W2KT;
    float* w3t  = ws + OFF_W3T;
    float* w4t  = ws + OFF_W4T;
    float* wdi  = ws + OFF_WDI;
    float* wsf0 = ws + OFF_WSF0; float* bns0 = ws + OFF_BNS0; float* bnb0 = ws + OFF_BNB0;
    float* wsf1 = ws + OFF_WSF1; float* bns1 = ws + OFF_BNS1; float* bnb1 = ws + OFF_BNB1;
    float* wsf2 = ws + OFF_WSF2; float* bns2 = ws + OFF_BNS2; float* bnb2 = ws + OFF_BNB2;
    float* wsf3 = ws + OFF_WSF3; float* bns3 = ws + OFF_BNS3; float* bnb3 = ws + OFF_BNB3;
    float* wsf4 = ws + OFF_WSF4; float* bns4 = ws + OFF_BNS4; float* bnb4 = ws + OFF_BNB4;
    float* wsfd = ws + OFF_WSFD;
    float* logits = ws + OFF_LOG;
    float* actA = ws + ACT_A_OFF;   // act2 / act4
    float* actB = ws + ACT_B_OFF;   // act1 / act3

    PrepAll pa;
    pa.umax = umax;
    const float* ww[6] = {w[0], w[1], w[2], w[3], w[4], wd};
    float* wsfp[6] = {wsf0, wsf1, wsf2, wsf3, wsf4, wsfd};
    float* dstp[6] = {w0kt, w1i, w2kt, w3t, w4t, wdi};
    float* dst2p[6] = {w0p, nullptr, nullptr, nullptr, nullptr, nullptr};
    float* bnsp[6] = {bns0, bns1, bns2, bns3, bns4, nullptr};
    float* bnbp[6] = {bnb0, bnb1, bnb2, bnb3, bnb4, nullptr};
    int Ks[6]   = {27, 32, 36, 288, 288, 2048};
    int modes[6] = {2, 0, 1, 3, 3, 0};
    for (int i = 0; i < 6; ++i) {
        pa.e[i].w = ww[i];
        pa.e[i].g = (i < 5) ? g[i] : nullptr;
        pa.e[i].bb = (i < 5) ? bb[i] : nullptr;
        pa.e[i].m = (i < 5) ? m[i] : nullptr;
        pa.e[i].v = (i < 5) ? v[i] : nullptr;
        pa.e[i].wsf = wsfp[i];
        pa.e[i].dst = dstp[i];
        pa.e[i].dst2 = dst2p[i];
        pa.e[i].bns = bnsp[i];
        pa.e[i].bnb = bnbp[i];
        pa.e[i].K = Ks[i];
        pa.e[i].has_bn = (i < 5) ? 1 : 0;
        pa.e[i].mode = modes[i];
    }

    hipLaunchKernelGGL(k_prep_all, dim3(143), dim3(256), 0, stream, pa);
    hipLaunchKernelGGL(k_absmax, dim3(1024), dim3(256), 0, stream,
                       (const float4*)x, 1024 * 3 * 32 * 32 / 4, umax + 0 * 64);
    hipLaunchKernelGGL(k_conv0maxN, dim3(2048), dim3(256), 0, stream,
                       x, w0kt, wsf0, bia[0], bns0, bnb0, umax, umax + 1 * 64);
    hipLaunchKernelGGL(k_conv01n, dim3(2048), dim3(256), 0, stream,
                       x, w0p, wsf0, bia[0], bns0, bnb0,
                       w1i, wsf1, bia[1], bns1, bnb1, umax, umax + 2 * 64, actB);
    hipLaunchKernelGGL(k_conv2c, dim3(1024), dim3(256), 0, stream,
                       actB, w2kt, wsf2, bia[2], bns2, bnb2, umax, umax + 3 * 64, actA);
    hipLaunchKernelGGL((k_conv34c<16, 2>), dim3(1024), dim3(256), 0, stream,
                       actA, w3t, wsf3, bia[3], bns3, bnb3, umax, 3, umax + 4 * 64, actB);
    hipLaunchKernelGGL((k_conv34c<8, 1>),  dim3(1024), dim3(256), 0, stream,
                       actB, w4t, wsf4, bia[4], bns4, bnb4, umax, 4, umax + 5 * 64, actA);
    hipLaunchKernelGGL(k_fc, dim3(1024), dim3(256), 0, stream, actA, wdi, wsfd, bd, umax, logits);
    hipLaunchKernelGGL(k_softmax, dim3(10), dim3(256), 0, stream, logits, out);
}

// Round 15
// 176.008 us; speedup vs baseline: 2.2784x; 1.0027x over previous
//
#include <hip/hip_runtime.h>

#define DI __device__ __forceinline__

// ---------------- ws layout (float offsets) ----------------
// umax[6][64] buckets (uint32) at 0..384
constexpr int OFF_W0KT = 384;     // 27*32 (k-major, conv0maxN)
constexpr int OFF_W0P  = 1248;    // 32*28 (padded oc-major, conv01n)
constexpr int OFF_W1I  = 2144;    // 4*32
constexpr int OFF_W2KT = 2272;    // 36*32 (k-major, conv2c)
constexpr int OFF_W3T  = 3424;    // 4*72*36 (phase-k-major, conv3)
constexpr int OFF_W4T  = 13792;   // 10368
constexpr int OFF_WDI  = 24160;   // 20480
constexpr int OFF_WSF0 = 44640;
constexpr int OFF_BNS0 = 44672;
constexpr int OFF_BNB0 = 44704;
constexpr int OFF_WSF1 = 44736;
constexpr int OFF_BNS1 = 44740;
constexpr int OFF_BNB1 = 44744;
constexpr int OFF_WSF2 = 44748;
constexpr int OFF_BNS2 = 44780;
constexpr int OFF_BNB2 = 44812;
constexpr int OFF_WSF3 = 44844;
constexpr int OFF_BNS3 = 44876;
constexpr int OFF_BNB3 = 44908;
constexpr int OFF_WSF4 = 44940;
constexpr int OFF_BNS4 = 44972;
constexpr int OFF_BNB4 = 45004;
constexpr int OFF_WSFD = 45036;   // 10
constexpr int OFF_LOG  = 45056;   // 10240
constexpr int OFF_ACT  = 55296;
constexpr long ACT_A_OFF = OFF_ACT;              // act2/act4
constexpr long ACT_B_OFF = OFF_ACT + 8388608L;   // act1/act3

// ---------------- helpers ----------------
DI float quantm(float x, float rsf) {
    float q = rintf(x * rsf);
    return fminf(fmaxf(q, -127.0f), 127.0f);
}
DI float get_sf(const unsigned* umax, int slot) {
    const unsigned* p = umax + slot * 64;
    unsigned m = 0u;
    #pragma unroll
    for (int i = 0; i < 64; ++i) m = m > p[i] ? m : p[i];
    return fmaxf(__uint_as_float(m) / 127.0f, 1e-8f);
}
DI void block_max_atomic(float v, unsigned* dst) {
    __shared__ float redm_[4];
    #pragma unroll
    for (int o = 32; o; o >>= 1) v = fmaxf(v, __shfl_down(v, o, 64));
    int wid = threadIdx.x >> 6;
    if ((threadIdx.x & 63) == 0) redm_[wid] = v;
    __syncthreads();
    if (threadIdx.x == 0) {
        int nw = blockDim.x >> 6;
        float m = redm_[0];
        for (int i = 1; i < nw; ++i) m = fmaxf(m, redm_[i]);
        atomicMax(dst + (blockIdx.x & 63), __float_as_uint(m));
    }
}

// ---------------- prep: weight quant + BN fold + layout transposes ----------------
struct PrepEntry {
    const float *w, *g, *bb, *m, *v;
    float *wsf, *dst, *dst2, *bns, *bnb;
    int K; int has_bn; int mode;
};
struct PrepAll { PrepEntry e[6]; unsigned* umax; };

__global__ __launch_bounds__(256) void k_prep_all(PrepAll pa) {
    int blk = blockIdx.x;
    if (blk == 142) {
        for (int i = threadIdx.x; i < 384; i += 256) pa.umax[i] = 0u;
        return;
    }
    int layer, oc;
    if      (blk < 32)  { layer = 0; oc = blk; }
    else if (blk < 36)  { layer = 1; oc = blk - 32; }
    else if (blk < 68)  { layer = 2; oc = blk - 36; }
    else if (blk < 100) { layer = 3; oc = blk - 68; }
    else if (blk < 132) { layer = 4; oc = blk - 100; }
    else                { layer = 5; oc = blk - 132; }
    PrepEntry a = pa.e[layer];
    const float* wr = a.w + (long)oc * a.K;
    float mx = 0.f;
    for (int i = threadIdx.x; i < a.K; i += 256) mx = fmaxf(mx, fabsf(wr[i]));
    __shared__ float red[4];
    __shared__ float s_sf;
    #pragma unroll
    for (int o = 32; o; o >>= 1) mx = fmaxf(mx, __shfl_down(mx, o, 64));
    if ((threadIdx.x & 63) == 0) red[threadIdx.x >> 6] = mx;
    __syncthreads();
    if (threadIdx.x == 0) {
        float t = fmaxf(fmaxf(red[0], red[1]), fmaxf(red[2], red[3]));
        t = fmaxf(t / 127.0f, 1e-8f);
        a.wsf[oc] = t; s_sf = t;
        if (a.has_bn) {
            float inv = a.g[oc] / sqrtf(a.v[oc] + 1e-5f);
            a.bns[oc] = inv;
            a.bnb[oc] = a.bb[oc] - a.m[oc] * inv;
        }
    }
    __syncthreads();
    float sf = s_sf;
    for (int i = threadIdx.x; i < a.K; i += 256) {
        float q = rintf(wr[i] / sf);
        if (a.mode == 0) {
            a.dst[(long)oc * a.K + i] = q;
        } else if (a.mode == 1) {
            a.dst[i * 32 + oc] = q;
        } else if (a.mode == 2) {
            a.dst[i * 32 + oc] = q;
            a.dst2[oc * 28 + i] = q;
        } else {
            int ph = i / 72, kk = i - ph * 72;
            a.dst[ph * 2592 + kk * 36 + oc] = q;
        }
    }
    if (a.mode == 2 && threadIdx.x == 0) a.dst2[oc * 28 + 27] = 0.f;
}

__global__ __launch_bounds__(256) void k_absmax(const float4* __restrict__ x, int n4, unsigned* dst) {
    float m = 0.f;
    for (int i = blockIdx.x * blockDim.x + threadIdx.x; i < n4; i += gridDim.x * blockDim.x) {
        float4 t = x[i];
        m = fmaxf(m, fmaxf(fmaxf(fabsf(t.x), fabsf(t.y)), fmaxf(fabsf(t.z), fabsf(t.w))));
    }
    block_max_atomic(m, dst);
}

// ---------------- conv0 pass 1: max only. grid 2048 = (image, row-half) ----------------
__global__ __launch_bounds__(256) void k_conv0maxN(
    const float* __restrict__ x, const float* __restrict__ w0kt,
    const float* __restrict__ wsf0, const float* __restrict__ bias0,
    const float* __restrict__ bns0, const float* __restrict__ bnb0,
    const unsigned* __restrict__ umax, unsigned* __restrict__ mout) {
    __shared__ float tile[3 * 18 * 36];   // 1944
    __shared__ float wlds[27 * 32];       // 864, k-major
    __shared__ float As[32], Cs[32];
    const int b  = blockIdx.x >> 1;
    const int r0 = (blockIdx.x & 1) * 16;
    const int tid = threadIdx.x;
    const float sfx = get_sf(umax, 0);
    const float rsfx = 1.0f / sfx;
    if (tid < 32) {
        int oc = tid;
        float bsf = wsf0[oc] * sfx;
        float bint = rintf(bias0[oc] / bsf);
        float a = bsf * bns0[oc];
        As[oc] = a;
        Cs[oc] = fmaf(bint, a, bnb0[oc]);
    }
    for (int i = tid; i < 1944; i += 256) tile[i] = 0.f;
    if (tid < 216) ((float4*)wlds)[tid] = ((const float4*)w0kt)[tid];
    __syncthreads();
    const float* xb = x + (long)b * 3072;
    for (int i = tid; i < 1728; i += 256) {
        int ci = i / 576, rem = i - ci * 576;
        int rr = rem >> 5, cc = rem & 31;
        int gr = r0 - 1 + rr;
        if ((unsigned)gr < 32u)
            tile[ci * 648 + rr * 36 + cc + 1] = quantm(xb[ci * 1024 + gr * 32 + cc], rsfx);
    }
    __syncthreads();
    const int oc0  = (tid >> 5) * 4;
    const int pxg  = tid & 31;
    const int row  = pxg >> 1;
    const int wcol = (pxg & 1) * 16;
    float acc[4][16];
    #pragma unroll
    for (int o = 0; o < 4; ++o)
        #pragma unroll
        for (int p = 0; p < 16; ++p) acc[o][p] = 0.f;
    #pragma unroll 1
    for (int kk = 0; kk < 9; ++kk) {
        int ci = kk / 3, ky = kk - ci * 3;
        const float* rp = tile + ci * 648 + (row + ky) * 36 + wcol;
        float wn[20];
        #pragma unroll
        for (int d = 0; d < 5; ++d) *(float4*)&wn[4 * d] = *(const float4*)&rp[4 * d];
        #pragma unroll
        for (int kx = 0; kx < 3; ++kx) {
            float4 wv = *(const float4*)&wlds[(kk * 3 + kx) * 32 + oc0];
            const float* wf = &wv.x;
            #pragma unroll
            for (int o = 0; o < 4; ++o)
                #pragma unroll
                for (int p = 0; p < 16; ++p)
                    acc[o][p] = fmaf(wn[p + kx], wf[o], acc[o][p]);
        }
    }
    float lmax = 0.f;
    #pragma unroll
    for (int o = 0; o < 4; ++o) {
        float A = As[oc0 + o], C = Cs[oc0 + o];
        #pragma unroll
        for (int p = 0; p < 16; ++p)
            lmax = fmaxf(lmax, fabsf(fmaf(acc[o][p], A, C)));
    }
    block_max_atomic(lmax, mout);
}

// ---------------- conv0 pass 2 + fused 1x1 conv1. grid 1024 = 1 image/block ----------------
// thread = 4 px, all 32 oc sequential; quant folded; f4/f2 window loads.
__global__ __launch_bounds__(256) void k_conv01n(
    const float* __restrict__ x, const float* __restrict__ w0p,
    const float* __restrict__ wsf0, const float* __restrict__ bias0,
    const float* __restrict__ bns0, const float* __restrict__ bnb0,
    const float* __restrict__ w1i,
    const float* __restrict__ wsf1, const float* __restrict__ bias1,
    const float* __restrict__ bns1, const float* __restrict__ bnb1,
    const unsigned* __restrict__ umax, unsigned* __restrict__ mout,
    float* __restrict__ out) {
    __shared__ float tile[3672];   // [3][34][36]
    __shared__ float wls0[896];    // [32][28] padded
    __shared__ float wls1[128];    // [32][4] oc-major
    __shared__ float Aq[32], Cq[32];
    __shared__ float A1s[4], C1s[4];
    const int b   = blockIdx.x;
    const int tid = threadIdx.x;
    const float sfx = get_sf(umax, 0);
    const float rsfx = 1.0f / sfx;
    const float sf1 = get_sf(umax, 1);
    const float rsf1 = 1.0f / sf1;
    if (tid < 32) {
        int oc = tid;
        float bsf = wsf0[oc] * sfx;
        float bint = rintf(bias0[oc] / bsf);
        float a = bsf * bns0[oc];
        float c = fmaf(bint, a, bnb0[oc]);
        Aq[oc] = a * rsf1;
        Cq[oc] = c * rsf1;
    }
    if (tid >= 64 && tid < 68) {
        int oc = tid - 64;
        float bsf = wsf1[oc] * sf1;
        float bint = rintf(bias1[oc] / bsf);
        float a = bsf * bns1[oc];
        A1s[oc] = a;
        C1s[oc] = fmaf(bint, a, bnb1[oc]);
    }
    for (int i = tid; i < 3672; i += 256) tile[i] = 0.f;
    if (tid < 224) ((float4*)wls0)[tid] = ((const float4*)w0p)[tid];
    if (tid >= 128 && tid < 256) {
        int j = tid - 128;
        wls1[(j & 31) * 4 + (j >> 5)] = w1i[j];
    }
    __syncthreads();
    const float* xb = x + (long)b * 3072;
    for (int i = tid; i < 3072; i += 256) {
        int ci = i >> 10, px = i & 1023;
        int iy = px >> 5, ix = px & 31;
        tile[ci * 1224 + (iy + 1) * 36 + (ix + 1)] = quantm(xb[i], rsfx);
    }
    __syncthreads();
    const int h   = tid >> 3;          // 0..31 out row
    const int w0c = (tid & 7) * 4;     // 0..28 out col base (16B-aligned window)
    float win[3][3][6];
    #pragma unroll
    for (int ci = 0; ci < 3; ++ci)
        #pragma unroll
        for (int ky = 0; ky < 3; ++ky) {
            const int base = ci * 1224 + (h + ky) * 36 + w0c;
            *(float4*)&win[ci][ky][0] = *(const float4*)&tile[base];
            *(float2*)&win[ci][ky][4] = *(const float2*)&tile[base + 4];
        }
    float acc1[4][4];
    #pragma unroll
    for (int o = 0; o < 4; ++o)
        #pragma unroll
        for (int p = 0; p < 4; ++p) acc1[o][p] = 0.f;
    #pragma unroll 1
    for (int oc = 0; oc < 32; ++oc) {
        float wreg[28];
        const float4* wp4 = (const float4*)&wls0[oc * 28];
        #pragma unroll
        for (int d = 0; d < 7; ++d) *(float4*)&wreg[4 * d] = wp4[d];
        float a0 = 0.f, a1 = 0.f, a2 = 0.f, a3 = 0.f;
        #pragma unroll
        for (int ci = 0; ci < 3; ++ci)
            #pragma unroll
            for (int ky = 0; ky < 3; ++ky)
                #pragma unroll
                for (int kx = 0; kx < 3; ++kx) {
                    float wv = wreg[ci * 9 + ky * 3 + kx];
                    a0 = fmaf(win[ci][ky][kx + 0], wv, a0);
                    a1 = fmaf(win[ci][ky][kx + 1], wv, a1);
                    a2 = fmaf(win[ci][ky][kx + 2], wv, a2);
                    a3 = fmaf(win[ci][ky][kx + 3], wv, a3);
                }
        float A = Aq[oc], C = Cq[oc];
        float q0 = fminf(fmaxf(rintf(fmaf(a0, A, C)), -127.0f), 127.0f);
        float q1 = fminf(fmaxf(rintf(fmaf(a1, A, C)), -127.0f), 127.0f);
        float q2 = fminf(fmaxf(rintf(fmaf(a2, A, C)), -127.0f), 127.0f);
        float q3 = fminf(fmaxf(rintf(fmaf(a3, A, C)), -127.0f), 127.0f);
        const float4 w1v = *(const float4*)&wls1[oc * 4];
        acc1[0][0] = fmaf(q0, w1v.x, acc1[0][0]); acc1[0][1] = fmaf(q1, w1v.x, acc1[0][1]);
        acc1[0][2] = fmaf(q2, w1v.x, acc1[0][2]); acc1[0][3] = fmaf(q3, w1v.x, acc1[0][3]);
        acc1[1][0] = fmaf(q0, w1v.y, acc1[1][0]); acc1[1][1] = fmaf(q1, w1v.y, acc1[1][1]);
        acc1[1][2] = fmaf(q2, w1v.y, acc1[1][2]); acc1[1][3] = fmaf(q3, w1v.y, acc1[1][3]);
        acc1[2][0] = fmaf(q0, w1v.z, acc1[2][0]); acc1[2][1] = fmaf(q1, w1v.z, acc1[2][1]);
        acc1[2][2] = fmaf(q2, w1v.z, acc1[2][2]); acc1[2][3] = fmaf(q3, w1v.z, acc1[2][3]);
        acc1[3][0] = fmaf(q0, w1v.w, acc1[3][0]); acc1[3][1] = fmaf(q1, w1v.w, acc1[3][1]);
        acc1[3][2] = fmaf(q2, w1v.w, acc1[3][2]); acc1[3][3] = fmaf(q3, w1v.w, acc1[3][3]);
    }
    float lmax = 0.f;
    float* ob = out + (long)b * 4096 + h * 32 + w0c;
    #pragma unroll
    for (int o = 0; o < 4; ++o) {
        float y0 = fmaf(acc1[o][0], A1s[o], C1s[o]);
        float y1 = fmaf(acc1[o][1], A1s[o], C1s[o]);
        float y2 = fmaf(acc1[o][2], A1s[o], C1s[o]);
        float y3 = fmaf(acc1[o][3], A1s[o], C1s[o]);
        lmax = fmaxf(lmax, fmaxf(fmaxf(fabsf(y0), fabsf(y1)), fmaxf(fabsf(y2), fabsf(y3))));
        float4 r4; r4.x = y0; r4.y = y1; r4.z = y2; r4.w = y3;
        *(float4*)&ob[o * 1024] = r4;
    }
    block_max_atomic(lmax, mout);
}

// ---------------- conv2 (4->32, 3x3, s2): thread = 8 oc x 4 px ----------------
__global__ __launch_bounds__(256) void k_conv2c(
    const float* __restrict__ inp, const float* __restrict__ w2kt,
    const float* __restrict__ wsf, const float* __restrict__ bias,
    const float* __restrict__ bns, const float* __restrict__ bnb,
    const unsigned* __restrict__ umax, unsigned* __restrict__ mout,
    float* __restrict__ out) {
    __shared__ float tile[4 * 34 * 36];
    __shared__ float wlds[36 * 32];
    __shared__ float As[32], Cs[32];
    const int tid = threadIdx.x;
    const float sf = get_sf(umax, 2);
    const float rsf = 1.0f / sf;
    if (tid < 32) {
        int oc = tid;
        float bsf = wsf[oc] * sf;
        float bint = rintf(bias[oc] / bsf);
        float a = bsf * bns[oc];
        As[oc] = a;
        Cs[oc] = fmaf(bint, a, bnb[oc]);
    }
    for (int i = tid; i < 4896; i += 256) tile[i] = 0.f;
    for (int i = tid; i < 288; i += 256) ((float4*)wlds)[i] = ((const float4*)w2kt)[i];
    __syncthreads();
    const float* ib = inp + (long)blockIdx.x * 4096;
    for (int i = tid; i < 4096; i += 256) {
        int ci = i >> 10, px = i & 1023;
        int iy = px >> 5, ix = px & 31;
        tile[ci * 1224 + (iy + 1) * 36 + (ix + 1)] = quantm(ib[i], rsf);
    }
    __syncthreads();
    const int oc0 = (tid >> 6) * 8;
    const int pxq = tid & 63;
    const int h = pxq >> 2, c = pxq & 3;
    float acc[8][4];
    #pragma unroll
    for (int k = 0; k < 8; ++k)
        #pragma unroll
        for (int p = 0; p < 4; ++p) acc[k][p] = 0.f;
    #pragma unroll 1
    for (int ci = 0; ci < 4; ++ci) {
        #pragma unroll
        for (int ky = 0; ky < 3; ++ky) {
            const float* rp = tile + ci * 1224 + (2 * h + ky) * 36 + 8 * c;
            float wn[12];
            #pragma unroll
            for (int d = 0; d < 3; ++d) *(float4*)&wn[4 * d] = *(const float4*)&rp[4 * d];
            #pragma unroll
            for (int kx = 0; kx < 3; ++kx) {
                const float* wp = &wlds[(ci * 9 + ky * 3 + kx) * 32 + oc0];
                float4 wa = *(const float4*)&wp[0];
                float4 wb = *(const float4*)&wp[4];
                float wf[8] = {wa.x, wa.y, wa.z, wa.w, wb.x, wb.y, wb.z, wb.w};
                #pragma unroll
                for (int k = 0; k < 8; ++k)
                    #pragma unroll
                    for (int p = 0; p < 4; ++p)
                        acc[k][p] = fmaf(wn[2 * p + kx], wf[k], acc[k][p]);
            }
        }
    }
    float lmax = 0.f;
    float* ob = out + (long)blockIdx.x * 8192;
    #pragma unroll
    for (int k = 0; k < 8; ++k) {
        int oc = oc0 + k;
        float A = As[oc], C = Cs[oc];
        float4 r;
        float* rp = &r.x;
        #pragma unroll
        for (int p = 0; p < 4; ++p) {
            float y = fmaf(acc[k][p], A, C);
            rp[p] = y;
            lmax = fmaxf(lmax, fabsf(y));
        }
        *(float4*)&ob[oc * 256 + h * 16 + c * 4] = r;
    }
    block_max_atomic(lmax, mout);
}

// ---------------- conv3/conv4: 1 img/block, 4oc x 2px, K-phased. grid 1024 ----------------
// pre-transposed weights (f4 copy); vectorized window loads.
template<int HIN, int S>
__global__ __launch_bounds__(256) void k_conv34c(
    const float* __restrict__ inp, const float* __restrict__ wt,
    const float* __restrict__ wsf, const float* __restrict__ bias,
    const float* __restrict__ bns, const float* __restrict__ bnb,
    const unsigned* __restrict__ umax, int slot, unsigned* __restrict__ mout,
    float* __restrict__ out) {
    constexpr int ROWS = HIN + 2;
    constexpr int RS   = (S == 2) ? 20 : 12;
    constexpr int TI   = 8 * ROWS * RS;
    constexpr int PIX  = HIN * HIN;
    constexpr int NELT = 8 * PIX;
    constexpr int WINW = S + 3;
    __shared__ float tile[TI];
    __shared__ float wlds[72 * 36];
    __shared__ float As[32], Cs[32];
    const int tid = threadIdx.x;
    const int ocg = tid >> 5;
    const int pxq = tid & 31;
    const int h = pxq >> 2, c = pxq & 3;
    const float sf = get_sf(umax, slot);
    const float rsf = 1.0f / sf;
    if (tid < 32) {
        int oc = tid;
        float bsf = wsf[oc] * sf;
        float bint = rintf(bias[oc] / bsf);
        float a = bsf * bns[oc];
        As[oc] = a;
        Cs[oc] = fmaf(bint, a, bnb[oc]);
    }
    for (int i = tid; i < TI; i += 256) tile[i] = 0.f;
    float acc[4][2];
    #pragma unroll
    for (int k = 0; k < 4; ++k) { acc[k][0] = 0.f; acc[k][1] = 0.f; }
    const float* ib = inp + (long)blockIdx.x * 32 * PIX;
    const float4* wt4 = (const float4*)wt;
    for (int ph = 0; ph < 4; ++ph) {
        __syncthreads();
        for (int i = tid; i < NELT; i += 256) {
            int ci = i / PIX;
            int px = i - ci * PIX;
            int iy = px / HIN, ix = px & (HIN - 1);
            tile[ci * (ROWS * RS) + (iy + 1) * RS + (ix + 1)] =
                quantm(ib[(long)(ph * 8 + ci) * PIX + px], rsf);
        }
        for (int i = tid; i < 648; i += 256) ((float4*)wlds)[i] = wt4[ph * 648 + i];
        __syncthreads();
        #pragma unroll 2
        for (int ci = 0; ci < 8; ++ci) {
            float win[3][WINW];
            #pragma unroll
            for (int ky = 0; ky < 3; ++ky) {
                const int base = ci * (ROWS * RS) + (S * h + ky) * RS + S * 2 * c;
                if (S == 2) {
                    // base 16B-aligned: f4 + scalar (WINW=5)
                    *(float4*)&win[ky][0] = *(const float4*)&tile[base];
                    win[ky][4] = tile[base + 4];
                } else {
                    // base 8B-aligned: 2x f2 (WINW=4)
                    *(float2*)&win[ky][0] = *(const float2*)&tile[base];
                    *(float2*)&win[ky][2] = *(const float2*)&tile[base + 2];
                }
            }
            #pragma unroll
            for (int ky = 0; ky < 3; ++ky)
                #pragma unroll
                for (int kx = 0; kx < 3; ++kx) {
                    int j = ky * 3 + kx;
                    float4 wv = *(const float4*)&wlds[(ci * 9 + j) * 36 + ocg * 4];
                    float x0 = win[ky][kx], x1 = win[ky][S + kx];
                    acc[0][0] = fmaf(x0, wv.x, acc[0][0]); acc[0][1] = fmaf(x1, wv.x, acc[0][1]);
                    acc[1][0] = fmaf(x0, wv.y, acc[1][0]); acc[1][1] = fmaf(x1, wv.y, acc[1][1]);
                    acc[2][0] = fmaf(x0, wv.z, acc[2][0]); acc[2][1] = fmaf(x1, wv.z, acc[2][1]);
                    acc[3][0] = fmaf(x0, wv.w, acc[3][0]); acc[3][1] = fmaf(x1, wv.w, acc[3][1]);
                }
        }
    }
    float lmax = 0.f;
    #pragma unroll
    for (int k = 0; k < 4; ++k) {
        int oc = ocg * 4 + k;
        float A = As[oc], C = Cs[oc];
        float y0 = fmaf(acc[k][0], A, C);
        float y1 = fmaf(acc[k][1], A, C);
        lmax = fmaxf(lmax, fmaxf(fabsf(y0), fabsf(y1)));
        float2 r2; r2.x = y0; r2.y = y1;
        *(float2*)&out[((long)blockIdx.x * 32 + oc) * 64 + h * 8 + c * 2] = r2;
    }
    block_max_atomic(lmax, mout);
}

// ---------------- linear 2048->10 per image ----------------
__global__ __launch_bounds__(256) void k_fc(
    const float* __restrict__ act, const float* __restrict__ wdi,
    const float* __restrict__ wsfd, const float* __restrict__ bd,
    const unsigned* __restrict__ umax, float* __restrict__ logits) {
    int b = blockIdx.x;
    float sf = get_sf(umax, 5);
    float rsf = 1.0f / sf;
    const float* ab = act + (long)b * 2048;
    float acc[10];
    #pragma unroll
    for (int c = 0; c < 10; ++c) acc[c] = 0.f;
    #pragma unroll
    for (int k = 0; k < 8; ++k) {
        int j = threadIdx.x + 256 * k;
        float q = quantm(ab[j], rsf);
        #pragma unroll
        for (int c = 0; c < 10; ++c) acc[c] = fmaf(q, wdi[c * 2048 + j], acc[c]);
    }
    #pragma unroll
    for (int c = 0; c < 10; ++c)
        #pragma unroll
        for (int o = 32; o; o >>= 1) acc[c] += __shfl_down(acc[c], o, 64);
    __shared__ float red[4][10];
    int wid = threadIdx.x >> 6;
    if ((threadIdx.x & 63) == 0)
        #pragma unroll
        for (int c = 0; c < 10; ++c) red[wid][c] = acc[c];
    __syncthreads();
    if (threadIdx.x < 10) {
        int c = threadIdx.x;
        float s = red[0][c] + red[1][c] + red[2][c] + red[3][c];
        float bsf = wsfd[c] * sf;
        float bint = rintf(bd[c] / bsf);
        logits[b * 10 + c] = (s + bint) * bsf;
    }
}

// ---------------- softmax over batch axis (dim 0) ----------------
__global__ __launch_bounds__(256) void k_softmax(const float* __restrict__ logits, float* __restrict__ out) {
    int c = blockIdx.x;
    float v0 = logits[(threadIdx.x +   0) * 10 + c];
    float v1 = logits[(threadIdx.x + 256) * 10 + c];
    float v2 = logits[(threadIdx.x + 512) * 10 + c];
    float v3 = logits[(threadIdx.x + 768) * 10 + c];
    float mx = fmaxf(fmaxf(v0, v1), fmaxf(v2, v3));
    __shared__ float redm[4];
    __shared__ float reds[4];
    #pragma unroll
    for (int o = 32; o; o >>= 1) mx = fmaxf(mx, __shfl_down(mx, o, 64));
    if ((threadIdx.x & 63) == 0) redm[threadIdx.x >> 6] = mx;
    __syncthreads();
    mx = fmaxf(fmaxf(redm[0], redm[1]), fmaxf(redm[2], redm[3]));
    float e0 = expf(v0 - mx), e1 = expf(v1 - mx), e2 = expf(v2 - mx), e3 = expf(v3 - mx);
    float s = (e0 + e1) + (e2 + e3);
    #pragma unroll
    for (int o = 32; o; o >>= 1) s += __shfl_down(s, o, 64);
    if ((threadIdx.x & 63) == 0) reds[threadIdx.x >> 6] = s;
    __syncthreads();
    s = reds[0] + reds[1] + reds[2] + reds[3];
    out[(threadIdx.x +   0) * 10 + c] = e0 / s;
    out[(threadIdx.x + 256) * 10 + c] = e1 / s;
    out[(threadIdx.x + 512) * 10 + c] = e2 / s;
    out[(threadIdx.x + 768) * 10 + c] = e3 / s;
}

extern "C" void kernel_launch(void* const* d_in, const int* in_sizes, int n_in,
                              void* d_out, int out_size, void* d_ws, size_t ws_size,
                              hipStream_t stream) {
    (void)in_sizes; (void)n_in; (void)out_size; (void)ws_size;
    const float* x = (const float*)d_in[0];
    const float *w[5], *bia[5], *g[5], *bb[5], *m[5], *v[5];
    for (int i = 0; i < 5; ++i) {
        w[i]   = (const float*)d_in[1 + 6 * i + 0];
        bia[i] = (const float*)d_in[1 + 6 * i + 1];
        g[i]   = (const float*)d_in[1 + 6 * i + 2];
        bb[i]  = (const float*)d_in[1 + 6 * i + 3];
        m[i]   = (const float*)d_in[1 + 6 * i + 4];
        v[i]   = (const float*)d_in[1 + 6 * i + 5];
    }
    const float* wd = (const float*)d_in[31];
    const float* bd = (const float*)d_in[32];
    float* ws = (float*)d_ws;
    unsigned* umax = (unsigned*)ws;   // [6][64] buckets
    float* out = (float*)d_out;

    float* w0kt = ws + OFF_W0KT;
    float* w0p  = ws + OFF_W0P;
    float* w1i  = ws + OFF_W1I;
    float* w2kt = ws + OFF_W2KT;
    float* w3t  = ws + OFF_W3T;
    float* w4t  = ws + OFF_W4T;
    float* wdi  = ws + OFF_WDI;
    float* wsf0 = ws + OFF_WSF0; float* bns0 = ws + OFF_BNS0; float* bnb0 = ws + OFF_BNB0;
    float* wsf1 = ws + OFF_WSF1; float* bns1 = ws + OFF_BNS1; float* bnb1 = ws + OFF_BNB1;
    float* wsf2 = ws + OFF_WSF2; float* bns2 = ws + OFF_BNS2; float* bnb2 = ws + OFF_BNB2;
    float* wsf3 = ws + OFF_WSF3; float* bns3 = ws + OFF_BNS3; float* bnb3 = ws + OFF_BNB3;
    float* wsf4 = ws + OFF_WSF4; float* bns4 = ws + OFF_BNS4; float* bnb4 = ws + OFF_BNB4;
    float* wsfd = ws + OFF_WSFD;
    float* logits = ws + OFF_LOG;
    float* actA = ws + ACT_A_OFF;   // act2 / act4
    float* actB = ws + ACT_B_OFF;   // act1 / act3

    PrepAll pa;
    pa.umax = umax;
    const float* ww[6] = {w[0], w[1], w[2], w[3], w[4], wd};
    float* wsfp[6] = {wsf0, wsf1, wsf2, wsf3, wsf4, wsfd};
    float* dstp[6] = {w0kt, w1i, w2kt, w3t, w4t, wdi};
    float* dst2p[6] = {w0p, nullptr, nullptr, nullptr, nullptr, nullptr};
    float* bnsp[6] = {bns0, bns1, bns2, bns3, bns4, nullptr};
    float* bnbp[6] = {bnb0, bnb1, bnb2, bnb3, bnb4, nullptr};
    int Ks[6]   = {27, 32, 36, 288, 288, 2048};
    int modes[6] = {2, 0, 1, 3, 3, 0};
    for (int i = 0; i < 6; ++i) {
        pa.e[i].w = ww[i];
        pa.e[i].g = (i < 5) ? g[i] : nullptr;
        pa.e[i].bb = (i < 5) ? bb[i] : nullptr;
        pa.e[i].m = (i < 5) ? m[i] : nullptr;
        pa.e[i].v = (i < 5) ? v[i] : nullptr;
        pa.e[i].wsf = wsfp[i];
        pa.e[i].dst = dstp[i];
        pa.e[i].dst2 = dst2p[i];
        pa.e[i].bns = bnsp[i];
        pa.e[i].bnb = bnbp[i];
        pa.e[i].K = Ks[i];
        pa.e[i].has_bn = (i < 5) ? 1 : 0;
        pa.e[i].mode = modes[i];
    }

    hipLaunchKernelGGL(k_prep_all, dim3(143), dim3(256), 0, stream, pa);
    hipLaunchKernelGGL(k_absmax, dim3(1024), dim3(256), 0, stream,
                       (const float4*)x, 1024 * 3 * 32 * 32 / 4, umax + 0 * 64);
    hipLaunchKernelGGL(k_conv0maxN, dim3(2048), dim3(256), 0, stream,
                       x, w0kt, wsf0, bia[0], bns0, bnb0, umax, umax + 1 * 64);
    hipLaunchKernelGGL(k_conv01n, dim3(1024), dim3(256), 0, stream,
                       x, w0p, wsf0, bia[0], bns0, bnb0,
                       w1i, wsf1, bia[1], bns1, bnb1, umax, umax + 2 * 64, actB);
    hipLaunchKernelGGL(k_conv2c, dim3(1024), dim3(256), 0, stream,
                       actB, w2kt, wsf2, bia[2], bns2, bnb2, umax, umax + 3 * 64, actA);
    hipLaunchKernelGGL((k_conv34c<16, 2>), dim3(1024), dim3(256), 0, stream,
                       actA, w3t, wsf3, bia[3], bns3, bnb3, umax, 3, umax + 4 * 64, actB);
    hipLaunchKernelGGL((k_conv34c<8, 1>),  dim3(1024), dim3(256), 0, stream,
                       actB, w4t, wsf4, bia[4], bns4, bnb4, umax, 4, umax + 5 * 64, actA);
    hipLaunchKernelGGL(k_fc, dim3(1024), dim3(256), 0, stream, actA, wdi, wsfd, bd, umax, logits);
    hipLaunchKernelGGL(k_softmax, dim3(10), dim3(256), 0, stream, logits, out);
}

// Round 16
// 164.618 us; speedup vs baseline: 2.4361x; 1.0692x over previous
//
#include <hip/hip_runtime.h>

#define DI __device__ __forceinline__

// ---------------- ws layout (float offsets) ----------------
// umax[6][64] buckets (uint32) at 0..384
constexpr int OFF_W0KT = 384;     // 27*32 (k-major, conv0maxN)
constexpr int OFF_W0P  = 1248;    // 32*28 (padded oc-major, conv01n)
constexpr int OFF_W1I  = 2144;    // 4*32
constexpr int OFF_W2KT = 2272;    // 36*32 (k-major, conv2c)
constexpr int OFF_W3T  = 3424;    // 4*72*36 (phase-k-major, conv3)
constexpr int OFF_W4T  = 13792;   // 10368
constexpr int OFF_WDI  = 24160;   // 20480
constexpr int OFF_WSF0 = 44640;
constexpr int OFF_BNS0 = 44672;
constexpr int OFF_BNB0 = 44704;
constexpr int OFF_WSF1 = 44736;
constexpr int OFF_BNS1 = 44740;
constexpr int OFF_BNB1 = 44744;
constexpr int OFF_WSF2 = 44748;
constexpr int OFF_BNS2 = 44780;
constexpr int OFF_BNB2 = 44812;
constexpr int OFF_WSF3 = 44844;
constexpr int OFF_BNS3 = 44876;
constexpr int OFF_BNB3 = 44908;
constexpr int OFF_WSF4 = 44940;
constexpr int OFF_BNS4 = 44972;
constexpr int OFF_BNB4 = 45004;
constexpr int OFF_WSFD = 45036;   // 10
constexpr int OFF_LOG  = 45056;   // 10240
constexpr int OFF_ACT  = 55296;
constexpr long ACT_A_OFF = OFF_ACT;              // act2/act4
constexpr long ACT_B_OFF = OFF_ACT + 8388608L;   // act1/act3

// ---------------- helpers ----------------
DI float quantm(float x, float rsf) {
    float q = rintf(x * rsf);
    return fminf(fmaxf(q, -127.0f), 127.0f);
}
DI float get_sf(const unsigned* umax, int slot) {
    const unsigned* p = umax + slot * 64;
    unsigned m = 0u;
    #pragma unroll
    for (int i = 0; i < 64; ++i) m = m > p[i] ? m : p[i];
    return fmaxf(__uint_as_float(m) / 127.0f, 1e-8f);
}
DI void block_max_atomic(float v, unsigned* dst) {
    __shared__ float redm_[4];
    #pragma unroll
    for (int o = 32; o; o >>= 1) v = fmaxf(v, __shfl_down(v, o, 64));
    int wid = threadIdx.x >> 6;
    if ((threadIdx.x & 63) == 0) redm_[wid] = v;
    __syncthreads();
    if (threadIdx.x == 0) {
        int nw = blockDim.x >> 6;
        float m = redm_[0];
        for (int i = 1; i < nw; ++i) m = fmaxf(m, redm_[i]);
        atomicMax(dst + (blockIdx.x & 63), __float_as_uint(m));
    }
}

// ---------------- prep: weight quant + BN fold + layout transposes ----------------
struct PrepEntry {
    const float *w, *g, *bb, *m, *v;
    float *wsf, *dst, *dst2, *bns, *bnb;
    int K; int has_bn; int mode;
};
struct PrepAll { PrepEntry e[6]; unsigned* umax; };

__global__ __launch_bounds__(256) void k_prep_all(PrepAll pa) {
    int blk = blockIdx.x;
    if (blk == 142) {
        for (int i = threadIdx.x; i < 384; i += 256) pa.umax[i] = 0u;
        return;
    }
    int layer, oc;
    if      (blk < 32)  { layer = 0; oc = blk; }
    else if (blk < 36)  { layer = 1; oc = blk - 32; }
    else if (blk < 68)  { layer = 2; oc = blk - 36; }
    else if (blk < 100) { layer = 3; oc = blk - 68; }
    else if (blk < 132) { layer = 4; oc = blk - 100; }
    else                { layer = 5; oc = blk - 132; }
    PrepEntry a = pa.e[layer];
    const float* wr = a.w + (long)oc * a.K;
    float mx = 0.f;
    for (int i = threadIdx.x; i < a.K; i += 256) mx = fmaxf(mx, fabsf(wr[i]));
    __shared__ float red[4];
    __shared__ float s_sf;
    #pragma unroll
    for (int o = 32; o; o >>= 1) mx = fmaxf(mx, __shfl_down(mx, o, 64));
    if ((threadIdx.x & 63) == 0) red[threadIdx.x >> 6] = mx;
    __syncthreads();
    if (threadIdx.x == 0) {
        float t = fmaxf(fmaxf(red[0], red[1]), fmaxf(red[2], red[3]));
        t = fmaxf(t / 127.0f, 1e-8f);
        a.wsf[oc] = t; s_sf = t;
        if (a.has_bn) {
            float inv = a.g[oc] / sqrtf(a.v[oc] + 1e-5f);
            a.bns[oc] = inv;
            a.bnb[oc] = a.bb[oc] - a.m[oc] * inv;
        }
    }
    __syncthreads();
    float sf = s_sf;
    for (int i = threadIdx.x; i < a.K; i += 256) {
        float q = rintf(wr[i] / sf);
        if (a.mode == 0) {
            a.dst[(long)oc * a.K + i] = q;
        } else if (a.mode == 1) {
            a.dst[i * 32 + oc] = q;
        } else if (a.mode == 2) {
            a.dst[i * 32 + oc] = q;
            a.dst2[oc * 28 + i] = q;
        } else {
            int ph = i / 72, kk = i - ph * 72;
            a.dst[ph * 2592 + kk * 36 + oc] = q;
        }
    }
    if (a.mode == 2 && threadIdx.x == 0) a.dst2[oc * 28 + 27] = 0.f;
}

__global__ __launch_bounds__(256) void k_absmax(const float4* __restrict__ x, int n4, unsigned* dst) {
    float m = 0.f;
    for (int i = blockIdx.x * blockDim.x + threadIdx.x; i < n4; i += gridDim.x * blockDim.x) {
        float4 t = x[i];
        m = fmaxf(m, fmaxf(fmaxf(fabsf(t.x), fabsf(t.y)), fmaxf(fabsf(t.z), fabsf(t.w))));
    }
    block_max_atomic(m, dst);
}

// ---------------- conv0 pass 1: max only. grid 2048 = (image, row-half) ----------------
__global__ __launch_bounds__(256) void k_conv0maxN(
    const float* __restrict__ x, const float* __restrict__ w0kt,
    const float* __restrict__ wsf0, const float* __restrict__ bias0,
    const float* __restrict__ bns0, const float* __restrict__ bnb0,
    const unsigned* __restrict__ umax, unsigned* __restrict__ mout) {
    __shared__ float tile[3 * 18 * 36];   // 1944
    __shared__ float wlds[27 * 32];       // 864, k-major
    __shared__ float As[32], Cs[32];
    const int b  = blockIdx.x >> 1;
    const int r0 = (blockIdx.x & 1) * 16;
    const int tid = threadIdx.x;
    const float sfx = get_sf(umax, 0);
    const float rsfx = 1.0f / sfx;
    if (tid < 32) {
        int oc = tid;
        float bsf = wsf0[oc] * sfx;
        float bint = rintf(bias0[oc] / bsf);
        float a = bsf * bns0[oc];
        As[oc] = a;
        Cs[oc] = fmaf(bint, a, bnb0[oc]);
    }
    for (int i = tid; i < 1944; i += 256) tile[i] = 0.f;
    if (tid < 216) ((float4*)wlds)[tid] = ((const float4*)w0kt)[tid];
    __syncthreads();
    const float* xb = x + (long)b * 3072;
    for (int i = tid; i < 1728; i += 256) {
        int ci = i / 576, rem = i - ci * 576;
        int rr = rem >> 5, cc = rem & 31;
        int gr = r0 - 1 + rr;
        if ((unsigned)gr < 32u)
            tile[ci * 648 + rr * 36 + cc + 1] = quantm(xb[ci * 1024 + gr * 32 + cc], rsfx);
    }
    __syncthreads();
    const int oc0  = (tid >> 5) * 4;
    const int pxg  = tid & 31;
    const int row  = pxg >> 1;
    const int wcol = (pxg & 1) * 16;
    float acc[4][16];
    #pragma unroll
    for (int o = 0; o < 4; ++o)
        #pragma unroll
        for (int p = 0; p < 16; ++p) acc[o][p] = 0.f;
    #pragma unroll 1
    for (int kk = 0; kk < 9; ++kk) {
        int ci = kk / 3, ky = kk - ci * 3;
        const float* rp = tile + ci * 648 + (row + ky) * 36 + wcol;
        float wn[20];
        #pragma unroll
        for (int d = 0; d < 5; ++d) *(float4*)&wn[4 * d] = *(const float4*)&rp[4 * d];
        #pragma unroll
        for (int kx = 0; kx < 3; ++kx) {
            float4 wv = *(const float4*)&wlds[(kk * 3 + kx) * 32 + oc0];
            const float* wf = &wv.x;
            #pragma unroll
            for (int o = 0; o < 4; ++o)
                #pragma unroll
                for (int p = 0; p < 16; ++p)
                    acc[o][p] = fmaf(wn[p + kx], wf[o], acc[o][p]);
        }
    }
    float lmax = 0.f;
    #pragma unroll
    for (int o = 0; o < 4; ++o) {
        float A = As[oc0 + o], C = Cs[oc0 + o];
        #pragma unroll
        for (int p = 0; p < 16; ++p)
            lmax = fmaxf(lmax, fabsf(fmaf(acc[o][p], A, C)));
    }
    block_max_atomic(lmax, mout);
}

// ---------------- conv0 pass 2 + fused 1x1 conv1. grid 1024 = 1 image/block ----------------
__global__ __launch_bounds__(256) void k_conv01n(
    const float* __restrict__ x, const float* __restrict__ w0p,
    const float* __restrict__ wsf0, const float* __restrict__ bias0,
    const float* __restrict__ bns0, const float* __restrict__ bnb0,
    const float* __restrict__ w1i,
    const float* __restrict__ wsf1, const float* __restrict__ bias1,
    const float* __restrict__ bns1, const float* __restrict__ bnb1,
    const unsigned* __restrict__ umax, unsigned* __restrict__ mout,
    float* __restrict__ out) {
    __shared__ float tile[3672];   // [3][34][36]
    __shared__ float wls0[896];    // [32][28] padded
    __shared__ float wls1[128];    // [32][4] oc-major
    __shared__ float Aq[32], Cq[32];
    __shared__ float A1s[4], C1s[4];
    const int b   = blockIdx.x;
    const int tid = threadIdx.x;
    const float sfx = get_sf(umax, 0);
    const float rsfx = 1.0f / sfx;
    const float sf1 = get_sf(umax, 1);
    const float rsf1 = 1.0f / sf1;
    if (tid < 32) {
        int oc = tid;
        float bsf = wsf0[oc] * sfx;
        float bint = rintf(bias0[oc] / bsf);
        float a = bsf * bns0[oc];
        float c = fmaf(bint, a, bnb0[oc]);
        Aq[oc] = a * rsf1;
        Cq[oc] = c * rsf1;
    }
    if (tid >= 64 && tid < 68) {
        int oc = tid - 64;
        float bsf = wsf1[oc] * sf1;
        float bint = rintf(bias1[oc] / bsf);
        float a = bsf * bns1[oc];
        A1s[oc] = a;
        C1s[oc] = fmaf(bint, a, bnb1[oc]);
    }
    for (int i = tid; i < 3672; i += 256) tile[i] = 0.f;
    if (tid < 224) ((float4*)wls0)[tid] = ((const float4*)w0p)[tid];
    if (tid >= 128 && tid < 256) {
        int j = tid - 128;
        wls1[(j & 31) * 4 + (j >> 5)] = w1i[j];
    }
    __syncthreads();
    const float* xb = x + (long)b * 3072;
    for (int i = tid; i < 3072; i += 256) {
        int ci = i >> 10, px = i & 1023;
        int iy = px >> 5, ix = px & 31;
        tile[ci * 1224 + (iy + 1) * 36 + (ix + 1)] = quantm(xb[i], rsfx);
    }
    __syncthreads();
    const int h   = tid >> 3;
    const int w0c = (tid & 7) * 4;
    float win[3][3][6];
    #pragma unroll
    for (int ci = 0; ci < 3; ++ci)
        #pragma unroll
        for (int ky = 0; ky < 3; ++ky) {
            const int base = ci * 1224 + (h + ky) * 36 + w0c;
            *(float4*)&win[ci][ky][0] = *(const float4*)&tile[base];
            *(float2*)&win[ci][ky][4] = *(const float2*)&tile[base + 4];
        }
    float acc1[4][4];
    #pragma unroll
    for (int o = 0; o < 4; ++o)
        #pragma unroll
        for (int p = 0; p < 4; ++p) acc1[o][p] = 0.f;
    #pragma unroll 1
    for (int oc = 0; oc < 32; ++oc) {
        float wreg[28];
        const float4* wp4 = (const float4*)&wls0[oc * 28];
        #pragma unroll
        for (int d = 0; d < 7; ++d) *(float4*)&wreg[4 * d] = wp4[d];
        float a0 = 0.f, a1 = 0.f, a2 = 0.f, a3 = 0.f;
        #pragma unroll
        for (int ci = 0; ci < 3; ++ci)
            #pragma unroll
            for (int ky = 0; ky < 3; ++ky)
                #pragma unroll
                for (int kx = 0; kx < 3; ++kx) {
                    float wv = wreg[ci * 9 + ky * 3 + kx];
                    a0 = fmaf(win[ci][ky][kx + 0], wv, a0);
                    a1 = fmaf(win[ci][ky][kx + 1], wv, a1);
                    a2 = fmaf(win[ci][ky][kx + 2], wv, a2);
                    a3 = fmaf(win[ci][ky][kx + 3], wv, a3);
                }
        float A = Aq[oc], C = Cq[oc];
        float q0 = fminf(fmaxf(rintf(fmaf(a0, A, C)), -127.0f), 127.0f);
        float q1 = fminf(fmaxf(rintf(fmaf(a1, A, C)), -127.0f), 127.0f);
        float q2 = fminf(fmaxf(rintf(fmaf(a2, A, C)), -127.0f), 127.0f);
        float q3 = fminf(fmaxf(rintf(fmaf(a3, A, C)), -127.0f), 127.0f);
        const float4 w1v = *(const float4*)&wls1[oc * 4];
        acc1[0][0] = fmaf(q0, w1v.x, acc1[0][0]); acc1[0][1] = fmaf(q1, w1v.x, acc1[0][1]);
        acc1[0][2] = fmaf(q2, w1v.x, acc1[0][2]); acc1[0][3] = fmaf(q3, w1v.x, acc1[0][3]);
        acc1[1][0] = fmaf(q0, w1v.y, acc1[1][0]); acc1[1][1] = fmaf(q1, w1v.y, acc1[1][1]);
        acc1[1][2] = fmaf(q2, w1v.y, acc1[1][2]); acc1[1][3] = fmaf(q3, w1v.y, acc1[1][3]);
        acc1[2][0] = fmaf(q0, w1v.z, acc1[2][0]); acc1[2][1] = fmaf(q1, w1v.z, acc1[2][1]);
        acc1[2][2] = fmaf(q2, w1v.z, acc1[2][2]); acc1[2][3] = fmaf(q3, w1v.z, acc1[2][3]);
        acc1[3][0] = fmaf(q0, w1v.w, acc1[3][0]); acc1[3][1] = fmaf(q1, w1v.w, acc1[3][1]);
        acc1[3][2] = fmaf(q2, w1v.w, acc1[3][2]); acc1[3][3] = fmaf(q3, w1v.w, acc1[3][3]);
    }
    float lmax = 0.f;
    float* ob = out + (long)b * 4096 + h * 32 + w0c;
    #pragma unroll
    for (int o = 0; o < 4; ++o) {
        float y0 = fmaf(acc1[o][0], A1s[o], C1s[o]);
        float y1 = fmaf(acc1[o][1], A1s[o], C1s[o]);
        float y2 = fmaf(acc1[o][2], A1s[o], C1s[o]);
        float y3 = fmaf(acc1[o][3], A1s[o], C1s[o]);
        lmax = fmaxf(lmax, fmaxf(fmaxf(fabsf(y0), fabsf(y1)), fmaxf(fabsf(y2), fabsf(y3))));
        float4 r4; r4.x = y0; r4.y = y1; r4.z = y2; r4.w = y3;
        *(float4*)&ob[o * 1024] = r4;
    }
    block_max_atomic(lmax, mout);
}

// ---------------- conv2 (4->32, 3x3, s2): thread = 8 oc x 4 px ----------------
__global__ __launch_bounds__(256) void k_conv2c(
    const float* __restrict__ inp, const float* __restrict__ w2kt,
    const float* __restrict__ wsf, const float* __restrict__ bias,
    const float* __restrict__ bns, const float* __restrict__ bnb,
    const unsigned* __restrict__ umax, unsigned* __restrict__ mout,
    float* __restrict__ out) {
    __shared__ float tile[4 * 34 * 36];
    __shared__ float wlds[36 * 32];
    __shared__ float As[32], Cs[32];
    const int tid = threadIdx.x;
    const float sf = get_sf(umax, 2);
    const float rsf = 1.0f / sf;
    if (tid < 32) {
        int oc = tid;
        float bsf = wsf[oc] * sf;
        float bint = rintf(bias[oc] / bsf);
        float a = bsf * bns[oc];
        As[oc] = a;
        Cs[oc] = fmaf(bint, a, bnb[oc]);
    }
    for (int i = tid; i < 4896; i += 256) tile[i] = 0.f;
    for (int i = tid; i < 288; i += 256) ((float4*)wlds)[i] = ((const float4*)w2kt)[i];
    __syncthreads();
    const float* ib = inp + (long)blockIdx.x * 4096;
    for (int i = tid; i < 4096; i += 256) {
        int ci = i >> 10, px = i & 1023;
        int iy = px >> 5, ix = px & 31;
        tile[ci * 1224 + (iy + 1) * 36 + (ix + 1)] = quantm(ib[i], rsf);
    }
    __syncthreads();
    const int oc0 = (tid >> 6) * 8;
    const int pxq = tid & 63;
    const int h = pxq >> 2, c = pxq & 3;
    float acc[8][4];
    #pragma unroll
    for (int k = 0; k < 8; ++k)
        #pragma unroll
        for (int p = 0; p < 4; ++p) acc[k][p] = 0.f;
    #pragma unroll 1
    for (int ci = 0; ci < 4; ++ci) {
        #pragma unroll
        for (int ky = 0; ky < 3; ++ky) {
            const float* rp = tile + ci * 1224 + (2 * h + ky) * 36 + 8 * c;
            float wn[12];
            #pragma unroll
            for (int d = 0; d < 3; ++d) *(float4*)&wn[4 * d] = *(const float4*)&rp[4 * d];
            #pragma unroll
            for (int kx = 0; kx < 3; ++kx) {
                const float* wp = &wlds[(ci * 9 + ky * 3 + kx) * 32 + oc0];
                float4 wa = *(const float4*)&wp[0];
                float4 wb = *(const float4*)&wp[4];
                float wf[8] = {wa.x, wa.y, wa.z, wa.w, wb.x, wb.y, wb.z, wb.w};
                #pragma unroll
                for (int k = 0; k < 8; ++k)
                    #pragma unroll
                    for (int p = 0; p < 4; ++p)
                        acc[k][p] = fmaf(wn[2 * p + kx], wf[k], acc[k][p]);
            }
        }
    }
    float lmax = 0.f;
    float* ob = out + (long)blockIdx.x * 8192;
    #pragma unroll
    for (int k = 0; k < 8; ++k) {
        int oc = oc0 + k;
        float A = As[oc], C = Cs[oc];
        float4 r;
        float* rp = &r.x;
        #pragma unroll
        for (int p = 0; p < 4; ++p) {
            float y = fmaf(acc[k][p], A, C);
            rp[p] = y;
            lmax = fmaxf(lmax, fabsf(y));
        }
        *(float4*)&ob[oc * 256 + h * 16 + c * 4] = r;
    }
    block_max_atomic(lmax, mout);
}

// ---------------- conv3/conv4: 2 img/block, 4oc x 4px, K-phased. grid 512 ----------------
// pre-transposed weights (f4 staging), f4 window loads, pow-2 indexing.
template<int HIN, int S>
__global__ __launch_bounds__(256) void k_conv34d(
    const float* __restrict__ inp, const float* __restrict__ wt,
    const float* __restrict__ wsf, const float* __restrict__ bias,
    const float* __restrict__ bns, const float* __restrict__ bnb,
    const unsigned* __restrict__ umax, int slot, unsigned* __restrict__ mout,
    float* __restrict__ out) {
    constexpr int ROWS = HIN + 2;
    constexpr int RS   = (S == 2) ? 20 : 12;
    constexpr int TI   = 8 * ROWS * RS;
    constexpr int PIX  = HIN * HIN;             // pow2
    constexpr int PSH  = (HIN == 16) ? 8 : 6;   // log2(PIX)
    constexpr int HSH  = (HIN == 16) ? 4 : 3;   // log2(HIN)
    constexpr int NELT = 2 * 8 * PIX;
    constexpr int WINW = (S == 2) ? 12 : 8;
    constexpr int ND   = (S == 2) ? 3 : 2;
    __shared__ float tile[2 * TI];
    __shared__ float wlds[2592];
    __shared__ float As[32], Cs[32];
    const int tid  = threadIdx.x;
    const int imgl = tid >> 7;
    const int ocg  = (tid >> 4) & 7;
    const int pxq  = tid & 15;
    const int h = pxq >> 1, c = pxq & 1;
    const float sf = get_sf(umax, slot);
    const float rsf = 1.0f / sf;
    if (tid < 32) {
        int oc = tid;
        float bsf = wsf[oc] * sf;
        float bint = rintf(bias[oc] / bsf);
        float a = bsf * bns[oc];
        As[oc] = a;
        Cs[oc] = fmaf(bint, a, bnb[oc]);
    }
    for (int i = tid; i < 2 * TI; i += 256) tile[i] = 0.f;
    float acc[4][4];
    #pragma unroll
    for (int k = 0; k < 4; ++k)
        #pragma unroll
        for (int p = 0; p < 4; ++p) acc[k][p] = 0.f;
    const float* ib = inp + (long)blockIdx.x * 2 * 32 * PIX;
    const float4* wt4 = (const float4*)wt;
    for (int ph = 0; ph < 4; ++ph) {
        __syncthreads();
        for (int i = tid; i < NELT; i += 256) {
            int im = i >> (PSH + 3);
            int ci = (i >> PSH) & 7;
            int px = i & (PIX - 1);
            int iy = px >> HSH, ix = px & (HIN - 1);
            tile[im * TI + ci * (ROWS * RS) + (iy + 1) * RS + (ix + 1)] =
                quantm(ib[(long)((im * 32 + ph * 8 + ci) << PSH) + px], rsf);
        }
        for (int i = tid; i < 648; i += 256) ((float4*)wlds)[i] = wt4[ph * 648 + i];
        __syncthreads();
        const int tbo = imgl * TI;
        #pragma unroll 2
        for (int ci = 0; ci < 8; ++ci) {
            float win[3][WINW];
            #pragma unroll
            for (int ky = 0; ky < 3; ++ky) {
                const int base = tbo + ci * (ROWS * RS) + (S * h + ky) * RS + S * 4 * c;
                #pragma unroll
                for (int d = 0; d < ND; ++d)
                    *(float4*)&win[ky][4 * d] = *(const float4*)&tile[base + 4 * d];
            }
            #pragma unroll
            for (int ky = 0; ky < 3; ++ky)
                #pragma unroll
                for (int kx = 0; kx < 3; ++kx) {
                    int j = ky * 3 + kx;
                    float4 wv = *(const float4*)&wlds[(ci * 9 + j) * 36 + ocg * 4];
                    float x0 = win[ky][S * 0 + kx];
                    float x1 = win[ky][S * 1 + kx];
                    float x2 = win[ky][S * 2 + kx];
                    float x3 = win[ky][S * 3 + kx];
                    acc[0][0] = fmaf(x0, wv.x, acc[0][0]); acc[0][1] = fmaf(x1, wv.x, acc[0][1]);
                    acc[0][2] = fmaf(x2, wv.x, acc[0][2]); acc[0][3] = fmaf(x3, wv.x, acc[0][3]);
                    acc[1][0] = fmaf(x0, wv.y, acc[1][0]); acc[1][1] = fmaf(x1, wv.y, acc[1][1]);
                    acc[1][2] = fmaf(x2, wv.y, acc[1][2]); acc[1][3] = fmaf(x3, wv.y, acc[1][3]);
                    acc[2][0] = fmaf(x0, wv.z, acc[2][0]); acc[2][1] = fmaf(x1, wv.z, acc[2][1]);
                    acc[2][2] = fmaf(x2, wv.z, acc[2][2]); acc[2][3] = fmaf(x3, wv.z, acc[2][3]);
                    acc[3][0] = fmaf(x0, wv.w, acc[3][0]); acc[3][1] = fmaf(x1, wv.w, acc[3][1]);
                    acc[3][2] = fmaf(x2, wv.w, acc[3][2]); acc[3][3] = fmaf(x3, wv.w, acc[3][3]);
                }
        }
    }
    float lmax = 0.f;
    long imgg = (long)blockIdx.x * 2 + imgl;
    #pragma unroll
    for (int k = 0; k < 4; ++k) {
        int oc = ocg * 4 + k;
        float A = As[oc], C = Cs[oc];
        float y0 = fmaf(acc[k][0], A, C);
        float y1 = fmaf(acc[k][1], A, C);
        float y2 = fmaf(acc[k][2], A, C);
        float y3 = fmaf(acc[k][3], A, C);
        lmax = fmaxf(lmax, fmaxf(fmaxf(fabsf(y0), fabsf(y1)), fmaxf(fabsf(y2), fabsf(y3))));
        float4 r4; r4.x = y0; r4.y = y1; r4.z = y2; r4.w = y3;
        *(float4*)&out[(imgg * 32 + oc) * 64 + h * 8 + c * 4] = r4;
    }
    block_max_atomic(lmax, mout);
}

// ---------------- linear 2048->10 per image ----------------
__global__ __launch_bounds__(256) void k_fc(
    const float* __restrict__ act, const float* __restrict__ wdi,
    const float* __restrict__ wsfd, const float* __restrict__ bd,
    const unsigned* __restrict__ umax, float* __restrict__ logits) {
    int b = blockIdx.x;
    float sf = get_sf(umax, 5);
    float rsf = 1.0f / sf;
    const float* ab = act + (long)b * 2048;
    float acc[10];
    #pragma unroll
    for (int c = 0; c < 10; ++c) acc[c] = 0.f;
    #pragma unroll
    for (int k = 0; k < 8; ++k) {
        int j = threadIdx.x + 256 * k;
        float q = quantm(ab[j], rsf);
        #pragma unroll
        for (int c = 0; c < 10; ++c) acc[c] = fmaf(q, wdi[c * 2048 + j], acc[c]);
    }
    #pragma unroll
    for (int c = 0; c < 10; ++c)
        #pragma unroll
        for (int o = 32; o; o >>= 1) acc[c] += __shfl_down(acc[c], o, 64);
    __shared__ float red[4][10];
    int wid = threadIdx.x >> 6;
    if ((threadIdx.x & 63) == 0)
        #pragma unroll
        for (int c = 0; c < 10; ++c) red[wid][c] = acc[c];
    __syncthreads();
    if (threadIdx.x < 10) {
        int c = threadIdx.x;
        float s = red[0][c] + red[1][c] + red[2][c] + red[3][c];
        float bsf = wsfd[c] * sf;
        float bint = rintf(bd[c] / bsf);
        logits[b * 10 + c] = (s + bint) * bsf;
    }
}

// ---------------- softmax over batch axis (dim 0) ----------------
__global__ __launch_bounds__(256) void k_softmax(const float* __restrict__ logits, float* __restrict__ out) {
    int c = blockIdx.x;
    float v0 = logits[(threadIdx.x +   0) * 10 + c];
    float v1 = logits[(threadIdx.x + 256) * 10 + c];
    float v2 = logits[(threadIdx.x + 512) * 10 + c];
    float v3 = logits[(threadIdx.x + 768) * 10 + c];
    float mx = fmaxf(fmaxf(v0, v1), fmaxf(v2, v3));
    __shared__ float redm[4];
    __shared__ float reds[4];
    #pragma unroll
    for (int o = 32; o; o >>= 1) mx = fmaxf(mx, __shfl_down(mx, o, 64));
    if ((threadIdx.x & 63) == 0) redm[threadIdx.x >> 6] = mx;
    __syncthreads();
    mx = fmaxf(fmaxf(redm[0], redm[1]), fmaxf(redm[2], redm[3]));
    float e0 = expf(v0 - mx), e1 = expf(v1 - mx), e2 = expf(v2 - mx), e3 = expf(v3 - mx);
    float s = (e0 + e1) + (e2 + e3);
    #pragma unroll
    for (int o = 32; o; o >>= 1) s += __shfl_down(s, o, 64);
    if ((threadIdx.x & 63) == 0) reds[threadIdx.x >> 6] = s;
    __syncthreads();
    s = reds[0] + reds[1] + reds[2] + reds[3];
    out[(threadIdx.x +   0) * 10 + c] = e0 / s;
    out[(threadIdx.x + 256) * 10 + c] = e1 / s;
    out[(threadIdx.x + 512) * 10 + c] = e2 / s;
    out[(threadIdx.x + 768) * 10 + c] = e3 / s;
}

extern "C" void kernel_launch(void* const* d_in, const int* in_sizes, int n_in,
                              void* d_out, int out_size, void* d_ws, size_t ws_size,
                              hipStream_t stream) {
    (void)in_sizes; (void)n_in; (void)out_size; (void)ws_size;
    const float* x = (const float*)d_in[0];
    const float *w[5], *bia[5], *g[5], *bb[5], *m[5], *v[5];
    for (int i = 0; i < 5; ++i) {
        w[i]   = (const float*)d_in[1 + 6 * i + 0];
        bia[i] = (const float*)d_in[1 + 6 * i + 1];
        g[i]   = (const float*)d_in[1 + 6 * i + 2];
        bb[i]  = (const float*)d_in[1 + 6 * i + 3];
        m[i]   = (const float*)d_in[1 + 6 * i + 4];
        v[i]   = (const float*)d_in[1 + 6 * i + 5];
    }
    const float* wd = (const float*)d_in[31];
    const float* bd = (const float*)d_in[32];
    float* ws = (float*)d_ws;
    unsigned* umax = (unsigned*)ws;   // [6][64] buckets
    float* out = (float*)d_out;

    float* w0kt = ws + OFF_W0KT;
    float* w0p  = ws + OFF_W0P;
    float* w1i  = ws + OFF_W1I;
    float* w2kt = ws + OFF_W2KT;
    float* w3t  = ws + OFF_W3T;
    float* w4t  = ws + OFF_W4T;
    float* wdi  = ws + OFF_WDI;
    float* wsf0 = ws + OFF_WSF0; float* bns0 = ws + OFF_BNS0; float* bnb0 = ws + OFF_BNB0;
    float* wsf1 = ws + OFF_WSF1; float* bns1 = ws + OFF_BNS1; float* bnb1 = ws + OFF_BNB1;
    float* wsf2 = ws + OFF_WSF2; float* bns2 = ws + OFF_BNS2; float* bnb2 = ws + OFF_BNB2;
    float* wsf3 = ws + OFF_WSF3; float* bns3 = ws + OFF_BNS3; float* bnb3 = ws + OFF_BNB3;
    float* wsf4 = ws + OFF_WSF4; float* bns4 = ws + OFF_BNS4; float* bnb4 = ws + OFF_BNB4;
    float* wsfd = ws + OFF_WSFD;
    float* logits = ws + OFF_LOG;
    float* actA = ws + ACT_A_OFF;   // act2 / act4
    float* actB = ws + ACT_B_OFF;   // act1 / act3

    PrepAll pa;
    pa.umax = umax;
    const float* ww[6] = {w[0], w[1], w[2], w[3], w[4], wd};
    float* wsfp[6] = {wsf0, wsf1, wsf2, wsf3, wsf4, wsfd};
    float* dstp[6] = {w0kt, w1i, w2kt, w3t, w4t, wdi};
    float* dst2p[6] = {w0p, nullptr, nullptr, nullptr, nullptr, nullptr};
    float* bnsp[6] = {bns0, bns1, bns2, bns3, bns4, nullptr};
    float* bnbp[6] = {bnb0, bnb1, bnb2, bnb3, bnb4, nullptr};
    int Ks[6]   = {27, 32, 36, 288, 288, 2048};
    int modes[6] = {2, 0, 1, 3, 3, 0};
    for (int i = 0; i < 6; ++i) {
        pa.e[i].w = ww[i];
        pa.e[i].g = (i < 5) ? g[i] : nullptr;
        pa.e[i].bb = (i < 5) ? bb[i] : nullptr;
        pa.e[i].m = (i < 5) ? m[i] : nullptr;
        pa.e[i].v = (i < 5) ? v[i] : nullptr;
        pa.e[i].wsf = wsfp[i];
        pa.e[i].dst = dstp[i];
        pa.e[i].dst2 = dst2p[i];
        pa.e[i].bns = bnsp[i];
        pa.e[i].bnb = bnbp[i];
        pa.e[i].K = Ks[i];
        pa.e[i].has_bn = (i < 5) ? 1 : 0;
        pa.e[i].mode = modes[i];
    }

    hipLaunchKernelGGL(k_prep_all, dim3(143), dim3(256), 0, stream, pa);
    hipLaunchKernelGGL(k_absmax, dim3(1024), dim3(256), 0, stream,
                       (const float4*)x, 1024 * 3 * 32 * 32 / 4, umax + 0 * 64);
    hipLaunchKernelGGL(k_conv0maxN, dim3(2048), dim3(256), 0, stream,
                       x, w0kt, wsf0, bia[0], bns0, bnb0, umax, umax + 1 * 64);
    hipLaunchKernelGGL(k_conv01n, dim3(1024), dim3(256), 0, stream,
                       x, w0p, wsf0, bia[0], bns0, bnb0,
                       w1i, wsf1, bia[1], bns1, bnb1, umax, umax + 2 * 64, actB);
    hipLaunchKernelGGL(k_conv2c, dim3(1024), dim3(256), 0, stream,
                       actB, w2kt, wsf2, bia[2], bns2, bnb2, umax, umax + 3 * 64, actA);
    hipLaunchKernelGGL((k_conv34d<16, 2>), dim3(512), dim3(256), 0, stream,
                       actA, w3t, wsf3, bia[3], bns3, bnb3, umax, 3, umax + 4 * 64, actB);
    hipLaunchKernelGGL((k_conv34d<8, 1>),  dim3(512), dim3(256), 0, stream,
                       actB, w4t, wsf4, bia[4], bns4, bnb4, umax, 4, umax + 5 * 64, actA);
    hipLaunchKernelGGL(k_fc, dim3(1024), dim3(256), 0, stream, actA, wdi, wsfd, bd, umax, logits);
    hipLaunchKernelGGL(k_softmax, dim3(10), dim3(256), 0, stream, logits, out);
}

// Round 17
// 162.383 us; speedup vs baseline: 2.4696x; 1.0138x over previous
//
#include <hip/hip_runtime.h>

#define DI __device__ __forceinline__

// ---------------- ws layout (float offsets) ----------------
// umax[6][64] buckets (uint32) at 0..384
constexpr int OFF_W0KT = 384;     // 27*32 (k-major, conv0maxN)
constexpr int OFF_W0P  = 1248;    // 32*28 (padded oc-major, conv01n)
constexpr int OFF_W1I  = 2144;    // 4*32
constexpr int OFF_W2KT = 2272;    // 36*32 (k-major, conv2c)
constexpr int OFF_W3T  = 3424;    // 4*72*36 (phase-k-major, conv3)
constexpr int OFF_W4T  = 13792;   // 10368
constexpr int OFF_WDI  = 24160;   // 20480
constexpr int OFF_WSF0 = 44640;
constexpr int OFF_BNS0 = 44672;
constexpr int OFF_BNB0 = 44704;
constexpr int OFF_WSF1 = 44736;
constexpr int OFF_BNS1 = 44740;
constexpr int OFF_BNB1 = 44744;
constexpr int OFF_WSF2 = 44748;
constexpr int OFF_BNS2 = 44780;
constexpr int OFF_BNB2 = 44812;
constexpr int OFF_WSF3 = 44844;
constexpr int OFF_BNS3 = 44876;
constexpr int OFF_BNB3 = 44908;
constexpr int OFF_WSF4 = 44940;
constexpr int OFF_BNS4 = 44972;
constexpr int OFF_BNB4 = 45004;
constexpr int OFF_WSFD = 45036;   // 10
constexpr int OFF_LOG  = 45056;   // 10240
constexpr int OFF_ACT  = 55296;
constexpr long ACT_A_OFF = OFF_ACT;              // act2/act4
constexpr long ACT_B_OFF = OFF_ACT + 8388608L;   // act1/act3

// ---------------- helpers ----------------
DI float quantm(float x, float rsf) {
    float q = rintf(x * rsf);
    return fminf(fmaxf(q, -127.0f), 127.0f);
}
DI float get_sf(const unsigned* umax, int slot) {
    const unsigned* p = umax + slot * 64;
    unsigned m = 0u;
    #pragma unroll
    for (int i = 0; i < 64; ++i) m = m > p[i] ? m : p[i];
    return fmaxf(__uint_as_float(m) / 127.0f, 1e-8f);
}
DI void block_max_atomic(float v, unsigned* dst) {
    __shared__ float redm_[4];
    #pragma unroll
    for (int o = 32; o; o >>= 1) v = fmaxf(v, __shfl_down(v, o, 64));
    int wid = threadIdx.x >> 6;
    if ((threadIdx.x & 63) == 0) redm_[wid] = v;
    __syncthreads();
    if (threadIdx.x == 0) {
        int nw = blockDim.x >> 6;
        float m = redm_[0];
        for (int i = 1; i < nw; ++i) m = fmaxf(m, redm_[i]);
        atomicMax(dst + (blockIdx.x & 63), __float_as_uint(m));
    }
}

// ---------------- prep: weight quant + BN fold + layout transposes ----------------
struct PrepEntry {
    const float *w, *g, *bb, *m, *v;
    float *wsf, *dst, *dst2, *bns, *bnb;
    int K; int has_bn; int mode;
};
struct PrepAll { PrepEntry e[6]; unsigned* umax; };

__global__ __launch_bounds__(256) void k_prep_all(PrepAll pa) {
    int blk = blockIdx.x;
    if (blk == 142) {
        for (int i = threadIdx.x; i < 384; i += 256) pa.umax[i] = 0u;
        return;
    }
    int layer, oc;
    if      (blk < 32)  { layer = 0; oc = blk; }
    else if (blk < 36)  { layer = 1; oc = blk - 32; }
    else if (blk < 68)  { layer = 2; oc = blk - 36; }
    else if (blk < 100) { layer = 3; oc = blk - 68; }
    else if (blk < 132) { layer = 4; oc = blk - 100; }
    else                { layer = 5; oc = blk - 132; }
    PrepEntry a = pa.e[layer];
    const float* wr = a.w + (long)oc * a.K;
    float mx = 0.f;
    for (int i = threadIdx.x; i < a.K; i += 256) mx = fmaxf(mx, fabsf(wr[i]));
    __shared__ float red[4];
    __shared__ float s_sf;
    #pragma unroll
    for (int o = 32; o; o >>= 1) mx = fmaxf(mx, __shfl_down(mx, o, 64));
    if ((threadIdx.x & 63) == 0) red[threadIdx.x >> 6] = mx;
    __syncthreads();
    if (threadIdx.x == 0) {
        float t = fmaxf(fmaxf(red[0], red[1]), fmaxf(red[2], red[3]));
        t = fmaxf(t / 127.0f, 1e-8f);
        a.wsf[oc] = t; s_sf = t;
        if (a.has_bn) {
            float inv = a.g[oc] / sqrtf(a.v[oc] + 1e-5f);
            a.bns[oc] = inv;
            a.bnb[oc] = a.bb[oc] - a.m[oc] * inv;
        }
    }
    __syncthreads();
    float sf = s_sf;
    for (int i = threadIdx.x; i < a.K; i += 256) {
        float q = rintf(wr[i] / sf);
        if (a.mode == 0) {
            a.dst[(long)oc * a.K + i] = q;
        } else if (a.mode == 1) {
            a.dst[i * 32 + oc] = q;
        } else if (a.mode == 2) {
            a.dst[i * 32 + oc] = q;
            a.dst2[oc * 28 + i] = q;
        } else {
            int ph = i / 72, kk = i - ph * 72;
            a.dst[ph * 2592 + kk * 36 + oc] = q;
        }
    }
    if (a.mode == 2 && threadIdx.x == 0) a.dst2[oc * 28 + 27] = 0.f;
}

__global__ __launch_bounds__(256) void k_absmax(const float4* __restrict__ x, int n4, unsigned* dst) {
    float m = 0.f;
    for (int i = blockIdx.x * blockDim.x + threadIdx.x; i < n4; i += gridDim.x * blockDim.x) {
        float4 t = x[i];
        m = fmaxf(m, fmaxf(fmaxf(fabsf(t.x), fabsf(t.y)), fmaxf(fabsf(t.z), fabsf(t.w))));
    }
    block_max_atomic(m, dst);
}

// ---------------- conv0 pass 1: max only. grid 2048 = (image, row-half) ----------------
__global__ __launch_bounds__(256) void k_conv0maxN(
    const float* __restrict__ x, const float* __restrict__ w0kt,
    const float* __restrict__ wsf0, const float* __restrict__ bias0,
    const float* __restrict__ bns0, const float* __restrict__ bnb0,
    const unsigned* __restrict__ umax, unsigned* __restrict__ mout) {
    __shared__ float tile[3 * 18 * 36];   // 1944
    __shared__ float wlds[27 * 32];       // 864, k-major
    __shared__ float As[32], Cs[32];
    const int b  = blockIdx.x >> 1;
    const int r0 = (blockIdx.x & 1) * 16;
    const int tid = threadIdx.x;
    const float sfx = get_sf(umax, 0);
    const float rsfx = 1.0f / sfx;
    if (tid < 32) {
        int oc = tid;
        float bsf = wsf0[oc] * sfx;
        float bint = rintf(bias0[oc] / bsf);
        float a = bsf * bns0[oc];
        As[oc] = a;
        Cs[oc] = fmaf(bint, a, bnb0[oc]);
    }
    for (int i = tid; i < 1944; i += 256) tile[i] = 0.f;
    if (tid < 216) ((float4*)wlds)[tid] = ((const float4*)w0kt)[tid];
    __syncthreads();
    const float* xb = x + (long)b * 3072;
    for (int i = tid; i < 1728; i += 256) {
        int ci = i / 576, rem = i - ci * 576;
        int rr = rem >> 5, cc = rem & 31;
        int gr = r0 - 1 + rr;
        if ((unsigned)gr < 32u)
            tile[ci * 648 + rr * 36 + cc + 1] = quantm(xb[ci * 1024 + gr * 32 + cc], rsfx);
    }
    __syncthreads();
    const int oc0  = (tid >> 5) * 4;
    const int pxg  = tid & 31;
    const int row  = pxg >> 1;
    const int wcol = (pxg & 1) * 16;
    float acc[4][16];
    #pragma unroll
    for (int o = 0; o < 4; ++o)
        #pragma unroll
        for (int p = 0; p < 16; ++p) acc[o][p] = 0.f;
    #pragma unroll
    for (int kk = 0; kk < 9; ++kk) {            // FULL unroll: pipeline ds_reads across iters
        int ci = kk / 3, ky = kk - ci * 3;
        const float* rp = tile + ci * 648 + (row + ky) * 36 + wcol;
        float wn[20];
        #pragma unroll
        for (int d = 0; d < 5; ++d) *(float4*)&wn[4 * d] = *(const float4*)&rp[4 * d];
        #pragma unroll
        for (int kx = 0; kx < 3; ++kx) {
            float4 wv = *(const float4*)&wlds[(kk * 3 + kx) * 32 + oc0];
            const float* wf = &wv.x;
            #pragma unroll
            for (int o = 0; o < 4; ++o)
                #pragma unroll
                for (int p = 0; p < 16; ++p)
                    acc[o][p] = fmaf(wn[p + kx], wf[o], acc[o][p]);
        }
    }
    float lmax = 0.f;
    #pragma unroll
    for (int o = 0; o < 4; ++o) {
        float A = As[oc0 + o], C = Cs[oc0 + o];
        #pragma unroll
        for (int p = 0; p < 16; ++p)
            lmax = fmaxf(lmax, fabsf(fmaf(acc[o][p], A, C)));
    }
    block_max_atomic(lmax, mout);
}

// ---------------- conv0 pass 2 + fused 1x1 conv1. grid 1024 = 1 image/block ----------------
__global__ __launch_bounds__(256) void k_conv01n(
    const float* __restrict__ x, const float* __restrict__ w0p,
    const float* __restrict__ wsf0, const float* __restrict__ bias0,
    const float* __restrict__ bns0, const float* __restrict__ bnb0,
    const float* __restrict__ w1i,
    const float* __restrict__ wsf1, const float* __restrict__ bias1,
    const float* __restrict__ bns1, const float* __restrict__ bnb1,
    const unsigned* __restrict__ umax, unsigned* __restrict__ mout,
    float* __restrict__ out) {
    __shared__ float tile[3672];   // [3][34][36]
    __shared__ float wls0[896];    // [32][28] padded
    __shared__ float wls1[128];    // [32][4] oc-major
    __shared__ float Aq[32], Cq[32];
    __shared__ float A1s[4], C1s[4];
    const int b   = blockIdx.x;
    const int tid = threadIdx.x;
    const float sfx = get_sf(umax, 0);
    const float rsfx = 1.0f / sfx;
    const float sf1 = get_sf(umax, 1);
    const float rsf1 = 1.0f / sf1;
    if (tid < 32) {
        int oc = tid;
        float bsf = wsf0[oc] * sfx;
        float bint = rintf(bias0[oc] / bsf);
        float a = bsf * bns0[oc];
        float c = fmaf(bint, a, bnb0[oc]);
        Aq[oc] = a * rsf1;
        Cq[oc] = c * rsf1;
    }
    if (tid >= 64 && tid < 68) {
        int oc = tid - 64;
        float bsf = wsf1[oc] * sf1;
        float bint = rintf(bias1[oc] / bsf);
        float a = bsf * bns1[oc];
        A1s[oc] = a;
        C1s[oc] = fmaf(bint, a, bnb1[oc]);
    }
    for (int i = tid; i < 3672; i += 256) tile[i] = 0.f;
    if (tid < 224) ((float4*)wls0)[tid] = ((const float4*)w0p)[tid];
    if (tid >= 128 && tid < 256) {
        int j = tid - 128;
        wls1[(j & 31) * 4 + (j >> 5)] = w1i[j];
    }
    __syncthreads();
    const float* xb = x + (long)b * 3072;
    for (int i = tid; i < 3072; i += 256) {
        int ci = i >> 10, px = i & 1023;
        int iy = px >> 5, ix = px & 31;
        tile[ci * 1224 + (iy + 1) * 36 + (ix + 1)] = quantm(xb[i], rsfx);
    }
    __syncthreads();
    const int h   = tid >> 3;
    const int w0c = (tid & 7) * 4;
    float win[3][3][6];
    #pragma unroll
    for (int ci = 0; ci < 3; ++ci)
        #pragma unroll
        for (int ky = 0; ky < 3; ++ky) {
            const int base = ci * 1224 + (h + ky) * 36 + w0c;
            *(float4*)&win[ci][ky][0] = *(const float4*)&tile[base];
            *(float2*)&win[ci][ky][4] = *(const float2*)&tile[base + 4];
        }
    float acc1[4][4];
    #pragma unroll
    for (int o = 0; o < 4; ++o)
        #pragma unroll
        for (int p = 0; p < 4; ++p) acc1[o][p] = 0.f;
    #pragma unroll 2
    for (int oc = 0; oc < 32; ++oc) {           // unroll 2: overlap next wreg load with FMAs
        float wreg[28];
        const float4* wp4 = (const float4*)&wls0[oc * 28];
        #pragma unroll
        for (int d = 0; d < 7; ++d) *(float4*)&wreg[4 * d] = wp4[d];
        float a0 = 0.f, a1 = 0.f, a2 = 0.f, a3 = 0.f;
        #pragma unroll
        for (int ci = 0; ci < 3; ++ci)
            #pragma unroll
            for (int ky = 0; ky < 3; ++ky)
                #pragma unroll
                for (int kx = 0; kx < 3; ++kx) {
                    float wv = wreg[ci * 9 + ky * 3 + kx];
                    a0 = fmaf(win[ci][ky][kx + 0], wv, a0);
                    a1 = fmaf(win[ci][ky][kx + 1], wv, a1);
                    a2 = fmaf(win[ci][ky][kx + 2], wv, a2);
                    a3 = fmaf(win[ci][ky][kx + 3], wv, a3);
                }
        float A = Aq[oc], C = Cq[oc];
        float q0 = fminf(fmaxf(rintf(fmaf(a0, A, C)), -127.0f), 127.0f);
        float q1 = fminf(fmaxf(rintf(fmaf(a1, A, C)), -127.0f), 127.0f);
        float q2 = fminf(fmaxf(rintf(fmaf(a2, A, C)), -127.0f), 127.0f);
        float q3 = fminf(fmaxf(rintf(fmaf(a3, A, C)), -127.0f), 127.0f);
        const float4 w1v = *(const float4*)&wls1[oc * 4];
        acc1[0][0] = fmaf(q0, w1v.x, acc1[0][0]); acc1[0][1] = fmaf(q1, w1v.x, acc1[0][1]);
        acc1[0][2] = fmaf(q2, w1v.x, acc1[0][2]); acc1[0][3] = fmaf(q3, w1v.x, acc1[0][3]);
        acc1[1][0] = fmaf(q0, w1v.y, acc1[1][0]); acc1[1][1] = fmaf(q1, w1v.y, acc1[1][1]);
        acc1[1][2] = fmaf(q2, w1v.y, acc1[1][2]); acc1[1][3] = fmaf(q3, w1v.y, acc1[1][3]);
        acc1[2][0] = fmaf(q0, w1v.z, acc1[2][0]); acc1[2][1] = fmaf(q1, w1v.z, acc1[2][1]);
        acc1[2][2] = fmaf(q2, w1v.z, acc1[2][2]); acc1[2][3] = fmaf(q3, w1v.z, acc1[2][3]);
        acc1[3][0] = fmaf(q0, w1v.w, acc1[3][0]); acc1[3][1] = fmaf(q1, w1v.w, acc1[3][1]);
        acc1[3][2] = fmaf(q2, w1v.w, acc1[3][2]); acc1[3][3] = fmaf(q3, w1v.w, acc1[3][3]);
    }
    float lmax = 0.f;
    float* ob = out + (long)b * 4096 + h * 32 + w0c;
    #pragma unroll
    for (int o = 0; o < 4; ++o) {
        float y0 = fmaf(acc1[o][0], A1s[o], C1s[o]);
        float y1 = fmaf(acc1[o][1], A1s[o], C1s[o]);
        float y2 = fmaf(acc1[o][2], A1s[o], C1s[o]);
        float y3 = fmaf(acc1[o][3], A1s[o], C1s[o]);
        lmax = fmaxf(lmax, fmaxf(fmaxf(fabsf(y0), fabsf(y1)), fmaxf(fabsf(y2), fabsf(y3))));
        float4 r4; r4.x = y0; r4.y = y1; r4.z = y2; r4.w = y3;
        *(float4*)&ob[o * 1024] = r4;
    }
    block_max_atomic(lmax, mout);
}

// ---------------- conv2 (4->32, 3x3, s2): thread = 8 oc x 4 px ----------------
__global__ __launch_bounds__(256) void k_conv2c(
    const float* __restrict__ inp, const float* __restrict__ w2kt,
    const float* __restrict__ wsf, const float* __restrict__ bias,
    const float* __restrict__ bns, const float* __restrict__ bnb,
    const unsigned* __restrict__ umax, unsigned* __restrict__ mout,
    float* __restrict__ out) {
    __shared__ float tile[4 * 34 * 36];
    __shared__ float wlds[36 * 32];
    __shared__ float As[32], Cs[32];
    const int tid = threadIdx.x;
    const float sf = get_sf(umax, 2);
    const float rsf = 1.0f / sf;
    if (tid < 32) {
        int oc = tid;
        float bsf = wsf[oc] * sf;
        float bint = rintf(bias[oc] / bsf);
        float a = bsf * bns[oc];
        As[oc] = a;
        Cs[oc] = fmaf(bint, a, bnb[oc]);
    }
    for (int i = tid; i < 4896; i += 256) tile[i] = 0.f;
    for (int i = tid; i < 288; i += 256) ((float4*)wlds)[i] = ((const float4*)w2kt)[i];
    __syncthreads();
    const float* ib = inp + (long)blockIdx.x * 4096;
    for (int i = tid; i < 4096; i += 256) {
        int ci = i >> 10, px = i & 1023;
        int iy = px >> 5, ix = px & 31;
        tile[ci * 1224 + (iy + 1) * 36 + (ix + 1)] = quantm(ib[i], rsf);
    }
    __syncthreads();
    const int oc0 = (tid >> 6) * 8;
    const int pxq = tid & 63;
    const int h = pxq >> 2, c = pxq & 3;
    float acc[8][4];
    #pragma unroll
    for (int k = 0; k < 8; ++k)
        #pragma unroll
        for (int p = 0; p < 4; ++p) acc[k][p] = 0.f;
    #pragma unroll
    for (int ci = 0; ci < 4; ++ci) {            // FULL unroll
        #pragma unroll
        for (int ky = 0; ky < 3; ++ky) {
            const float* rp = tile + ci * 1224 + (2 * h + ky) * 36 + 8 * c;
            float wn[12];
            #pragma unroll
            for (int d = 0; d < 3; ++d) *(float4*)&wn[4 * d] = *(const float4*)&rp[4 * d];
            #pragma unroll
            for (int kx = 0; kx < 3; ++kx) {
                const float* wp = &wlds[(ci * 9 + ky * 3 + kx) * 32 + oc0];
                float4 wa = *(const float4*)&wp[0];
                float4 wb = *(const float4*)&wp[4];
                float wf[8] = {wa.x, wa.y, wa.z, wa.w, wb.x, wb.y, wb.z, wb.w};
                #pragma unroll
                for (int k = 0; k < 8; ++k)
                    #pragma unroll
                    for (int p = 0; p < 4; ++p)
                        acc[k][p] = fmaf(wn[2 * p + kx], wf[k], acc[k][p]);
            }
        }
    }
    float lmax = 0.f;
    float* ob = out + (long)blockIdx.x * 8192;
    #pragma unroll
    for (int k = 0; k < 8; ++k) {
        int oc = oc0 + k;
        float A = As[oc], C = Cs[oc];
        float4 r;
        float* rp = &r.x;
        #pragma unroll
        for (int p = 0; p < 4; ++p) {
            float y = fmaf(acc[k][p], A, C);
            rp[p] = y;
            lmax = fmaxf(lmax, fabsf(y));
        }
        *(float4*)&ob[oc * 256 + h * 16 + c * 4] = r;
    }
    block_max_atomic(lmax, mout);
}

// ---------------- conv3/conv4: 2 img/block, 4oc x 4px, K-phased. grid 512 ----------------
template<int HIN, int S>
__global__ __launch_bounds__(256) void k_conv34d(
    const float* __restrict__ inp, const float* __restrict__ wt,
    const float* __restrict__ wsf, const float* __restrict__ bias,
    const float* __restrict__ bns, const float* __restrict__ bnb,
    const unsigned* __restrict__ umax, int slot, unsigned* __restrict__ mout,
    float* __restrict__ out) {
    constexpr int ROWS = HIN + 2;
    constexpr int RS   = (S == 2) ? 20 : 12;
    constexpr int TI   = 8 * ROWS * RS;
    constexpr int PIX  = HIN * HIN;
    constexpr int PSH  = (HIN == 16) ? 8 : 6;
    constexpr int HSH  = (HIN == 16) ? 4 : 3;
    constexpr int NELT = 2 * 8 * PIX;
    constexpr int WINW = (S == 2) ? 12 : 8;
    constexpr int ND   = (S == 2) ? 3 : 2;
    __shared__ float tile[2 * TI];
    __shared__ float wlds[2592];
    __shared__ float As[32], Cs[32];
    const int tid  = threadIdx.x;
    const int imgl = tid >> 7;
    const int ocg  = (tid >> 4) & 7;
    const int pxq  = tid & 15;
    const int h = pxq >> 1, c = pxq & 1;
    const float sf = get_sf(umax, slot);
    const float rsf = 1.0f / sf;
    if (tid < 32) {
        int oc = tid;
        float bsf = wsf[oc] * sf;
        float bint = rintf(bias[oc] / bsf);
        float a = bsf * bns[oc];
        As[oc] = a;
        Cs[oc] = fmaf(bint, a, bnb[oc]);
    }
    for (int i = tid; i < 2 * TI; i += 256) tile[i] = 0.f;
    float acc[4][4];
    #pragma unroll
    for (int k = 0; k < 4; ++k)
        #pragma unroll
        for (int p = 0; p < 4; ++p) acc[k][p] = 0.f;
    const float* ib = inp + (long)blockIdx.x * 2 * 32 * PIX;
    const float4* wt4 = (const float4*)wt;
    for (int ph = 0; ph < 4; ++ph) {
        __syncthreads();
        for (int i = tid; i < NELT; i += 256) {
            int im = i >> (PSH + 3);
            int ci = (i >> PSH) & 7;
            int px = i & (PIX - 1);
            int iy = px >> HSH, ix = px & (HIN - 1);
            tile[im * TI + ci * (ROWS * RS) + (iy + 1) * RS + (ix + 1)] =
                quantm(ib[(long)((im * 32 + ph * 8 + ci) << PSH) + px], rsf);
        }
        for (int i = tid; i < 648; i += 256) ((float4*)wlds)[i] = wt4[ph * 648 + i];
        __syncthreads();
        const int tbo = imgl * TI;
        #pragma unroll
        for (int ci = 0; ci < 8; ++ci) {        // FULL unroll: deep pipeline across 8 ci
            float win[3][WINW];
            #pragma unroll
            for (int ky = 0; ky < 3; ++ky) {
                const int base = tbo + ci * (ROWS * RS) + (S * h + ky) * RS + S * 4 * c;
                #pragma unroll
                for (int d = 0; d < ND; ++d)
                    *(float4*)&win[ky][4 * d] = *(const float4*)&tile[base + 4 * d];
            }
            #pragma unroll
            for (int ky = 0; ky < 3; ++ky)
                #pragma unroll
                for (int kx = 0; kx < 3; ++kx) {
                    int j = ky * 3 + kx;
                    float4 wv = *(const float4*)&wlds[(ci * 9 + j) * 36 + ocg * 4];
                    float x0 = win[ky][S * 0 + kx];
                    float x1 = win[ky][S * 1 + kx];
                    float x2 = win[ky][S * 2 + kx];
                    float x3 = win[ky][S * 3 + kx];
                    acc[0][0] = fmaf(x0, wv.x, acc[0][0]); acc[0][1] = fmaf(x1, wv.x, acc[0][1]);
                    acc[0][2] = fmaf(x2, wv.x, acc[0][2]); acc[0][3] = fmaf(x3, wv.x, acc[0][3]);
                    acc[1][0] = fmaf(x0, wv.y, acc[1][0]); acc[1][1] = fmaf(x1, wv.y, acc[1][1]);
                    acc[1][2] = fmaf(x2, wv.y, acc[1][2]); acc[1][3] = fmaf(x3, wv.y, acc[1][3]);
                    acc[2][0] = fmaf(x0, wv.z, acc[2][0]); acc[2][1] = fmaf(x1, wv.z, acc[2][1]);
                    acc[2][2] = fmaf(x2, wv.z, acc[2][2]); acc[2][3] = fmaf(x3, wv.z, acc[2][3]);
                    acc[3][0] = fmaf(x0, wv.w, acc[3][0]); acc[3][1] = fmaf(x1, wv.w, acc[3][1]);
                    acc[3][2] = fmaf(x2, wv.w, acc[3][2]); acc[3][3] = fmaf(x3, wv.w, acc[3][3]);
                }
        }
    }
    float lmax = 0.f;
    long imgg = (long)blockIdx.x * 2 + imgl;
    #pragma unroll
    for (int k = 0; k < 4; ++k) {
        int oc = ocg * 4 + k;
        float A = As[oc], C = Cs[oc];
        float y0 = fmaf(acc[k][0], A, C);
        float y1 = fmaf(acc[k][1], A, C);
        float y2 = fmaf(acc[k][2], A, C);
        float y3 = fmaf(acc[k][3], A, C);
        lmax = fmaxf(lmax, fmaxf(fmaxf(fabsf(y0), fabsf(y1)), fmaxf(fabsf(y2), fabsf(y3))));
        float4 r4; r4.x = y0; r4.y = y1; r4.z = y2; r4.w = y3;
        *(float4*)&out[(imgg * 32 + oc) * 64 + h * 8 + c * 4] = r4;
    }
    block_max_atomic(lmax, mout);
}

// ---------------- linear 2048->10 per image ----------------
__global__ __launch_bounds__(256) void k_fc(
    const float* __restrict__ act, const float* __restrict__ wdi,
    const float* __restrict__ wsfd, const float* __restrict__ bd,
    const unsigned* __restrict__ umax, float* __restrict__ logits) {
    int b = blockIdx.x;
    float sf = get_sf(umax, 5);
    float rsf = 1.0f / sf;
    const float* ab = act + (long)b * 2048;
    float acc[10];
    #pragma unroll
    for (int c = 0; c < 10; ++c) acc[c] = 0.f;
    #pragma unroll
    for (int k = 0; k < 8; ++k) {
        int j = threadIdx.x + 256 * k;
        float q = quantm(ab[j], rsf);
        #pragma unroll
        for (int c = 0; c < 10; ++c) acc[c] = fmaf(q, wdi[c * 2048 + j], acc[c]);
    }
    #pragma unroll
    for (int c = 0; c < 10; ++c)
        #pragma unroll
        for (int o = 32; o; o >>= 1) acc[c] += __shfl_down(acc[c], o, 64);
    __shared__ float red[4][10];
    int wid = threadIdx.x >> 6;
    if ((threadIdx.x & 63) == 0)
        #pragma unroll
        for (int c = 0; c < 10; ++c) red[wid][c] = acc[c];
    __syncthreads();
    if (threadIdx.x < 10) {
        int c = threadIdx.x;
        float s = red[0][c] + red[1][c] + red[2][c] + red[3][c];
        float bsf = wsfd[c] * sf;
        float bint = rintf(bd[c] / bsf);
        logits[b * 10 + c] = (s + bint) * bsf;
    }
}

// ---------------- softmax over batch axis (dim 0) ----------------
__global__ __launch_bounds__(256) void k_softmax(const float* __restrict__ logits, float* __restrict__ out) {
    int c = blockIdx.x;
    float v0 = logits[(threadIdx.x +   0) * 10 + c];
    float v1 = logits[(threadIdx.x + 256) * 10 + c];
    float v2 = logits[(threadIdx.x + 512) * 10 + c];
    float v3 = logits[(threadIdx.x + 768) * 10 + c];
    float mx = fmaxf(fmaxf(v0, v1), fmaxf(v2, v3));
    __shared__ float redm[4];
    __shared__ float reds[4];
    #pragma unroll
    for (int o = 32; o; o >>= 1) mx = fmaxf(mx, __shfl_down(mx, o, 64));
    if ((threadIdx.x & 63) == 0) redm[threadIdx.x >> 6] = mx;
    __syncthreads();
    mx = fmaxf(fmaxf(redm[0], redm[1]), fmaxf(redm[2], redm[3]));
    float e0 = expf(v0 - mx), e1 = expf(v1 - mx), e2 = expf(v2 - mx), e3 = expf(v3 - mx);
    float s = (e0 + e1) + (e2 + e3);
    #pragma unroll
    for (int o = 32; o; o >>= 1) s += __shfl_down(s, o, 64);
    if ((threadIdx.x & 63) == 0) reds[threadIdx.x >> 6] = s;
    __syncthreads();
    s = reds[0] + reds[1] + reds[2] + reds[3];
    out[(threadIdx.x +   0) * 10 + c] = e0 / s;
    out[(threadIdx.x + 256) * 10 + c] = e1 / s;
    out[(threadIdx.x + 512) * 10 + c] = e2 / s;
    out[(threadIdx.x + 768) * 10 + c] = e3 / s;
}

extern "C" void kernel_launch(void* const* d_in, const int* in_sizes, int n_in,
                              void* d_out, int out_size, void* d_ws, size_t ws_size,
                              hipStream_t stream) {
    (void)in_sizes; (void)n_in; (void)out_size; (void)ws_size;
    const float* x = (const float*)d_in[0];
    const float *w[5], *bia[5], *g[5], *bb[5], *m[5], *v[5];
    for (int i = 0; i < 5; ++i) {
        w[i]   = (const float*)d_in[1 + 6 * i + 0];
        bia[i] = (const float*)d_in[1 + 6 * i + 1];
        g[i]   = (const float*)d_in[1 + 6 * i + 2];
        bb[i]  = (const float*)d_in[1 + 6 * i + 3];
        m[i]   = (const float*)d_in[1 + 6 * i + 4];
        v[i]   = (const float*)d_in[1 + 6 * i + 5];
    }
    const float* wd = (const float*)d_in[31];
    const float* bd = (const float*)d_in[32];
    float* ws = (float*)d_ws;
    unsigned* umax = (unsigned*)ws;   // [6][64] buckets
    float* out = (float*)d_out;

    float* w0kt = ws + OFF_W0KT;
    float* w0p  = ws + OFF_W0P;
    float* w1i  = ws + OFF_W1I;
    float* w2kt = ws + OFF_W2KT;
    float* w3t  = ws + OFF_W3T;
    float* w4t  = ws + OFF_W4T;
    float* wdi  = ws + OFF_WDI;
    float* wsf0 = ws + OFF_WSF0; float* bns0 = ws + OFF_BNS0; float* bnb0 = ws + OFF_BNB0;
    float* wsf1 = ws + OFF_WSF1; float* bns1 = ws + OFF_BNS1; float* bnb1 = ws + OFF_BNB1;
    float* wsf2 = ws + OFF_WSF2; float* bns2 = ws + OFF_BNS2; float* bnb2 = ws + OFF_BNB2;
    float* wsf3 = ws + OFF_WSF3; float* bns3 = ws + OFF_BNS3; float* bnb3 = ws + OFF_BNB3;
    float* wsf4 = ws + OFF_WSF4; float* bns4 = ws + OFF_BNS4; float* bnb4 = ws + OFF_BNB4;
    float* wsfd = ws + OFF_WSFD;
    float* logits = ws + OFF_LOG;
    float* actA = ws + ACT_A_OFF;   // act2 / act4
    float* actB = ws + ACT_B_OFF;   // act1 / act3

    PrepAll pa;
    pa.umax = umax;
    const float* ww[6] = {w[0], w[1], w[2], w[3], w[4], wd};
    float* wsfp[6] = {wsf0, wsf1, wsf2, wsf3, wsf4, wsfd};
    float* dstp[6] = {w0kt, w1i, w2kt, w3t, w4t, wdi};
    float* dst2p[6] = {w0p, nullptr, nullptr, nullptr, nullptr, nullptr};
    float* bnsp[6] = {bns0, bns1, bns2, bns3, bns4, nullptr};
    float* bnbp[6] = {bnb0, bnb1, bnb2, bnb3, bnb4, nullptr};
    int Ks[6]   = {27, 32, 36, 288, 288, 2048};
    int modes[6] = {2, 0, 1, 3, 3, 0};
    for (int i = 0; i < 6; ++i) {
        pa.e[i].w = ww[i];
        pa.e[i].g = (i < 5) ? g[i] : nullptr;
        pa.e[i].bb = (i < 5) ? bb[i] : nullptr;
        pa.e[i].m = (i < 5) ? m[i] : nullptr;
        pa.e[i].v = (i < 5) ? v[i] : nullptr;
        pa.e[i].wsf = wsfp[i];
        pa.e[i].dst = dstp[i];
        pa.e[i].dst2 = dst2p[i];
        pa.e[i].bns = bnsp[i];
        pa.e[i].bnb = bnbp[i];
        pa.e[i].K = Ks[i];
        pa.e[i].has_bn = (i < 5) ? 1 : 0;
        pa.e[i].mode = modes[i];
    }

    hipLaunchKernelGGL(k_prep_all, dim3(143), dim3(256), 0, stream, pa);
    hipLaunchKernelGGL(k_absmax, dim3(1024), dim3(256), 0, stream,
                       (const float4*)x, 1024 * 3 * 32 * 32 / 4, umax + 0 * 64);
    hipLaunchKernelGGL(k_conv0maxN, dim3(2048), dim3(256), 0, stream,
                       x, w0kt, wsf0, bia[0], bns0, bnb0, umax, umax + 1 * 64);
    hipLaunchKernelGGL(k_conv01n, dim3(1024), dim3(256), 0, stream,
                       x, w0p, wsf0, bia[0], bns0, bnb0,
                       w1i, wsf1, bia[1], bns1, bnb1, umax, umax + 2 * 64, actB);
    hipLaunchKernelGGL(k_conv2c, dim3(1024), dim3(256), 0, stream,
                       actB, w2kt, wsf2, bia[2], bns2, bnb2, umax, umax + 3 * 64, actA);
    hipLaunchKernelGGL((k_conv34d<16, 2>), dim3(512), dim3(256), 0, stream,
                       actA, w3t, wsf3, bia[3], bns3, bnb3, umax, 3, umax + 4 * 64, actB);
    hipLaunchKernelGGL((k_conv34d<8, 1>),  dim3(512), dim3(256), 0, stream,
                       actB, w4t, wsf4, bia[4], bns4, bnb4, umax, 4, umax + 5 * 64, actA);
    hipLaunchKernelGGL(k_fc, dim3(1024), dim3(256), 0, stream, actA, wdi, wsfd, bd, umax, logits);
    hipLaunchKernelGGL(k_softmax, dim3(10), dim3(256), 0, stream, logits, out);
}